// Round 5
// baseline (344.743 us; speedup 1.0000x reference)
//
#include <hip/hip_runtime.h>
#include <hip/hip_bf16.h>

typedef __attribute__((ext_vector_type(8))) short short8;
typedef __attribute__((ext_vector_type(4))) float floatx4;
typedef __attribute__((ext_vector_type(2))) unsigned short ushortx2;

#define NHID 128
#define PADROW 136   // u16 row stride: 272B, 16B-aligned b128, benign banking
#define EB 64        // nodes per tile (encdec / fallback)
#define EB2 128      // edges per tile (edge_sorted)
#define PB 256       // partition blocks for the 2-level sort

__device__ __forceinline__ unsigned short f2bf(float x) {
  unsigned int u = __float_as_uint(x);
  u += 0x7FFFu + ((u >> 16) & 1u);          // RNE
  return (unsigned short)(u >> 16);
}

__device__ __forceinline__ unsigned int pkbf(float a, float b) {
  __hip_bfloat162 h = __float22bfloat162_rn(make_float2(a, b));
  union { __hip_bfloat162 h; unsigned int u; } cv;
  cv.h = h;
  return cv.u;
}

__device__ __forceinline__ unsigned int pack2(float a, float b) {
  return (unsigned int)f2bf(a) | ((unsigned int)f2bf(b) << 16);
}

// packed u16 max (v_pk_max_u16)
__device__ __forceinline__ unsigned int pkmax(unsigned int a, unsigned int b) {
  union { unsigned int u; ushortx2 v; } x, y;
  x.u = a; y.u = b;
  x.v = __builtin_elementwise_max(x.v, y.v);
  return x.u;
}

__device__ __forceinline__ void casmax(unsigned int* ap, unsigned int run) {
  unsigned int old = *ap;
  while (true) {
    unsigned int mx = pkmax(old, run);
    if (mx == old) break;
    unsigned int got = atomicCAS(ap, old, mx);
    if (got == old) break;
    old = got;
  }
}

// all-wave inline int64 probe: odd int32 slots all-zero <=> int64 edge_index
__device__ __forceinline__ bool detect64(const int* __restrict__ ei) {
  unsigned long long b = __ballot(ei[2 * (threadIdx.x & 63) + 1] != 0);
  return b == 0ULL;
}

// 32 loop-invariant B-fragments of a 128x128 row-major f32 weight (registers), natural k.
__device__ __forceinline__ void load_bfrags(const float* __restrict__ wmat,
                                            short8* bf, int m, int q) {
  #pragma unroll
  for (int kc = 0; kc < 4; ++kc) {
    #pragma unroll
    for (int nt = 0; nt < 8; ++nt) {
      short8 v;
      #pragma unroll
      for (int j = 0; j < 8; ++j)
        v[j] = (short)f2bf(wmat[(kc * 32 + q * 8 + j) * NHID + nt * 16 + m]);
      bf[kc * 8 + nt] = v;
    }
  }
}

// same but k-permuted: B[khw][n] = w[pi(khw)][n], pi(k) = ((k&7)<<4)|(k>>3)
__device__ __forceinline__ void load_bfrags_perm(const float* __restrict__ wmat,
                                                 short8* bf, int m, int q) {
  #pragma unroll
  for (int kc = 0; kc < 4; ++kc) {
    #pragma unroll
    for (int nt = 0; nt < 8; ++nt) {
      short8 v;
      #pragma unroll
      for (int j = 0; j < 8; ++j) {
        const int khw = kc * 32 + q * 8 + j;
        const int ctrue = ((khw & 7) << 4) | (khw >> 3);
        v[j] = (short)f2bf(wmat[ctrue * NHID + nt * 16 + m]);
      }
      bf[kc * 8 + nt] = v;
    }
  }
}

__device__ __forceinline__ void mfma_block(const unsigned short* uA,
                                           const short8* bf, floatx4* acc,
                                           int w, int m, int q) {
  #pragma unroll
  for (int kc = 0; kc < 4; ++kc) {
    short8 a = *(const short8*)(uA + (16 * w + m) * PADROW + kc * 32 + q * 8);
    #pragma unroll
    for (int nt = 0; nt < 8; ++nt)
      acc[nt] = __builtin_amdgcn_mfma_f32_16x16x32_bf16(a, bf[kc * 8 + nt],
                                                        acc[nt], 0, 0, 0);
  }
}

// fallback-path zero (agg16) + detect->flag
__global__ void zero_detect_kernel(float4* __restrict__ p, int n4,
                                   const int* __restrict__ ei, int* __restrict__ flag) {
  if (blockIdx.x == 0 && threadIdx.x < 64) {
    unsigned long long b = __ballot(ei[2 * threadIdx.x + 1] != 0);
    if (threadIdx.x == 0) flag[0] = (b == 0ULL) ? 1 : 0;
  }
  int i = blockIdx.x * blockDim.x + threadIdx.x;
  int stride = gridDim.x * blockDim.x;
  float4 z = make_float4(0.f, 0.f, 0.f, 0.f);
  for (; i < n4; i += stride) p[i] = z;
}

// ---------------- 2-level counting sort by dst (no global atomics) ----------------
// Split pipeline (R11): grid-barrier fusion regressed badly (R12: 230 µs @ 4 waves/CU;
// R13: 570 µs @ 16 waves/CU — global phase lockstep + hot counter line, not occupancy).

// A1: per-partition LDS histogram over coarse buckets (dst>>8); tail blocks zero agg16
__global__ __launch_bounds__(256) void part_hist(const int* __restrict__ ei,
                                                 int* __restrict__ mat, int E, int nbuck,
                                                 float4* __restrict__ aggz, int n4) {
  const int bl = blockIdx.x, t = threadIdx.x;
  if (bl >= PB) {
    int i = (bl - PB) * 256 + t;
    const int st = (gridDim.x - PB) * 256;
    float4 z = make_float4(0.f, 0.f, 0.f, 0.f);
    for (; i < n4; i += st) aggz[i] = z;
    return;
  }
  __shared__ int hist[512];
  const bool is64 = detect64(ei);
  for (int i = t; i < nbuck; i += 256) hist[i] = 0;
  __syncthreads();
  const int chunk = (E + PB - 1) / PB;
  const int lo = bl * chunk;
  const int hi = min(lo + chunk, E);
  for (int i = lo + t; i < hi; i += 256) {
    int d = is64 ? ei[2 * E + 2 * i] : ei[E + i];
    atomicAdd(&hist[d >> 8], 1);
  }
  __syncthreads();
  for (int bu = t; bu < nbuck; bu += 256) mat[bu * PB + bl] = hist[bu];
}

// A2: per-bucket exclusive scan over the PB partitions (in place) + bucket totals
__global__ __launch_bounds__(256) void scan_rows(int* __restrict__ mat,
                                                 int* __restrict__ btot, int nbuck) {
  __shared__ int sh[256];
  const int bu = blockIdx.x, t = threadIdx.x;
  const int v = mat[bu * PB + t];
  sh[t] = v;
  __syncthreads();
  for (int off = 1; off < 256; off <<= 1) {
    int x = (t >= off) ? sh[t - off] : 0;
    __syncthreads();
    sh[t] += x;
    __syncthreads();
  }
  mat[bu * PB + t] = sh[t] - v;
  if (t == 255) btot[bu] = sh[255];
}

// A3: scatter into coarse-bucket regions; bucket starts scanned in-LDS from btot.
// 512 threads (was 256): 256-block grid is only ~4 waves/CU at 256 thr — latency-
// starved (R12 lesson). Scan section guarded to t<256 (pattern validated in R13).
__global__ __launch_bounds__(512) void part_scatter(const int* __restrict__ ei,
                                                    const int* __restrict__ mat,
                                                    const int* __restrict__ btot,
                                                    int* __restrict__ bstart,
                                                    int2* __restrict__ mid, int E, int nbuck) {
  __shared__ int off[512];
  __shared__ int bsS[512];
  const bool is64 = detect64(ei);
  const int bl = blockIdx.x, t = threadIdx.x;
  const int o0 = (t < 256 && t < nbuck) ? btot[t] : 0;
  const int o1 = (t < 256 && t + 256 < nbuck) ? btot[t + 256] : 0;
  if (t < 256) { bsS[t] = o0; bsS[t + 256] = o1; }
  __syncthreads();
  for (int o = 1; o < 256; o <<= 1) {
    int x0 = (t >= o && t < 256) ? bsS[t - o] : 0;
    int x1 = (t >= o && t < 256) ? bsS[256 + t - o] : 0;
    __syncthreads();
    if (t < 256) { bsS[t] += x0; bsS[256 + t] += x1; }
    __syncthreads();
  }
  const int tot0 = bsS[255];
  if (t < 256) bsS[256 + t] += tot0;
  __syncthreads();
  if (t < 256) {
    const int ex0 = bsS[t] - o0;
    const int ex1 = bsS[256 + t] - o1;
    if (bl == 0) { bstart[t] = ex0; bstart[256 + t] = ex1; }
    off[t]       = ex0 + ((t < nbuck) ? mat[t * PB + bl] : 0);
    off[256 + t] = ex1 + ((t + 256 < nbuck) ? mat[(t + 256) * PB + bl] : 0);
  }
  __syncthreads();
  const int chunk = (E + PB - 1) / PB;
  const int lo = bl * chunk;
  const int hi = min(lo + chunk, E);
  for (int i = lo + t; i < hi; i += 512) {
    int s = is64 ? ei[2 * i]         : ei[i];
    int d = is64 ? ei[2 * E + 2 * i] : ei[E + i];
    int p = atomicAdd(&off[d >> 8], 1);
    mid[p] = make_int2(s, d);
  }
}

// B: per-bucket counting sort by exact dst (256 local nodes), L2-resident traffic.
// 512 threads (was 256) for the same latency-starvation reason.
__global__ __launch_bounds__(512) void bucket_sort(const int2* __restrict__ mid,
                                                   const int* __restrict__ bstart,
                                                   int2* __restrict__ sorted) {
  __shared__ int h[256], cnt[256];
  const int bu = blockIdx.x, t = threadIdx.x;
  const int lo = bstart[bu], hi = bstart[bu + 1];
  if (t < 256) { h[t] = 0; cnt[t] = 0; }
  __syncthreads();
  for (int i = lo + t; i < hi; i += 512) atomicAdd(&h[mid[i].y & 255], 1);
  __syncthreads();
  const int v = (t < 256) ? h[t] : 0;
  for (int off = 1; off < 256; off <<= 1) {
    int x = (t >= off && t < 256) ? h[t - off] : 0;
    __syncthreads();
    if (t < 256) h[t] += x;
    __syncthreads();
  }
  const int excl = (t < 256) ? h[t] - v : 0;
  __syncthreads();
  if (t < 256) h[t] = excl;
  __syncthreads();
  for (int i = lo + t; i < hi; i += 512) {
    int2 e = mid[i];
    const int dl = e.y & 255;
    const int p = lo + h[dl] + atomicAdd(&cnt[dl], 1);
    sorted[p] = e;
  }
}

// ---------------- fused edge MLP (both layers MFMA) + segmented max ----------------
// R9 structure (barriers A/B/C/D/E/F): barrier lockstep is a beneficial scheduling
// fence — R10's barrier removal raised VGPR 60->92 and regressed 178->260 µs.
// FROZEN RULES (R10/R14/R15 all hit the same cliff): acc MUST be zero-init
// (bias-splat C-operand init hoists 32 loop-invariant VGPRs -> total regs cross
// the 128 residency bucket -> 1 block/CU, occupancy 43->23%). No loop-invariant
// state growth; barrier structure frozen.
// R16 (kept): layer-1 bias via spare K-slot — A k=6 := 1.0, B row j=6 := b1.
// R17 (kept): layer-2 wave remap — wave owns 32 rows (rowg=w>>1) x 64 true cols
// (colg=w&1); 36->24 b128/thread/tile. uint2 hS stores.
// R18: hS-store bank swizzle. Bank math: store bank = 16(q&1)+4r+4m — m-stride
// 16B=4 banks and q-offset 16 are both ==0 mod 4 -> 128 dwords on 16 bank-slots
// = 8-way conflict (R17's 6.4M counter). XOR col by ((row>>2)&1)<<2 u16 (8B,
// alignment-safe) moves q in {1,3} rows to odd bank-pairs -> exactly 4/bank = 0
// conflicts. Stage-3 read applies inverse XOR on its u32 index (1 v_xor/row).
// agg16: u16[N][128] in kstore (k-permuted) order. Stage-3: two-pass LDS run merge.

__global__ __launch_bounds__(512, 2) void edge_sorted_kernel(
    const float* __restrict__ x, const int2* __restrict__ sorted,
    const float* __restrict__ w1, const float* __restrict__ b1,
    const float* __restrict__ w2, const float* __restrict__ b2,
    unsigned int* aggu, int N, int E) {
  __shared__ unsigned short us[EB2 * PADROW];     // uA then hS (bf16)
  __shared__ short8 w2f[2048];                    // 32 frags x 64 lanes, k-permuted
  __shared__ int esS[EB2], edS[EB2];
  __shared__ int pn[2];                           // dst before / after tile (-2 = none)
  __shared__ unsigned long long maskS[2];         // run-start bitmask
  __shared__ unsigned int pmS[8][64];             // per-quarter partial of run covering r0

  const int t = threadIdx.x;
  const int lane = t & 63;
  const int w = t >> 6;                           // wave 0..7
  const int m = lane & 15;
  const int q = lane >> 4;
  const int rowg = w >> 1;                        // layer-2: rows [32*rowg, +32)
  const int colg = w & 1;                         // layer-2: true cols [64*colg, +64)

  float b2c[4];
  #pragma unroll
  for (int nt = 0; nt < 4; ++nt) b2c[nt] = b2[(4 * colg + nt) * 16 + m];

  short8 bf1[8];
  #pragma unroll
  for (int nt = 0; nt < 8; ++nt) {
    short8 v;
    #pragma unroll
    for (int j = 0; j < 8; ++j) {
      short sj = 0;
      if (q == 0 && j < 6) sj = (short)f2bf(w1[j * NHID + nt * 16 + m]);
      else if (q == 0 && j == 6) sj = (short)f2bf(b1[nt * 16 + m]);  // bias row, k=6
      v[j] = sj;
    }
    bf1[nt] = v;
  }

  for (int idx = t; idx < 2048; idx += 512) {
    const int fg = idx >> 6, ln = idx & 63;
    const int mm = ln & 15;
    const int kc = fg >> 3, nt = fg & 7;
    short8 v;
    #pragma unroll
    for (int j = 0; j < 8; ++j) {
      const int khw = kc * 32 + (ln >> 4) * 8 + j;
      const int ctrue = ((khw & 7) << 4) | (khw >> 3);
      v[j] = (short)f2bf(w2[ctrue * NHID + nt * 16 + mm]);
    }
    w2f[idx] = v;
  }

  const int jc = t & 63;                          // u32 col in kstore order
  const int quarter = t >> 6;                     // rows [16*quarter, +16)

  const int nbt = (E + EB2 - 1) / EB2;
  __syncthreads();

  // preload first tile's index data
  int2 sv = make_int2(0, -1);
  {
    const int tile0 = blockIdx.x;
    const int gb = tile0 * EB2;
    if (t < EB2) {
      const int e = gb + t;
      if (tile0 < nbt && e < E) sv = sorted[e];
    } else if (t == EB2) {
      sv.y = (tile0 < nbt && gb > 0) ? sorted[gb - 1].y : -2;
    } else if (t == EB2 + 1) {
      sv.y = (tile0 < nbt && gb + EB2 < E) ? sorted[gb + EB2].y : -2;
    }
  }

  for (int tile = blockIdx.x; tile < nbt; tile += gridDim.x) {
    if (t < EB2) { esS[t] = sv.x; edS[t] = sv.y; }
    else if (t == EB2) pn[0] = sv.y;
    else if (t == EB2 + 1) pn[1] = sv.y;
    __syncthreads();   // A

    if (w == 0) {
      int d0 = edS[lane];
      int dp0 = (lane == 0) ? -9 : edS[lane - 1];
      unsigned long long mk0 = __ballot(lane == 0 || d0 != dp0);
      int d1 = edS[64 + lane];
      int dp1 = edS[63 + lane];
      unsigned long long mk1 = __ballot(d1 != dp1);
      if (lane == 0) { maskS[0] = mk0; maskS[1] = mk1; }
    }

    // layer 1 (zero acc init — FROZEN; bias enters via K-slot 6)
    floatx4 acc[8];
    #pragma unroll
    for (int nt = 0; nt < 8; ++nt) { floatx4 z = {0.f, 0.f, 0.f, 0.f}; acc[nt] = z; }
    short8 a1 = {0, 0, 0, 0, 0, 0, 0, 0};
    if (q == 0) {
      const int e = 16 * w + m;
      const int si = esS[e];
      const int d0 = edS[e];
      const int di = (d0 < 0) ? 0 : d0;
      float xi0 = x[di * 3], xi1 = x[di * 3 + 1], xi2 = x[di * 3 + 2];
      float dd0 = x[si * 3] - xi0, dd1 = x[si * 3 + 1] - xi1, dd2 = x[si * 3 + 2] - xi2;
      union { short8 s; uint4 u; } cv;
      cv.u = make_uint4(pkbf(xi0, xi1), pkbf(xi2, dd0), pkbf(dd1, dd2),
                        0x00003F80u);             // k=6: 1.0 (bias lane), k=7: 0
      a1 = cv.s;
    }
    #pragma unroll
    for (int nt = 0; nt < 8; ++nt)
      acc[nt] = __builtin_amdgcn_mfma_f32_16x16x32_bf16(a1, bf1[nt], acc[nt], 0, 0, 0);

    #pragma unroll
    for (int r = 0; r < 4; ++r) {
      union { short8 s; uint4 u; } cv;
      cv.u = make_uint4(
        pkbf(fmaxf(acc[0][r], 0.f), fmaxf(acc[1][r], 0.f)),
        pkbf(fmaxf(acc[2][r], 0.f), fmaxf(acc[3][r], 0.f)),
        pkbf(fmaxf(acc[4][r], 0.f), fmaxf(acc[5][r], 0.f)),
        pkbf(fmaxf(acc[6][r], 0.f), fmaxf(acc[7][r], 0.f)));
      *(short8*)(&us[(16 * w + q * 4 + r) * PADROW + m * 8]) = cv.s;
    }
    __syncthreads();   // B

    // layer 2 (zero acc init — FROZEN; bias in epilogue; R17 remap)
    #pragma unroll
    for (int nt = 0; nt < 8; ++nt) { floatx4 z = {0.f, 0.f, 0.f, 0.f}; acc[nt] = z; }
    #pragma unroll
    for (int kc = 0; kc < 4; ++kc) {
      short8 a0 = *(const short8*)(&us[(32 * rowg + m) * PADROW + kc * 32 + q * 8]);
      short8 a1r = *(const short8*)(&us[(32 * rowg + 16 + m) * PADROW + kc * 32 + q * 8]);
      #pragma unroll
      for (int nt = 0; nt < 4; ++nt) {
        short8 b = w2f[(kc * 8 + 4 * colg + nt) * 64 + lane];
        acc[nt]     = __builtin_amdgcn_mfma_f32_16x16x32_bf16(a0, b, acc[nt], 0, 0, 0);
        acc[4 + nt] = __builtin_amdgcn_mfma_f32_16x16x32_bf16(a1r, b, acc[4 + nt], 0, 0, 0);
      }
    }
    __syncthreads();   // C

    #pragma unroll
    for (int rb = 0; rb < 2; ++rb) {
      #pragma unroll
      for (int r = 0; r < 4; ++r) {
        const int row = 32 * rowg + 16 * rb + q * 4 + r;
        const int col = (m * 8 + 4 * colg) ^ (((row >> 2) & 1) << 2);  // R18 swizzle
        uint2 uu;
        uu.x = pkbf(fmaxf(acc[rb * 4 + 0][r] + b2c[0], 0.f),
                    fmaxf(acc[rb * 4 + 1][r] + b2c[1], 0.f));
        uu.y = pkbf(fmaxf(acc[rb * 4 + 2][r] + b2c[2], 0.f),
                    fmaxf(acc[rb * 4 + 3][r] + b2c[3], 0.f));
        *(uint2*)(&us[row * PADROW + col]) = uu;
      }
    }
    __syncthreads();   // D: hS ready

    // prefetch next tile's index data
    {
      const int tn = tile + gridDim.x;
      const int gb = tn * EB2;
      int2 nv = make_int2(0, -1);
      if (t < EB2) {
        const int e = gb + t;
        if (tn < nbt && e < E) nv = sorted[e];
      } else if (t == EB2) {
        nv.y = (tn < nbt && gb > 0) ? sorted[gb - 1].y : -2;
      } else if (t == EB2 + 1) {
        nv.y = (tn < nbt && gb + EB2 < E) ? sorted[gb + EB2].y : -2;
      }
      sv = nv;
    }

    // stage 3 pass 1: per-quarter partials; contained runs stored directly
    int os = -1, onxt = 0, od = -1; unsigned int opart = 0;
    {
      const unsigned long long mk0 = maskS[0], mk1 = maskS[1];
      const int prevd = pn[0], nextd = pn[1];
      const int r0 = quarter * 16, r1 = r0 + 16;
      const unsigned int* us32 = (const unsigned int*)us;
      int s;
      if (r0 < 64) {
        s = 63 - __builtin_clzll(mk0 & (~0ULL >> (63 - r0)));
      } else {
        unsigned long long hm = mk1 & (~0ULL >> (127 - r0));
        s = hm ? 127 - __builtin_clzll(hm) : 63 - __builtin_clzll(mk0);
      }
      while (s < r1) {
        int nxt;
        if (s < 63) {
          unsigned long long ab = mk0 & (~0ULL << (s + 1));
          if (ab) nxt = __builtin_ffsll((long long)ab) - 1;
          else    nxt = mk1 ? 64 + __builtin_ffsll((long long)mk1) - 1 : 128;
        } else if (s == 63) {
          nxt = mk1 ? 64 + __builtin_ffsll((long long)mk1) - 1 : 128;
        } else if (s < 127) {
          unsigned long long ab = mk1 & (~0ULL << (s - 63));
          nxt = ab ? 64 + __builtin_ffsll((long long)ab) - 1 : 128;
        } else nxt = 128;

        const int lo = (s > r0) ? s : r0;
        const int hi = (nxt < r1) ? nxt : r1;
        unsigned int run = 0;
        for (int r = lo; r < hi; ++r)
          run = pkmax(run, us32[r * (PADROW >> 1) + (jc ^ (((r >> 2) & 1) << 1))]);

        if (s < r0) {
          pmS[quarter][jc] = run;                 // run covering this quarter's r0
        } else if (nxt <= r1) {
          const int d = edS[s];
          if (d >= 0) {
            const bool bnd = (s == 0 && prevd == d) || (nxt == 128 && nextd == d);
            unsigned int* ap = aggu + (size_t)d * 64 + jc;
            if (!bnd) *ap = run;
            else if (run) casmax(ap, run);
          }
        } else {                                  // owner of a spanning run
          os = s; onxt = nxt; od = edS[s]; opart = run;
        }
        s = nxt;
      }
    }
    __syncthreads();   // E: pmS ready

    // stage 3 pass 2: owners combine partials and write once
    if (os >= 0 && od >= 0) {
      const int endq = (onxt - 1) >> 4;
      #pragma unroll 4
      for (int qq = quarter + 1; qq <= endq; ++qq)
        opart = pkmax(opart, pmS[qq][jc]);
      const bool bnd = (os == 0 && pn[0] == od) || (onxt == 128 && pn[1] == od);
      unsigned int* ap = aggu + (size_t)od * 64 + jc;
      if (!bnd) *ap = opart;
      else if (opart) casmax(ap, opart);
    }
    __syncthreads();   // F
  }
}

// ---------------- fallback: atomic edge kernel (small ws) ----------------

__global__ __launch_bounds__(256, 2) void edge_atomic_kernel(
    const float* __restrict__ x, const int* __restrict__ ei,
    const float* __restrict__ w1, const float* __restrict__ b1,
    const float* __restrict__ w2, const float* __restrict__ b2,
    unsigned int* aggu, const int* __restrict__ flag64, int N, int E) {
  __shared__ unsigned short uA[EB * PADROW];
  __shared__ float w1s[6 * NHID];
  __shared__ float b1s[NHID], b2s[NHID];
  __shared__ int es[EB], ed[EB];

  const int t = threadIdx.x;
  const int lane = t & 63;
  const int w = t >> 6;
  const int m = lane & 15;
  const int q = lane >> 4;

  for (int i = t; i < 6 * NHID; i += 256) w1s[i] = w1[i];
  if (t < NHID) { b1s[t] = b1[t]; b2s[t] = b2[t]; }

  short8 bf[32];
  load_bfrags(w2, bf, m, q);

  const bool is64 = (flag64[0] != 0);
  const int nb = (E + EB - 1) / EB;

  for (int batch = blockIdx.x; batch < nb; batch += gridDim.x) {
    const int gbase = batch * EB;
    if (t < EB) {
      int e = gbase + t;
      es[t] = (e < E) ? (is64 ? ei[2 * e] : ei[e]) : 0;
    } else if (t < 2 * EB) {
      int tt = t - EB;
      int e = gbase + tt;
      ed[tt] = (e < E) ? (is64 ? ei[2 * E + 2 * e] : ei[E + e]) : 0;
    }
    __syncthreads();
    {
      const int e = t >> 2;
      const int c0 = (t & 3) * 32;
      const int si = es[e], di = ed[e];
      float xi0 = x[di * 3], xi1 = x[di * 3 + 1], xi2 = x[di * 3 + 2];
      float msg[6];
      msg[0] = xi0; msg[1] = xi1; msg[2] = xi2;
      msg[3] = x[si * 3] - xi0; msg[4] = x[si * 3 + 1] - xi1; msg[5] = x[si * 3 + 2] - xi2;
      unsigned int* d32 = (unsigned int*)uA;
      const int base32 = (e * PADROW + c0) >> 1;
      #pragma unroll
      for (int cc = 0; cc < 32; cc += 2) {
        float u0 = b1s[c0 + cc], u1 = b1s[c0 + cc + 1];
        #pragma unroll
        for (int d = 0; d < 6; ++d) {
          u0 += msg[d] * w1s[d * NHID + c0 + cc];
          u1 += msg[d] * w1s[d * NHID + c0 + cc + 1];
        }
        d32[base32 + (cc >> 1)] = pack2(fmaxf(u0, 0.f), fmaxf(u1, 0.f));
      }
    }
    __syncthreads();

    floatx4 acc[8];
    #pragma unroll
    for (int nt = 0; nt < 8; ++nt) { floatx4 z = {0.f, 0.f, 0.f, 0.f}; acc[nt] = z; }
    mfma_block(uA, bf, acc, w, m, q);

    #pragma unroll
    for (int nt = 0; nt < 8; ++nt) {
      const int c = nt * 16 + m;
      const float bb = b2s[c];
      const int kst = m * 8 + nt;
      #pragma unroll
      for (int r = 0; r < 4; ++r) {
        const int erow = 16 * w + q * 4 + r;
        if (gbase + erow < E) {
          float hb = acc[nt][r] + bb;
          if (hb > 0.f) {
            unsigned int v = (unsigned int)f2bf(hb);
            casmax(aggu + (size_t)ed[erow] * 64 + (kst >> 1), v << (16 * (kst & 1)));
          }
        }
      }
    }
    __syncthreads();
  }
}

// ---------------- fused node MLPs: enc (w3) + dec (w4,w5), agg16 input ----------------
// R9 structure (barriers B0/B1/B2/B3) — R10's barrier removal regressed.
// R15 lesson applies here too: acc zero-init FROZEN (bias in epilogue).

__global__ __launch_bounds__(256, 2) void encdec_kernel(
    const float* __restrict__ w3, const float* __restrict__ b3,
    const float* __restrict__ w4, const float* __restrict__ b4,
    const float* __restrict__ w5, const float* __restrict__ b5,
    const float* __restrict__ pos, const unsigned short* __restrict__ agg16,
    float* __restrict__ out, int N) {
  __shared__ unsigned short uA[EB * PADROW];
  __shared__ short8 w4f[2048];                    // k-permuted w4 frags
  __shared__ float w5s[NHID * 3];

  const int t = threadIdx.x;
  const int lane = t & 63;
  const int w = t >> 6;
  const int m = lane & 15;
  const int q = lane >> 4;

  float b3c[8], b4c[8];
  #pragma unroll
  for (int nt = 0; nt < 8; ++nt) { b3c[nt] = b3[nt * 16 + m]; b4c[nt] = b4[nt * 16 + m]; }

  short8 bf3[32];
  load_bfrags_perm(w3, bf3, m, q);                // k-permuted (agg16 is kstore-ordered)

  for (int idx = t; idx < 2048; idx += 256) {
    const int fg = idx >> 6, ln = idx & 63;
    const int mm = ln & 15;
    const int kc = fg >> 3, nt = fg & 7;
    short8 v;
    #pragma unroll
    for (int j = 0; j < 8; ++j) {
      const int khw = kc * 32 + (ln >> 4) * 8 + j;
      const int ctrue = ((khw & 7) << 4) | (khw >> 3);
      v[j] = (short)f2bf(w4[ctrue * NHID + nt * 16 + mm]);
    }
    w4f[idx] = v;
  }
  for (int i = t; i < NHID * 3; i += 256) w5s[i] = w5[i];
  const float b50 = b5[0], b51 = b5[1], b52 = b5[2];

  const int ch = t & 15;
  const int rr = t >> 4;
  const int nb = (N + EB - 1) / EB;
  __syncthreads();

  uint4 rv[4];
  const uint4 uz = make_uint4(0u, 0u, 0u, 0u);
  {
    const int b0 = blockIdx.x;
    #pragma unroll
    for (int k = 0; k < 4; ++k) {
      const int node = b0 * EB + rr + 16 * k;
      rv[k] = (b0 < nb && node < N) ? ((const uint4*)agg16)[(size_t)node * 16 + ch] : uz;
    }
  }

  for (int batch = blockIdx.x; batch < nb; batch += gridDim.x) {
    const int base = batch * EB;
    #pragma unroll
    for (int k = 0; k < 4; ++k)
      *(uint4*)(&uA[(rr + 16 * k) * PADROW + ch * 8]) = rv[k];
    __syncthreads();   // B0

    {
      const int nxb = batch + gridDim.x;
      #pragma unroll
      for (int k = 0; k < 4; ++k) {
        const int node = nxb * EB + rr + 16 * k;
        rv[k] = (nxb < nb && node < N) ? ((const uint4*)agg16)[(size_t)node * 16 + ch] : uz;
      }
    }

    floatx4 acc[8];
    #pragma unroll
    for (int nt = 0; nt < 8; ++nt) { floatx4 z = {0.f, 0.f, 0.f, 0.f}; acc[nt] = z; }
    mfma_block(uA, bf3, acc, w, m, q);
    __syncthreads();   // B1

    #pragma unroll
    for (int r = 0; r < 4; ++r) {
      union { short8 s; uint4 u; } cv;
      cv.u = make_uint4(
        pkbf(acc[0][r] + b3c[0], acc[1][r] + b3c[1]),
        pkbf(acc[2][r] + b3c[2], acc[3][r] + b3c[3]),
        pkbf(acc[4][r] + b3c[4], acc[5][r] + b3c[5]),
        pkbf(acc[6][r] + b3c[6], acc[7][r] + b3c[7]));
      *(short8*)(&uA[(16 * w + q * 4 + r) * PADROW + m * 8]) = cv.s;
    }
    __syncthreads();   // B2

    #pragma unroll
    for (int nt = 0; nt < 8; ++nt) { floatx4 z = {0.f, 0.f, 0.f, 0.f}; acc[nt] = z; }
    #pragma unroll
    for (int kc = 0; kc < 4; ++kc) {
      short8 a = *(const short8*)(&uA[(16 * w + m) * PADROW + kc * 32 + q * 8]);
      #pragma unroll
      for (int nt = 0; nt < 8; ++nt)
        acc[nt] = __builtin_amdgcn_mfma_f32_16x16x32_bf16(a, w4f[(kc * 8 + nt) * 64 + lane],
                                                          acc[nt], 0, 0, 0);
    }

    float p[4][3];
    #pragma unroll
    for (int r = 0; r < 4; ++r) { p[r][0] = 0.f; p[r][1] = 0.f; p[r][2] = 0.f; }
    #pragma unroll
    for (int nt = 0; nt < 8; ++nt) {
      const int c = nt * 16 + m;
      const float bb = b4c[nt];
      const float w50 = w5s[c * 3], w51 = w5s[c * 3 + 1], w52 = w5s[c * 3 + 2];
      #pragma unroll
      for (int r = 0; r < 4; ++r) {
        float tv = fmaxf(acc[nt][r] + bb, 0.f);
        p[r][0] += tv * w50; p[r][1] += tv * w51; p[r][2] += tv * w52;
      }
    }
    #pragma unroll
    for (int off = 8; off >= 1; off >>= 1) {
      #pragma unroll
      for (int r = 0; r < 4; ++r) {
        p[r][0] += __shfl_xor(p[r][0], off, 16);
        p[r][1] += __shfl_xor(p[r][1], off, 16);
        p[r][2] += __shfl_xor(p[r][2], off, 16);
      }
    }
    if (m == 0) {
      #pragma unroll
      for (int r = 0; r < 4; ++r) {
        const int node = base + 16 * w + q * 4 + r;
        if (node < N) {
          out[node * 3]     = pos[node * 3]     + 0.1f * tanhf(p[r][0] + b50);
          out[node * 3 + 1] = pos[node * 3 + 1] + 0.1f * tanhf(p[r][1] + b51);
          out[node * 3 + 2] = pos[node * 3 + 2] + 0.1f * tanhf(p[r][2] + b52);
        }
      }
    }
    __syncthreads();   // B3
  }
}

extern "C" void kernel_launch(void* const* d_in, const int* in_sizes, int n_in,
                              void* d_out, int out_size, void* d_ws, size_t ws_size,
                              hipStream_t stream) {
  const float* x   = (const float*)d_in[0];
  const float* pos = (const float*)d_in[1];
  const int*   ei  = (const int*)d_in[2];
  const float* w1  = (const float*)d_in[3];
  const float* b1  = (const float*)d_in[4];
  const float* w2  = (const float*)d_in[5];
  const float* b2  = (const float*)d_in[6];
  const float* w3  = (const float*)d_in[7];
  const float* b3  = (const float*)d_in[8];
  const float* w4  = (const float*)d_in[9];
  const float* b4  = (const float*)d_in[10];
  const float* w5  = (const float*)d_in[11];
  const float* b5  = (const float*)d_in[12];
  float* out = (float*)d_out;

  const int N = in_sizes[0] / 3;
  const int E = in_sizes[2] / 2;
  const int nbuck = (N + 255) >> 8;

  char* ws = (char*)d_ws;
  unsigned short* agg16 = (unsigned short*)ws;                // N*128 u16 (kstore order)
  const size_t aggB = (size_t)N * NHID * sizeof(unsigned short);
  int2* mid    = (int2*)(ws + aggB);
  int2* sorted = (int2*)(ws + aggB + (size_t)E * 8);
  int*  mat    = (int*)(ws + aggB + (size_t)E * 16);
  int*  btot   = mat + (size_t)nbuck * PB;
  int*  bstart = btot + nbuck;
  const size_t needed = aggB + (size_t)E * 16 + ((size_t)nbuck * PB + nbuck + 520) * 4;

  if (ws_size >= needed && nbuck <= 511 && E >= 64) {
    part_hist<<<2048, 256, 0, stream>>>(ei, mat, E, nbuck, (float4*)agg16, N * 16);
    scan_rows<<<nbuck, 256, 0, stream>>>(mat, btot, nbuck);
    part_scatter<<<PB, 512, 0, stream>>>(ei, mat, btot, bstart, mid, E, nbuck);
    bucket_sort<<<nbuck, 512, 0, stream>>>(mid, bstart, sorted);
    edge_sorted_kernel<<<512, 512, 0, stream>>>(x, sorted, w1, b1, w2, b2,
                                                (unsigned int*)agg16, N, E);
  } else {
    int* flag2 = (int*)(ws + aggB);
    zero_detect_kernel<<<2048, 256, 0, stream>>>((float4*)agg16, N * 16, ei, flag2);
    edge_atomic_kernel<<<512, 256, 0, stream>>>(x, ei, w1, b1, w2, b2,
                                                (unsigned int*)agg16, flag2, N, E);
  }
  encdec_kernel<<<512, 256, 0, stream>>>(w3, b3, w4, b4, w5, b5, pos, agg16, out, N);
}

// Round 6
// 334.336 us; speedup vs baseline: 1.0311x; 1.0311x over previous
//
#include <hip/hip_runtime.h>
#include <hip/hip_bf16.h>

typedef __attribute__((ext_vector_type(8))) short short8;
typedef __attribute__((ext_vector_type(4))) float floatx4;
typedef __attribute__((ext_vector_type(2))) unsigned short ushortx2;

#define NHID 128
#define PADROW 136   // u16 row stride: 272B, 16B-aligned b128, benign banking
#define EB 64        // nodes per tile (encdec / fallback)
#define EB2 128      // edges per tile (edge_sorted)
#define PB 256       // partition blocks for the 2-level sort

__device__ __forceinline__ unsigned short f2bf(float x) {
  unsigned int u = __float_as_uint(x);
  u += 0x7FFFu + ((u >> 16) & 1u);          // RNE
  return (unsigned short)(u >> 16);
}

__device__ __forceinline__ unsigned int pkbf(float a, float b) {
  __hip_bfloat162 h = __float22bfloat162_rn(make_float2(a, b));
  union { __hip_bfloat162 h; unsigned int u; } cv;
  cv.h = h;
  return cv.u;
}

__device__ __forceinline__ unsigned int pack2(float a, float b) {
  return (unsigned int)f2bf(a) | ((unsigned int)f2bf(b) << 16);
}

// packed u16 max (v_pk_max_u16)
__device__ __forceinline__ unsigned int pkmax(unsigned int a, unsigned int b) {
  union { unsigned int u; ushortx2 v; } x, y;
  x.u = a; y.u = b;
  x.v = __builtin_elementwise_max(x.v, y.v);
  return x.u;
}

__device__ __forceinline__ void casmax(unsigned int* ap, unsigned int run) {
  unsigned int old = *ap;
  while (true) {
    unsigned int mx = pkmax(old, run);
    if (mx == old) break;
    unsigned int got = atomicCAS(ap, old, mx);
    if (got == old) break;
    old = got;
  }
}

// all-wave inline int64 probe: odd int32 slots all-zero <=> int64 edge_index
__device__ __forceinline__ bool detect64(const int* __restrict__ ei) {
  unsigned long long b = __ballot(ei[2 * (threadIdx.x & 63) + 1] != 0);
  return b == 0ULL;
}

// 32 loop-invariant B-fragments of a 128x128 row-major f32 weight (registers), natural k.
__device__ __forceinline__ void load_bfrags(const float* __restrict__ wmat,
                                            short8* bf, int m, int q) {
  #pragma unroll
  for (int kc = 0; kc < 4; ++kc) {
    #pragma unroll
    for (int nt = 0; nt < 8; ++nt) {
      short8 v;
      #pragma unroll
      for (int j = 0; j < 8; ++j)
        v[j] = (short)f2bf(wmat[(kc * 32 + q * 8 + j) * NHID + nt * 16 + m]);
      bf[kc * 8 + nt] = v;
    }
  }
}

// same but k-permuted: B[khw][n] = w[pi(khw)][n], pi(k) = ((k&7)<<4)|(k>>3)
__device__ __forceinline__ void load_bfrags_perm(const float* __restrict__ wmat,
                                                 short8* bf, int m, int q) {
  #pragma unroll
  for (int kc = 0; kc < 4; ++kc) {
    #pragma unroll
    for (int nt = 0; nt < 8; ++nt) {
      short8 v;
      #pragma unroll
      for (int j = 0; j < 8; ++j) {
        const int khw = kc * 32 + q * 8 + j;
        const int ctrue = ((khw & 7) << 4) | (khw >> 3);
        v[j] = (short)f2bf(wmat[ctrue * NHID + nt * 16 + m]);
      }
      bf[kc * 8 + nt] = v;
    }
  }
}

__device__ __forceinline__ void mfma_block(const unsigned short* uA,
                                           const short8* bf, floatx4* acc,
                                           int w, int m, int q) {
  #pragma unroll
  for (int kc = 0; kc < 4; ++kc) {
    short8 a = *(const short8*)(uA + (16 * w + m) * PADROW + kc * 32 + q * 8);
    #pragma unroll
    for (int nt = 0; nt < 8; ++nt)
      acc[nt] = __builtin_amdgcn_mfma_f32_16x16x32_bf16(a, bf[kc * 8 + nt],
                                                        acc[nt], 0, 0, 0);
  }
}

// fallback-path zero (agg16) + detect->flag
__global__ void zero_detect_kernel(float4* __restrict__ p, int n4,
                                   const int* __restrict__ ei, int* __restrict__ flag) {
  if (blockIdx.x == 0 && threadIdx.x < 64) {
    unsigned long long b = __ballot(ei[2 * threadIdx.x + 1] != 0);
    if (threadIdx.x == 0) flag[0] = (b == 0ULL) ? 1 : 0;
  }
  int i = blockIdx.x * blockDim.x + threadIdx.x;
  int stride = gridDim.x * blockDim.x;
  float4 z = make_float4(0.f, 0.f, 0.f, 0.f);
  for (; i < n4; i += stride) p[i] = z;
}

// ---------------- 2-level counting sort by dst (no global atomics) ----------------
// Split pipeline (R11): grid-barrier fusion regressed badly (R12: 230 µs @ 4 waves/CU;
// R13: 570 µs @ 16 waves/CU — global phase lockstep + hot counter line, not occupancy).

// A1: per-partition LDS histogram over coarse buckets (dst>>8); tail blocks zero agg16
__global__ __launch_bounds__(256) void part_hist(const int* __restrict__ ei,
                                                 int* __restrict__ mat, int E, int nbuck,
                                                 float4* __restrict__ aggz, int n4) {
  const int bl = blockIdx.x, t = threadIdx.x;
  if (bl >= PB) {
    int i = (bl - PB) * 256 + t;
    const int st = (gridDim.x - PB) * 256;
    float4 z = make_float4(0.f, 0.f, 0.f, 0.f);
    for (; i < n4; i += st) aggz[i] = z;
    return;
  }
  __shared__ int hist[512];
  const bool is64 = detect64(ei);
  for (int i = t; i < nbuck; i += 256) hist[i] = 0;
  __syncthreads();
  const int chunk = (E + PB - 1) / PB;
  const int lo = bl * chunk;
  const int hi = min(lo + chunk, E);
  for (int i = lo + t; i < hi; i += 256) {
    int d = is64 ? ei[2 * E + 2 * i] : ei[E + i];
    atomicAdd(&hist[d >> 8], 1);
  }
  __syncthreads();
  for (int bu = t; bu < nbuck; bu += 256) mat[bu * PB + bl] = hist[bu];
}

// A2: per-bucket exclusive scan over the PB partitions (in place) + bucket totals
__global__ __launch_bounds__(256) void scan_rows(int* __restrict__ mat,
                                                 int* __restrict__ btot, int nbuck) {
  __shared__ int sh[256];
  const int bu = blockIdx.x, t = threadIdx.x;
  const int v = mat[bu * PB + t];
  sh[t] = v;
  __syncthreads();
  for (int off = 1; off < 256; off <<= 1) {
    int x = (t >= off) ? sh[t - off] : 0;
    __syncthreads();
    sh[t] += x;
    __syncthreads();
  }
  mat[bu * PB + t] = sh[t] - v;
  if (t == 255) btot[bu] = sh[255];
}

// A3: scatter into coarse-bucket regions; bucket starts scanned in-LDS from btot.
// 512 threads (was 256): 256-block grid is only ~4 waves/CU at 256 thr — latency-
// starved (R12 lesson). Scan section guarded to t<256 (pattern validated in R13).
__global__ __launch_bounds__(512) void part_scatter(const int* __restrict__ ei,
                                                    const int* __restrict__ mat,
                                                    const int* __restrict__ btot,
                                                    int* __restrict__ bstart,
                                                    int2* __restrict__ mid, int E, int nbuck) {
  __shared__ int off[512];
  __shared__ int bsS[512];
  const bool is64 = detect64(ei);
  const int bl = blockIdx.x, t = threadIdx.x;
  const int o0 = (t < 256 && t < nbuck) ? btot[t] : 0;
  const int o1 = (t < 256 && t + 256 < nbuck) ? btot[t + 256] : 0;
  if (t < 256) { bsS[t] = o0; bsS[t + 256] = o1; }
  __syncthreads();
  for (int o = 1; o < 256; o <<= 1) {
    int x0 = (t >= o && t < 256) ? bsS[t - o] : 0;
    int x1 = (t >= o && t < 256) ? bsS[256 + t - o] : 0;
    __syncthreads();
    if (t < 256) { bsS[t] += x0; bsS[256 + t] += x1; }
    __syncthreads();
  }
  const int tot0 = bsS[255];
  if (t < 256) bsS[256 + t] += tot0;
  __syncthreads();
  if (t < 256) {
    const int ex0 = bsS[t] - o0;
    const int ex1 = bsS[256 + t] - o1;
    if (bl == 0) { bstart[t] = ex0; bstart[256 + t] = ex1; }
    off[t]       = ex0 + ((t < nbuck) ? mat[t * PB + bl] : 0);
    off[256 + t] = ex1 + ((t + 256 < nbuck) ? mat[(t + 256) * PB + bl] : 0);
  }
  __syncthreads();
  const int chunk = (E + PB - 1) / PB;
  const int lo = bl * chunk;
  const int hi = min(lo + chunk, E);
  for (int i = lo + t; i < hi; i += 512) {
    int s = is64 ? ei[2 * i]         : ei[i];
    int d = is64 ? ei[2 * E + 2 * i] : ei[E + i];
    int p = atomicAdd(&off[d >> 8], 1);
    mid[p] = make_int2(s, d);
  }
}

// B: per-bucket counting sort by exact dst (256 local nodes), L2-resident traffic.
// 512 threads (was 256) for the same latency-starvation reason.
__global__ __launch_bounds__(512) void bucket_sort(const int2* __restrict__ mid,
                                                   const int* __restrict__ bstart,
                                                   int2* __restrict__ sorted) {
  __shared__ int h[256], cnt[256];
  const int bu = blockIdx.x, t = threadIdx.x;
  const int lo = bstart[bu], hi = bstart[bu + 1];
  if (t < 256) { h[t] = 0; cnt[t] = 0; }
  __syncthreads();
  for (int i = lo + t; i < hi; i += 512) atomicAdd(&h[mid[i].y & 255], 1);
  __syncthreads();
  const int v = (t < 256) ? h[t] : 0;
  for (int off = 1; off < 256; off <<= 1) {
    int x = (t >= off && t < 256) ? h[t - off] : 0;
    __syncthreads();
    if (t < 256) h[t] += x;
    __syncthreads();
  }
  const int excl = (t < 256) ? h[t] - v : 0;
  __syncthreads();
  if (t < 256) h[t] = excl;
  __syncthreads();
  for (int i = lo + t; i < hi; i += 512) {
    int2 e = mid[i];
    const int dl = e.y & 255;
    const int p = lo + h[dl] + atomicAdd(&cnt[dl], 1);
    sorted[p] = e;
  }
}

// ---------------- fused edge MLP (both layers MFMA) + segmented max ----------------
// R9 structure: barrier lockstep is a beneficial scheduling fence — R10's bulk
// barrier removal raised VGPR 60->92 and regressed.
// FROZEN RULES (R10/R14/R15): acc MUST be zero-init (bias-splat C-init hoists 32
// loop-invariant VGPRs -> crosses 128 residency bucket -> occupancy halves).
// R16 (kept): layer-1 bias via spare K-slot — A k=6 := 1.0, B row j=6 := b1.
// R17 (kept): layer-2 wave remap — wave owns 32 rows (rowg=w>>1) x 64 true cols
// (colg=w&1); 36->24 b128/thread/tile. uint2 hS stores.
// R18 REVERTED: store bank-swizzle — SQ_LDS_BANK_CONFLICT unchanged (exactly 6.4M
// = 4/edge both ways) and time +3%. The counter here records structural 2-way
// aliasing phases of wave64 b128/b64 LDS ops (free in time, m136), NOT stalls.
// Do not chase this counter on this kernel.
// R19: barrier F removed with prevd/nextd register-captured in pass 1. Safety:
// after barrier E, stragglers touch only pmS + captured regs; fast waves' loop-top
// esS/edS/pn writes are dead to pass-2, and their next pmS write sits behind the
// next tile's A..D barrier chain (they can't pass A while a wave is in pass 2).
// 5 barriers/tile (A/B/C/D/E).
// agg16: u16[N][128] in kstore (k-permuted) order. Stage-3: two-pass LDS run merge.

__global__ __launch_bounds__(512, 2) void edge_sorted_kernel(
    const float* __restrict__ x, const int2* __restrict__ sorted,
    const float* __restrict__ w1, const float* __restrict__ b1,
    const float* __restrict__ w2, const float* __restrict__ b2,
    unsigned int* aggu, int N, int E) {
  __shared__ unsigned short us[EB2 * PADROW];     // uA then hS (bf16)
  __shared__ short8 w2f[2048];                    // 32 frags x 64 lanes, k-permuted
  __shared__ int esS[EB2], edS[EB2];
  __shared__ int pn[2];                           // dst before / after tile (-2 = none)
  __shared__ unsigned long long maskS[2];         // run-start bitmask
  __shared__ unsigned int pmS[8][64];             // per-quarter partial of run covering r0

  const int t = threadIdx.x;
  const int lane = t & 63;
  const int w = t >> 6;                           // wave 0..7
  const int m = lane & 15;
  const int q = lane >> 4;
  const int rowg = w >> 1;                        // layer-2: rows [32*rowg, +32)
  const int colg = w & 1;                         // layer-2: true cols [64*colg, +64)

  float b2c[4];
  #pragma unroll
  for (int nt = 0; nt < 4; ++nt) b2c[nt] = b2[(4 * colg + nt) * 16 + m];

  short8 bf1[8];
  #pragma unroll
  for (int nt = 0; nt < 8; ++nt) {
    short8 v;
    #pragma unroll
    for (int j = 0; j < 8; ++j) {
      short sj = 0;
      if (q == 0 && j < 6) sj = (short)f2bf(w1[j * NHID + nt * 16 + m]);
      else if (q == 0 && j == 6) sj = (short)f2bf(b1[nt * 16 + m]);  // bias row, k=6
      v[j] = sj;
    }
    bf1[nt] = v;
  }

  for (int idx = t; idx < 2048; idx += 512) {
    const int fg = idx >> 6, ln = idx & 63;
    const int mm = ln & 15;
    const int kc = fg >> 3, nt = fg & 7;
    short8 v;
    #pragma unroll
    for (int j = 0; j < 8; ++j) {
      const int khw = kc * 32 + (ln >> 4) * 8 + j;
      const int ctrue = ((khw & 7) << 4) | (khw >> 3);
      v[j] = (short)f2bf(w2[ctrue * NHID + nt * 16 + mm]);
    }
    w2f[idx] = v;
  }

  const int jc = t & 63;                          // u32 col in kstore order
  const int quarter = t >> 6;                     // rows [16*quarter, +16)

  const int nbt = (E + EB2 - 1) / EB2;
  __syncthreads();

  // preload first tile's index data
  int2 sv = make_int2(0, -1);
  {
    const int tile0 = blockIdx.x;
    const int gb = tile0 * EB2;
    if (t < EB2) {
      const int e = gb + t;
      if (tile0 < nbt && e < E) sv = sorted[e];
    } else if (t == EB2) {
      sv.y = (tile0 < nbt && gb > 0) ? sorted[gb - 1].y : -2;
    } else if (t == EB2 + 1) {
      sv.y = (tile0 < nbt && gb + EB2 < E) ? sorted[gb + EB2].y : -2;
    }
  }

  for (int tile = blockIdx.x; tile < nbt; tile += gridDim.x) {
    if (t < EB2) { esS[t] = sv.x; edS[t] = sv.y; }
    else if (t == EB2) pn[0] = sv.y;
    else if (t == EB2 + 1) pn[1] = sv.y;
    __syncthreads();   // A

    if (w == 0) {
      int d0 = edS[lane];
      int dp0 = (lane == 0) ? -9 : edS[lane - 1];
      unsigned long long mk0 = __ballot(lane == 0 || d0 != dp0);
      int d1 = edS[64 + lane];
      int dp1 = edS[63 + lane];
      unsigned long long mk1 = __ballot(d1 != dp1);
      if (lane == 0) { maskS[0] = mk0; maskS[1] = mk1; }
    }

    // layer 1 (zero acc init — FROZEN; bias enters via K-slot 6)
    floatx4 acc[8];
    #pragma unroll
    for (int nt = 0; nt < 8; ++nt) { floatx4 z = {0.f, 0.f, 0.f, 0.f}; acc[nt] = z; }
    short8 a1 = {0, 0, 0, 0, 0, 0, 0, 0};
    if (q == 0) {
      const int e = 16 * w + m;
      const int si = esS[e];
      const int d0 = edS[e];
      const int di = (d0 < 0) ? 0 : d0;
      float xi0 = x[di * 3], xi1 = x[di * 3 + 1], xi2 = x[di * 3 + 2];
      float dd0 = x[si * 3] - xi0, dd1 = x[si * 3 + 1] - xi1, dd2 = x[si * 3 + 2] - xi2;
      union { short8 s; uint4 u; } cv;
      cv.u = make_uint4(pkbf(xi0, xi1), pkbf(xi2, dd0), pkbf(dd1, dd2),
                        0x00003F80u);             // k=6: 1.0 (bias lane), k=7: 0
      a1 = cv.s;
    }
    #pragma unroll
    for (int nt = 0; nt < 8; ++nt)
      acc[nt] = __builtin_amdgcn_mfma_f32_16x16x32_bf16(a1, bf1[nt], acc[nt], 0, 0, 0);

    #pragma unroll
    for (int r = 0; r < 4; ++r) {
      union { short8 s; uint4 u; } cv;
      cv.u = make_uint4(
        pkbf(fmaxf(acc[0][r], 0.f), fmaxf(acc[1][r], 0.f)),
        pkbf(fmaxf(acc[2][r], 0.f), fmaxf(acc[3][r], 0.f)),
        pkbf(fmaxf(acc[4][r], 0.f), fmaxf(acc[5][r], 0.f)),
        pkbf(fmaxf(acc[6][r], 0.f), fmaxf(acc[7][r], 0.f)));
      *(short8*)(&us[(16 * w + q * 4 + r) * PADROW + m * 8]) = cv.s;
    }
    __syncthreads();   // B

    // layer 2 (zero acc init — FROZEN; bias in epilogue; R17 remap)
    #pragma unroll
    for (int nt = 0; nt < 8; ++nt) { floatx4 z = {0.f, 0.f, 0.f, 0.f}; acc[nt] = z; }
    #pragma unroll
    for (int kc = 0; kc < 4; ++kc) {
      short8 a0 = *(const short8*)(&us[(32 * rowg + m) * PADROW + kc * 32 + q * 8]);
      short8 a1r = *(const short8*)(&us[(32 * rowg + 16 + m) * PADROW + kc * 32 + q * 8]);
      #pragma unroll
      for (int nt = 0; nt < 4; ++nt) {
        short8 b = w2f[(kc * 8 + 4 * colg + nt) * 64 + lane];
        acc[nt]     = __builtin_amdgcn_mfma_f32_16x16x32_bf16(a0, b, acc[nt], 0, 0, 0);
        acc[4 + nt] = __builtin_amdgcn_mfma_f32_16x16x32_bf16(a1r, b, acc[4 + nt], 0, 0, 0);
      }
    }
    __syncthreads();   // C

    #pragma unroll
    for (int rb = 0; rb < 2; ++rb) {
      #pragma unroll
      for (int r = 0; r < 4; ++r) {
        uint2 uu;
        uu.x = pkbf(fmaxf(acc[rb * 4 + 0][r] + b2c[0], 0.f),
                    fmaxf(acc[rb * 4 + 1][r] + b2c[1], 0.f));
        uu.y = pkbf(fmaxf(acc[rb * 4 + 2][r] + b2c[2], 0.f),
                    fmaxf(acc[rb * 4 + 3][r] + b2c[3], 0.f));
        *(uint2*)(&us[(32 * rowg + 16 * rb + q * 4 + r) * PADROW + m * 8 + 4 * colg]) = uu;
      }
    }
    __syncthreads();   // D: hS ready

    // prefetch next tile's index data
    {
      const int tn = tile + gridDim.x;
      const int gb = tn * EB2;
      int2 nv = make_int2(0, -1);
      if (t < EB2) {
        const int e = gb + t;
        if (tn < nbt && e < E) nv = sorted[e];
      } else if (t == EB2) {
        nv.y = (tn < nbt && gb > 0) ? sorted[gb - 1].y : -2;
      } else if (t == EB2 + 1) {
        nv.y = (tn < nbt && gb + EB2 < E) ? sorted[gb + EB2].y : -2;
      }
      sv = nv;
    }

    // stage 3 pass 1: per-quarter partials; contained runs stored directly.
    // prevd/nextd captured to registers (R19): pass 2 must not touch pn[].
    int os = -1, onxt = 0, od = -1; unsigned int opart = 0;
    int prevd, nextd;
    {
      const unsigned long long mk0 = maskS[0], mk1 = maskS[1];
      prevd = pn[0]; nextd = pn[1];
      const int r0 = quarter * 16, r1 = r0 + 16;
      const unsigned int* us32 = (const unsigned int*)us;
      int s;
      if (r0 < 64) {
        s = 63 - __builtin_clzll(mk0 & (~0ULL >> (63 - r0)));
      } else {
        unsigned long long hm = mk1 & (~0ULL >> (127 - r0));
        s = hm ? 127 - __builtin_clzll(hm) : 63 - __builtin_clzll(mk0);
      }
      while (s < r1) {
        int nxt;
        if (s < 63) {
          unsigned long long ab = mk0 & (~0ULL << (s + 1));
          if (ab) nxt = __builtin_ffsll((long long)ab) - 1;
          else    nxt = mk1 ? 64 + __builtin_ffsll((long long)mk1) - 1 : 128;
        } else if (s == 63) {
          nxt = mk1 ? 64 + __builtin_ffsll((long long)mk1) - 1 : 128;
        } else if (s < 127) {
          unsigned long long ab = mk1 & (~0ULL << (s - 63));
          nxt = ab ? 64 + __builtin_ffsll((long long)ab) - 1 : 128;
        } else nxt = 128;

        const int lo = (s > r0) ? s : r0;
        const int hi = (nxt < r1) ? nxt : r1;
        unsigned int run = 0;
        for (int r = lo; r < hi; ++r)
          run = pkmax(run, us32[r * (PADROW >> 1) + jc]);

        if (s < r0) {
          pmS[quarter][jc] = run;                 // run covering this quarter's r0
        } else if (nxt <= r1) {
          const int d = edS[s];
          if (d >= 0) {
            const bool bnd = (s == 0 && prevd == d) || (nxt == 128 && nextd == d);
            unsigned int* ap = aggu + (size_t)d * 64 + jc;
            if (!bnd) *ap = run;
            else if (run) casmax(ap, run);
          }
        } else {                                  // owner of a spanning run
          os = s; onxt = nxt; od = edS[s]; opart = run;
        }
        s = nxt;
      }
    }
    __syncthreads();   // E: pmS ready

    // stage 3 pass 2: owners combine partials and write once.
    // Touches only pmS + registers (prevd/nextd/od captured) -> no barrier F:
    // next-tile esS/edS/pn writes are dead here; next pmS write is behind the
    // next tile's A..D barrier chain.
    if (os >= 0 && od >= 0) {
      const int endq = (onxt - 1) >> 4;
      #pragma unroll 4
      for (int qq = quarter + 1; qq <= endq; ++qq)
        opart = pkmax(opart, pmS[qq][jc]);
      const bool bnd = (os == 0 && prevd == od) || (onxt == 128 && nextd == od);
      unsigned int* ap = aggu + (size_t)od * 64 + jc;
      if (!bnd) *ap = opart;
      else if (opart) casmax(ap, opart);
    }
  }
}

// ---------------- fallback: atomic edge kernel (small ws) ----------------

__global__ __launch_bounds__(256, 2) void edge_atomic_kernel(
    const float* __restrict__ x, const int* __restrict__ ei,
    const float* __restrict__ w1, const float* __restrict__ b1,
    const float* __restrict__ w2, const float* __restrict__ b2,
    unsigned int* aggu, const int* __restrict__ flag64, int N, int E) {
  __shared__ unsigned short uA[EB * PADROW];
  __shared__ float w1s[6 * NHID];
  __shared__ float b1s[NHID], b2s[NHID];
  __shared__ int es[EB], ed[EB];

  const int t = threadIdx.x;
  const int lane = t & 63;
  const int w = t >> 6;
  const int m = lane & 15;
  const int q = lane >> 4;

  for (int i = t; i < 6 * NHID; i += 256) w1s[i] = w1[i];
  if (t < NHID) { b1s[t] = b1[t]; b2s[t] = b2[t]; }

  short8 bf[32];
  load_bfrags(w2, bf, m, q);

  const bool is64 = (flag64[0] != 0);
  const int nb = (E + EB - 1) / EB;

  for (int batch = blockIdx.x; batch < nb; batch += gridDim.x) {
    const int gbase = batch * EB;
    if (t < EB) {
      int e = gbase + t;
      es[t] = (e < E) ? (is64 ? ei[2 * e] : ei[e]) : 0;
    } else if (t < 2 * EB) {
      int tt = t - EB;
      int e = gbase + tt;
      ed[tt] = (e < E) ? (is64 ? ei[2 * E + 2 * e] : ei[E + e]) : 0;
    }
    __syncthreads();
    {
      const int e = t >> 2;
      const int c0 = (t & 3) * 32;
      const int si = es[e], di = ed[e];
      float xi0 = x[di * 3], xi1 = x[di * 3 + 1], xi2 = x[di * 3 + 2];
      float msg[6];
      msg[0] = xi0; msg[1] = xi1; msg[2] = xi2;
      msg[3] = x[si * 3] - xi0; msg[4] = x[si * 3 + 1] - xi1; msg[5] = x[si * 3 + 2] - xi2;
      unsigned int* d32 = (unsigned int*)uA;
      const int base32 = (e * PADROW + c0) >> 1;
      #pragma unroll
      for (int cc = 0; cc < 32; cc += 2) {
        float u0 = b1s[c0 + cc], u1 = b1s[c0 + cc + 1];
        #pragma unroll
        for (int d = 0; d < 6; ++d) {
          u0 += msg[d] * w1s[d * NHID + c0 + cc];
          u1 += msg[d] * w1s[d * NHID + c0 + cc + 1];
        }
        d32[base32 + (cc >> 1)] = pack2(fmaxf(u0, 0.f), fmaxf(u1, 0.f));
      }
    }
    __syncthreads();

    floatx4 acc[8];
    #pragma unroll
    for (int nt = 0; nt < 8; ++nt) { floatx4 z = {0.f, 0.f, 0.f, 0.f}; acc[nt] = z; }
    mfma_block(uA, bf, acc, w, m, q);

    #pragma unroll
    for (int nt = 0; nt < 8; ++nt) {
      const int c = nt * 16 + m;
      const float bb = b2s[c];
      const int kst = m * 8 + nt;
      #pragma unroll
      for (int r = 0; r < 4; ++r) {
        const int erow = 16 * w + q * 4 + r;
        if (gbase + erow < E) {
          float hb = acc[nt][r] + bb;
          if (hb > 0.f) {
            unsigned int v = (unsigned int)f2bf(hb);
            casmax(aggu + (size_t)ed[erow] * 64 + (kst >> 1), v << (16 * (kst & 1)));
          }
        }
      }
    }
    __syncthreads();
  }
}

// ---------------- fused node MLPs: enc (w3) + dec (w4,w5), agg16 input ----------------
// R9 structure (barriers B0/B1/B2/B3) — R10's barrier removal regressed.
// R15 lesson applies here too: acc zero-init FROZEN (bias in epilogue).

__global__ __launch_bounds__(256, 2) void encdec_kernel(
    const float* __restrict__ w3, const float* __restrict__ b3,
    const float* __restrict__ w4, const float* __restrict__ b4,
    const float* __restrict__ w5, const float* __restrict__ b5,
    const float* __restrict__ pos, const unsigned short* __restrict__ agg16,
    float* __restrict__ out, int N) {
  __shared__ unsigned short uA[EB * PADROW];
  __shared__ short8 w4f[2048];                    // k-permuted w4 frags
  __shared__ float w5s[NHID * 3];

  const int t = threadIdx.x;
  const int lane = t & 63;
  const int w = t >> 6;
  const int m = lane & 15;
  const int q = lane >> 4;

  float b3c[8], b4c[8];
  #pragma unroll
  for (int nt = 0; nt < 8; ++nt) { b3c[nt] = b3[nt * 16 + m]; b4c[nt] = b4[nt * 16 + m]; }

  short8 bf3[32];
  load_bfrags_perm(w3, bf3, m, q);                // k-permuted (agg16 is kstore-ordered)

  for (int idx = t; idx < 2048; idx += 256) {
    const int fg = idx >> 6, ln = idx & 63;
    const int mm = ln & 15;
    const int kc = fg >> 3, nt = fg & 7;
    short8 v;
    #pragma unroll
    for (int j = 0; j < 8; ++j) {
      const int khw = kc * 32 + (ln >> 4) * 8 + j;
      const int ctrue = ((khw & 7) << 4) | (khw >> 3);
      v[j] = (short)f2bf(w4[ctrue * NHID + nt * 16 + mm]);
    }
    w4f[idx] = v;
  }
  for (int i = t; i < NHID * 3; i += 256) w5s[i] = w5[i];
  const float b50 = b5[0], b51 = b5[1], b52 = b5[2];

  const int ch = t & 15;
  const int rr = t >> 4;
  const int nb = (N + EB - 1) / EB;
  __syncthreads();

  uint4 rv[4];
  const uint4 uz = make_uint4(0u, 0u, 0u, 0u);
  {
    const int b0 = blockIdx.x;
    #pragma unroll
    for (int k = 0; k < 4; ++k) {
      const int node = b0 * EB + rr + 16 * k;
      rv[k] = (b0 < nb && node < N) ? ((const uint4*)agg16)[(size_t)node * 16 + ch] : uz;
    }
  }

  for (int batch = blockIdx.x; batch < nb; batch += gridDim.x) {
    const int base = batch * EB;
    #pragma unroll
    for (int k = 0; k < 4; ++k)
      *(uint4*)(&uA[(rr + 16 * k) * PADROW + ch * 8]) = rv[k];
    __syncthreads();   // B0

    {
      const int nxb = batch + gridDim.x;
      #pragma unroll
      for (int k = 0; k < 4; ++k) {
        const int node = nxb * EB + rr + 16 * k;
        rv[k] = (nxb < nb && node < N) ? ((const uint4*)agg16)[(size_t)node * 16 + ch] : uz;
      }
    }

    floatx4 acc[8];
    #pragma unroll
    for (int nt = 0; nt < 8; ++nt) { floatx4 z = {0.f, 0.f, 0.f, 0.f}; acc[nt] = z; }
    mfma_block(uA, bf3, acc, w, m, q);
    __syncthreads();   // B1

    #pragma unroll
    for (int r = 0; r < 4; ++r) {
      union { short8 s; uint4 u; } cv;
      cv.u = make_uint4(
        pkbf(acc[0][r] + b3c[0], acc[1][r] + b3c[1]),
        pkbf(acc[2][r] + b3c[2], acc[3][r] + b3c[3]),
        pkbf(acc[4][r] + b3c[4], acc[5][r] + b3c[5]),
        pkbf(acc[6][r] + b3c[6], acc[7][r] + b3c[7]));
      *(short8*)(&uA[(16 * w + q * 4 + r) * PADROW + m * 8]) = cv.s;
    }
    __syncthreads();   // B2

    #pragma unroll
    for (int nt = 0; nt < 8; ++nt) { floatx4 z = {0.f, 0.f, 0.f, 0.f}; acc[nt] = z; }
    #pragma unroll
    for (int kc = 0; kc < 4; ++kc) {
      short8 a = *(const short8*)(&uA[(16 * w + m) * PADROW + kc * 32 + q * 8]);
      #pragma unroll
      for (int nt = 0; nt < 8; ++nt)
        acc[nt] = __builtin_amdgcn_mfma_f32_16x16x32_bf16(a, w4f[(kc * 8 + nt) * 64 + lane],
                                                          acc[nt], 0, 0, 0);
    }

    float p[4][3];
    #pragma unroll
    for (int r = 0; r < 4; ++r) { p[r][0] = 0.f; p[r][1] = 0.f; p[r][2] = 0.f; }
    #pragma unroll
    for (int nt = 0; nt < 8; ++nt) {
      const int c = nt * 16 + m;
      const float bb = b4c[nt];
      const float w50 = w5s[c * 3], w51 = w5s[c * 3 + 1], w52 = w5s[c * 3 + 2];
      #pragma unroll
      for (int r = 0; r < 4; ++r) {
        float tv = fmaxf(acc[nt][r] + bb, 0.f);
        p[r][0] += tv * w50; p[r][1] += tv * w51; p[r][2] += tv * w52;
      }
    }
    #pragma unroll
    for (int off = 8; off >= 1; off >>= 1) {
      #pragma unroll
      for (int r = 0; r < 4; ++r) {
        p[r][0] += __shfl_xor(p[r][0], off, 16);
        p[r][1] += __shfl_xor(p[r][1], off, 16);
        p[r][2] += __shfl_xor(p[r][2], off, 16);
      }
    }
    if (m == 0) {
      #pragma unroll
      for (int r = 0; r < 4; ++r) {
        const int node = base + 16 * w + q * 4 + r;
        if (node < N) {
          out[node * 3]     = pos[node * 3]     + 0.1f * tanhf(p[r][0] + b50);
          out[node * 3 + 1] = pos[node * 3 + 1] + 0.1f * tanhf(p[r][1] + b51);
          out[node * 3 + 2] = pos[node * 3 + 2] + 0.1f * tanhf(p[r][2] + b52);
        }
      }
    }
    __syncthreads();   // B3
  }
}

extern "C" void kernel_launch(void* const* d_in, const int* in_sizes, int n_in,
                              void* d_out, int out_size, void* d_ws, size_t ws_size,
                              hipStream_t stream) {
  const float* x   = (const float*)d_in[0];
  const float* pos = (const float*)d_in[1];
  const int*   ei  = (const int*)d_in[2];
  const float* w1  = (const float*)d_in[3];
  const float* b1  = (const float*)d_in[4];
  const float* w2  = (const float*)d_in[5];
  const float* b2  = (const float*)d_in[6];
  const float* w3  = (const float*)d_in[7];
  const float* b3  = (const float*)d_in[8];
  const float* w4  = (const float*)d_in[9];
  const float* b4  = (const float*)d_in[10];
  const float* w5  = (const float*)d_in[11];
  const float* b5  = (const float*)d_in[12];
  float* out = (float*)d_out;

  const int N = in_sizes[0] / 3;
  const int E = in_sizes[2] / 2;
  const int nbuck = (N + 255) >> 8;

  char* ws = (char*)d_ws;
  unsigned short* agg16 = (unsigned short*)ws;                // N*128 u16 (kstore order)
  const size_t aggB = (size_t)N * NHID * sizeof(unsigned short);
  int2* mid    = (int2*)(ws + aggB);
  int2* sorted = (int2*)(ws + aggB + (size_t)E * 8);
  int*  mat    = (int*)(ws + aggB + (size_t)E * 16);
  int*  btot   = mat + (size_t)nbuck * PB;
  int*  bstart = btot + nbuck;
  const size_t needed = aggB + (size_t)E * 16 + ((size_t)nbuck * PB + nbuck + 520) * 4;

  if (ws_size >= needed && nbuck <= 511 && E >= 64) {
    part_hist<<<2048, 256, 0, stream>>>(ei, mat, E, nbuck, (float4*)agg16, N * 16);
    scan_rows<<<nbuck, 256, 0, stream>>>(mat, btot, nbuck);
    part_scatter<<<PB, 512, 0, stream>>>(ei, mat, btot, bstart, mid, E, nbuck);
    bucket_sort<<<nbuck, 512, 0, stream>>>(mid, bstart, sorted);
    edge_sorted_kernel<<<512, 512, 0, stream>>>(x, sorted, w1, b1, w2, b2,
                                                (unsigned int*)agg16, N, E);
  } else {
    int* flag2 = (int*)(ws + aggB);
    zero_detect_kernel<<<2048, 256, 0, stream>>>((float4*)agg16, N * 16, ei, flag2);
    edge_atomic_kernel<<<512, 256, 0, stream>>>(x, ei, w1, b1, w2, b2,
                                                (unsigned int*)agg16, flag2, N, E);
  }
  encdec_kernel<<<512, 256, 0, stream>>>(w3, b3, w4, b4, w5, b5, pos, agg16, out, N);
}

// Round 7
// 331.976 us; speedup vs baseline: 1.0385x; 1.0071x over previous
//
#include <hip/hip_runtime.h>
#include <hip/hip_bf16.h>

typedef __attribute__((ext_vector_type(8))) short short8;
typedef __attribute__((ext_vector_type(4))) float floatx4;
typedef __attribute__((ext_vector_type(2))) unsigned short ushortx2;

#define NHID 128
#define PADROW 136   // u16 row stride: 272B, 16B-aligned b128, benign banking
#define EB 64        // nodes per tile (encdec / fallback)
#define EB2 128      // edges per tile (edge_sorted)
#define PB 512       // partition blocks for the 2-level sort (R20: 256->512,
                     // part_scatter was 1 block/CU = latency-starved)

__device__ __forceinline__ unsigned short f2bf(float x) {
  unsigned int u = __float_as_uint(x);
  u += 0x7FFFu + ((u >> 16) & 1u);          // RNE
  return (unsigned short)(u >> 16);
}

__device__ __forceinline__ unsigned int pkbf(float a, float b) {
  __hip_bfloat162 h = __float22bfloat162_rn(make_float2(a, b));
  union { __hip_bfloat162 h; unsigned int u; } cv;
  cv.h = h;
  return cv.u;
}

__device__ __forceinline__ unsigned int pack2(float a, float b) {
  return (unsigned int)f2bf(a) | ((unsigned int)f2bf(b) << 16);
}

// packed u16 max (v_pk_max_u16)
__device__ __forceinline__ unsigned int pkmax(unsigned int a, unsigned int b) {
  union { unsigned int u; ushortx2 v; } x, y;
  x.u = a; y.u = b;
  x.v = __builtin_elementwise_max(x.v, y.v);
  return x.u;
}

__device__ __forceinline__ void casmax(unsigned int* ap, unsigned int run) {
  unsigned int old = *ap;
  while (true) {
    unsigned int mx = pkmax(old, run);
    if (mx == old) break;
    unsigned int got = atomicCAS(ap, old, mx);
    if (got == old) break;
    old = got;
  }
}

// all-wave inline int64 probe: odd int32 slots all-zero <=> int64 edge_index
__device__ __forceinline__ bool detect64(const int* __restrict__ ei) {
  unsigned long long b = __ballot(ei[2 * (threadIdx.x & 63) + 1] != 0);
  return b == 0ULL;
}

// 32 loop-invariant B-fragments of a 128x128 row-major f32 weight (registers), natural k.
__device__ __forceinline__ void load_bfrags(const float* __restrict__ wmat,
                                            short8* bf, int m, int q) {
  #pragma unroll
  for (int kc = 0; kc < 4; ++kc) {
    #pragma unroll
    for (int nt = 0; nt < 8; ++nt) {
      short8 v;
      #pragma unroll
      for (int j = 0; j < 8; ++j)
        v[j] = (short)f2bf(wmat[(kc * 32 + q * 8 + j) * NHID + nt * 16 + m]);
      bf[kc * 8 + nt] = v;
    }
  }
}

// same but k-permuted: B[khw][n] = w[pi(khw)][n], pi(k) = ((k&7)<<4)|(k>>3)
__device__ __forceinline__ void load_bfrags_perm(const float* __restrict__ wmat,
                                                 short8* bf, int m, int q) {
  #pragma unroll
  for (int kc = 0; kc < 4; ++kc) {
    #pragma unroll
    for (int nt = 0; nt < 8; ++nt) {
      short8 v;
      #pragma unroll
      for (int j = 0; j < 8; ++j) {
        const int khw = kc * 32 + q * 8 + j;
        const int ctrue = ((khw & 7) << 4) | (khw >> 3);
        v[j] = (short)f2bf(wmat[ctrue * NHID + nt * 16 + m]);
      }
      bf[kc * 8 + nt] = v;
    }
  }
}

__device__ __forceinline__ void mfma_block(const unsigned short* uA,
                                           const short8* bf, floatx4* acc,
                                           int w, int m, int q) {
  #pragma unroll
  for (int kc = 0; kc < 4; ++kc) {
    short8 a = *(const short8*)(uA + (16 * w + m) * PADROW + kc * 32 + q * 8);
    #pragma unroll
    for (int nt = 0; nt < 8; ++nt)
      acc[nt] = __builtin_amdgcn_mfma_f32_16x16x32_bf16(a, bf[kc * 8 + nt],
                                                        acc[nt], 0, 0, 0);
  }
}

// fallback-path zero (agg16) + detect->flag
__global__ void zero_detect_kernel(float4* __restrict__ p, int n4,
                                   const int* __restrict__ ei, int* __restrict__ flag) {
  if (blockIdx.x == 0 && threadIdx.x < 64) {
    unsigned long long b = __ballot(ei[2 * threadIdx.x + 1] != 0);
    if (threadIdx.x == 0) flag[0] = (b == 0ULL) ? 1 : 0;
  }
  int i = blockIdx.x * blockDim.x + threadIdx.x;
  int stride = gridDim.x * blockDim.x;
  float4 z = make_float4(0.f, 0.f, 0.f, 0.f);
  for (; i < n4; i += stride) p[i] = z;
}

// ---------------- 2-level counting sort by dst (no global atomics) ----------------
// Split pipeline (R11): grid-barrier fusion regressed badly (R12/R13).
// R20: (1) PB 256->512 — part_scatter was 256 blocks = 1 block/CU (latency-
// starved, the R12 lesson); now 2 blocks/CU. (2) mid packed to u32:
// s | (d&255)<<24 — within a coarse region d>>8 == bucket id (bucket_sort's
// blockIdx), so full d is reconstructible; s <= 17 bits via the nbuck<=511
// guard. Halves part_scatter's scattered write + bucket_sort's two reads
// (-19 MB HBM, halved L2 footprint).

// A1: per-partition LDS histogram over coarse buckets (dst>>8); tail blocks zero agg16
__global__ __launch_bounds__(256) void part_hist(const int* __restrict__ ei,
                                                 int* __restrict__ mat, int E, int nbuck,
                                                 float4* __restrict__ aggz, int n4) {
  const int bl = blockIdx.x, t = threadIdx.x;
  if (bl >= PB) {
    int i = (bl - PB) * 256 + t;
    const int st = (gridDim.x - PB) * 256;
    float4 z = make_float4(0.f, 0.f, 0.f, 0.f);
    for (; i < n4; i += st) aggz[i] = z;
    return;
  }
  __shared__ int hist[512];
  const bool is64 = detect64(ei);
  for (int i = t; i < nbuck; i += 256) hist[i] = 0;
  __syncthreads();
  const int chunk = (E + PB - 1) / PB;
  const int lo = bl * chunk;
  const int hi = min(lo + chunk, E);
  for (int i = lo + t; i < hi; i += 256) {
    int d = is64 ? ei[2 * E + 2 * i] : ei[E + i];
    atomicAdd(&hist[d >> 8], 1);
  }
  __syncthreads();
  for (int bu = t; bu < nbuck; bu += 256) mat[bu * PB + bl] = hist[bu];
}

// A2: per-bucket exclusive scan over the PB partitions (in place) + bucket totals
__global__ __launch_bounds__(512) void scan_rows(int* __restrict__ mat,
                                                 int* __restrict__ btot, int nbuck) {
  __shared__ int sh[512];
  const int bu = blockIdx.x, t = threadIdx.x;
  const int v = mat[bu * PB + t];
  sh[t] = v;
  __syncthreads();
  for (int off = 1; off < 512; off <<= 1) {
    int x = (t >= off) ? sh[t - off] : 0;
    __syncthreads();
    sh[t] += x;
    __syncthreads();
  }
  mat[bu * PB + t] = sh[t] - v;
  if (t == 511) btot[bu] = sh[511];
}

// A3: scatter into coarse-bucket regions; bucket starts scanned in-LDS from btot.
__global__ __launch_bounds__(512) void part_scatter(const int* __restrict__ ei,
                                                    const int* __restrict__ mat,
                                                    const int* __restrict__ btot,
                                                    int* __restrict__ bstart,
                                                    unsigned int* __restrict__ mid32,
                                                    int E, int nbuck) {
  __shared__ int off[512];
  __shared__ int bsS[512];
  const bool is64 = detect64(ei);
  const int bl = blockIdx.x, t = threadIdx.x;
  const int o0 = (t < 256 && t < nbuck) ? btot[t] : 0;
  const int o1 = (t < 256 && t + 256 < nbuck) ? btot[t + 256] : 0;
  if (t < 256) { bsS[t] = o0; bsS[t + 256] = o1; }
  __syncthreads();
  for (int o = 1; o < 256; o <<= 1) {
    int x0 = (t >= o && t < 256) ? bsS[t - o] : 0;
    int x1 = (t >= o && t < 256) ? bsS[256 + t - o] : 0;
    __syncthreads();
    if (t < 256) { bsS[t] += x0; bsS[256 + t] += x1; }
    __syncthreads();
  }
  const int tot0 = bsS[255];
  if (t < 256) bsS[256 + t] += tot0;
  __syncthreads();
  if (t < 256) {
    const int ex0 = bsS[t] - o0;
    const int ex1 = bsS[256 + t] - o1;
    if (bl == 0) { bstart[t] = ex0; bstart[256 + t] = ex1; }
    off[t]       = ex0 + ((t < nbuck) ? mat[t * PB + bl] : 0);
    off[256 + t] = ex1 + ((t + 256 < nbuck) ? mat[(t + 256) * PB + bl] : 0);
  }
  __syncthreads();
  const int chunk = (E + PB - 1) / PB;
  const int lo = bl * chunk;
  const int hi = min(lo + chunk, E);
  for (int i = lo + t; i < hi; i += 512) {
    int s = is64 ? ei[2 * i]         : ei[i];
    int d = is64 ? ei[2 * E + 2 * i] : ei[E + i];
    int p = atomicAdd(&off[d >> 8], 1);
    mid32[p] = (unsigned int)s | ((unsigned int)(d & 255) << 24);
  }
}

// B: per-bucket counting sort by exact dst (256 local nodes), L2-resident traffic.
__global__ __launch_bounds__(512) void bucket_sort(const unsigned int* __restrict__ mid32,
                                                   const int* __restrict__ bstart,
                                                   int2* __restrict__ sorted) {
  __shared__ int h[256], cnt[256];
  const int bu = blockIdx.x, t = threadIdx.x;
  const int lo = bstart[bu], hi = bstart[bu + 1];
  if (t < 256) { h[t] = 0; cnt[t] = 0; }
  __syncthreads();
  for (int i = lo + t; i < hi; i += 512) atomicAdd(&h[mid32[i] >> 24], 1);
  __syncthreads();
  const int v = (t < 256) ? h[t] : 0;
  for (int off = 1; off < 256; off <<= 1) {
    int x = (t >= off && t < 256) ? h[t - off] : 0;
    __syncthreads();
    if (t < 256) h[t] += x;
    __syncthreads();
  }
  const int excl = (t < 256) ? h[t] - v : 0;
  __syncthreads();
  if (t < 256) h[t] = excl;
  __syncthreads();
  for (int i = lo + t; i < hi; i += 512) {
    const unsigned int e = mid32[i];
    const int dl = (int)(e >> 24);
    const int p = lo + h[dl] + atomicAdd(&cnt[dl], 1);
    sorted[p] = make_int2((int)(e & 0xFFFFFFu), (bu << 8) | dl);
  }
}

// ---------------- fused edge MLP (both layers MFMA) + segmented max ----------------
// R9 structure: barrier lockstep is a beneficial scheduling fence — R10's bulk
// barrier removal raised VGPR 60->92 and regressed.
// FROZEN RULES (R10/R14/R15): acc MUST be zero-init (bias-splat C-init hoists 32
// loop-invariant VGPRs -> crosses 128 residency bucket -> occupancy halves).
// Total regs sit at 64 arch + 64 acc = 128, the residency-bucket edge: NO
// live-range growth across barriers.
// R16: layer-1 bias via spare K-slot — A k=6 := 1.0, B row j=6 := b1.
// R17: layer-2 wave remap — wave owns 32 rows (rowg) x 64 true cols (colg);
// 36->24 b128/thread/tile.
// R18 REVERTED: bank-swizzle — SQ_LDS_BANK_CONFLICT here counts benign 2-way
// wave64 aliasing phases (exactly 4/edge), NOT stalls. Don't chase it.
// R19: barrier F removed, prevd/nextd register-captured. 5 barriers/tile.
// agg16: u16[N][128] in kstore (k-permuted) order. Stage-3: two-pass LDS run merge.

__global__ __launch_bounds__(512, 2) void edge_sorted_kernel(
    const float* __restrict__ x, const int2* __restrict__ sorted,
    const float* __restrict__ w1, const float* __restrict__ b1,
    const float* __restrict__ w2, const float* __restrict__ b2,
    unsigned int* aggu, int N, int E) {
  __shared__ unsigned short us[EB2 * PADROW];     // uA then hS (bf16)
  __shared__ short8 w2f[2048];                    // 32 frags x 64 lanes, k-permuted
  __shared__ int esS[EB2], edS[EB2];
  __shared__ int pn[2];                           // dst before / after tile (-2 = none)
  __shared__ unsigned long long maskS[2];         // run-start bitmask
  __shared__ unsigned int pmS[8][64];             // per-quarter partial of run covering r0

  const int t = threadIdx.x;
  const int lane = t & 63;
  const int w = t >> 6;                           // wave 0..7
  const int m = lane & 15;
  const int q = lane >> 4;
  const int rowg = w >> 1;                        // layer-2: rows [32*rowg, +32)
  const int colg = w & 1;                         // layer-2: true cols [64*colg, +64)

  float b2c[4];
  #pragma unroll
  for (int nt = 0; nt < 4; ++nt) b2c[nt] = b2[(4 * colg + nt) * 16 + m];

  short8 bf1[8];
  #pragma unroll
  for (int nt = 0; nt < 8; ++nt) {
    short8 v;
    #pragma unroll
    for (int j = 0; j < 8; ++j) {
      short sj = 0;
      if (q == 0 && j < 6) sj = (short)f2bf(w1[j * NHID + nt * 16 + m]);
      else if (q == 0 && j == 6) sj = (short)f2bf(b1[nt * 16 + m]);  // bias row, k=6
      v[j] = sj;
    }
    bf1[nt] = v;
  }

  for (int idx = t; idx < 2048; idx += 512) {
    const int fg = idx >> 6, ln = idx & 63;
    const int mm = ln & 15;
    const int kc = fg >> 3, nt = fg & 7;
    short8 v;
    #pragma unroll
    for (int j = 0; j < 8; ++j) {
      const int khw = kc * 32 + (ln >> 4) * 8 + j;
      const int ctrue = ((khw & 7) << 4) | (khw >> 3);
      v[j] = (short)f2bf(w2[ctrue * NHID + nt * 16 + mm]);
    }
    w2f[idx] = v;
  }

  const int jc = t & 63;                          // u32 col in kstore order
  const int quarter = t >> 6;                     // rows [16*quarter, +16)

  const int nbt = (E + EB2 - 1) / EB2;
  __syncthreads();

  // preload first tile's index data
  int2 sv = make_int2(0, -1);
  {
    const int tile0 = blockIdx.x;
    const int gb = tile0 * EB2;
    if (t < EB2) {
      const int e = gb + t;
      if (tile0 < nbt && e < E) sv = sorted[e];
    } else if (t == EB2) {
      sv.y = (tile0 < nbt && gb > 0) ? sorted[gb - 1].y : -2;
    } else if (t == EB2 + 1) {
      sv.y = (tile0 < nbt && gb + EB2 < E) ? sorted[gb + EB2].y : -2;
    }
  }

  for (int tile = blockIdx.x; tile < nbt; tile += gridDim.x) {
    if (t < EB2) { esS[t] = sv.x; edS[t] = sv.y; }
    else if (t == EB2) pn[0] = sv.y;
    else if (t == EB2 + 1) pn[1] = sv.y;
    __syncthreads();   // A

    if (w == 0) {
      int d0 = edS[lane];
      int dp0 = (lane == 0) ? -9 : edS[lane - 1];
      unsigned long long mk0 = __ballot(lane == 0 || d0 != dp0);
      int d1 = edS[64 + lane];
      int dp1 = edS[63 + lane];
      unsigned long long mk1 = __ballot(d1 != dp1);
      if (lane == 0) { maskS[0] = mk0; maskS[1] = mk1; }
    }

    // layer 1 (zero acc init — FROZEN; bias enters via K-slot 6)
    floatx4 acc[8];
    #pragma unroll
    for (int nt = 0; nt < 8; ++nt) { floatx4 z = {0.f, 0.f, 0.f, 0.f}; acc[nt] = z; }
    short8 a1 = {0, 0, 0, 0, 0, 0, 0, 0};
    if (q == 0) {
      const int e = 16 * w + m;
      const int si = esS[e];
      const int d0 = edS[e];
      const int di = (d0 < 0) ? 0 : d0;
      float xi0 = x[di * 3], xi1 = x[di * 3 + 1], xi2 = x[di * 3 + 2];
      float dd0 = x[si * 3] - xi0, dd1 = x[si * 3 + 1] - xi1, dd2 = x[si * 3 + 2] - xi2;
      union { short8 s; uint4 u; } cv;
      cv.u = make_uint4(pkbf(xi0, xi1), pkbf(xi2, dd0), pkbf(dd1, dd2),
                        0x00003F80u);             // k=6: 1.0 (bias lane), k=7: 0
      a1 = cv.s;
    }
    #pragma unroll
    for (int nt = 0; nt < 8; ++nt)
      acc[nt] = __builtin_amdgcn_mfma_f32_16x16x32_bf16(a1, bf1[nt], acc[nt], 0, 0, 0);

    #pragma unroll
    for (int r = 0; r < 4; ++r) {
      union { short8 s; uint4 u; } cv;
      cv.u = make_uint4(
        pkbf(fmaxf(acc[0][r], 0.f), fmaxf(acc[1][r], 0.f)),
        pkbf(fmaxf(acc[2][r], 0.f), fmaxf(acc[3][r], 0.f)),
        pkbf(fmaxf(acc[4][r], 0.f), fmaxf(acc[5][r], 0.f)),
        pkbf(fmaxf(acc[6][r], 0.f), fmaxf(acc[7][r], 0.f)));
      *(short8*)(&us[(16 * w + q * 4 + r) * PADROW + m * 8]) = cv.s;
    }
    __syncthreads();   // B

    // layer 2 (zero acc init — FROZEN; bias in epilogue; R17 remap)
    #pragma unroll
    for (int nt = 0; nt < 8; ++nt) { floatx4 z = {0.f, 0.f, 0.f, 0.f}; acc[nt] = z; }
    #pragma unroll
    for (int kc = 0; kc < 4; ++kc) {
      short8 a0 = *(const short8*)(&us[(32 * rowg + m) * PADROW + kc * 32 + q * 8]);
      short8 a1r = *(const short8*)(&us[(32 * rowg + 16 + m) * PADROW + kc * 32 + q * 8]);
      #pragma unroll
      for (int nt = 0; nt < 4; ++nt) {
        short8 b = w2f[(kc * 8 + 4 * colg + nt) * 64 + lane];
        acc[nt]     = __builtin_amdgcn_mfma_f32_16x16x32_bf16(a0, b, acc[nt], 0, 0, 0);
        acc[4 + nt] = __builtin_amdgcn_mfma_f32_16x16x32_bf16(a1r, b, acc[4 + nt], 0, 0, 0);
      }
    }
    __syncthreads();   // C

    #pragma unroll
    for (int rb = 0; rb < 2; ++rb) {
      #pragma unroll
      for (int r = 0; r < 4; ++r) {
        uint2 uu;
        uu.x = pkbf(fmaxf(acc[rb * 4 + 0][r] + b2c[0], 0.f),
                    fmaxf(acc[rb * 4 + 1][r] + b2c[1], 0.f));
        uu.y = pkbf(fmaxf(acc[rb * 4 + 2][r] + b2c[2], 0.f),
                    fmaxf(acc[rb * 4 + 3][r] + b2c[3], 0.f));
        *(uint2*)(&us[(32 * rowg + 16 * rb + q * 4 + r) * PADROW + m * 8 + 4 * colg]) = uu;
      }
    }
    __syncthreads();   // D: hS ready

    // prefetch next tile's index data
    {
      const int tn = tile + gridDim.x;
      const int gb = tn * EB2;
      int2 nv = make_int2(0, -1);
      if (t < EB2) {
        const int e = gb + t;
        if (tn < nbt && e < E) nv = sorted[e];
      } else if (t == EB2) {
        nv.y = (tn < nbt && gb > 0) ? sorted[gb - 1].y : -2;
      } else if (t == EB2 + 1) {
        nv.y = (tn < nbt && gb + EB2 < E) ? sorted[gb + EB2].y : -2;
      }
      sv = nv;
    }

    // stage 3 pass 1: per-quarter partials; contained runs stored directly.
    // prevd/nextd captured to registers (R19): pass 2 must not touch pn[].
    int os = -1, onxt = 0, od = -1; unsigned int opart = 0;
    int prevd, nextd;
    {
      const unsigned long long mk0 = maskS[0], mk1 = maskS[1];
      prevd = pn[0]; nextd = pn[1];
      const int r0 = quarter * 16, r1 = r0 + 16;
      const unsigned int* us32 = (const unsigned int*)us;
      int s;
      if (r0 < 64) {
        s = 63 - __builtin_clzll(mk0 & (~0ULL >> (63 - r0)));
      } else {
        unsigned long long hm = mk1 & (~0ULL >> (127 - r0));
        s = hm ? 127 - __builtin_clzll(hm) : 63 - __builtin_clzll(mk0);
      }
      while (s < r1) {
        int nxt;
        if (s < 63) {
          unsigned long long ab = mk0 & (~0ULL << (s + 1));
          if (ab) nxt = __builtin_ffsll((long long)ab) - 1;
          else    nxt = mk1 ? 64 + __builtin_ffsll((long long)mk1) - 1 : 128;
        } else if (s == 63) {
          nxt = mk1 ? 64 + __builtin_ffsll((long long)mk1) - 1 : 128;
        } else if (s < 127) {
          unsigned long long ab = mk1 & (~0ULL << (s - 63));
          nxt = ab ? 64 + __builtin_ffsll((long long)ab) - 1 : 128;
        } else nxt = 128;

        const int lo = (s > r0) ? s : r0;
        const int hi = (nxt < r1) ? nxt : r1;
        unsigned int run = 0;
        for (int r = lo; r < hi; ++r)
          run = pkmax(run, us32[r * (PADROW >> 1) + jc]);

        if (s < r0) {
          pmS[quarter][jc] = run;                 // run covering this quarter's r0
        } else if (nxt <= r1) {
          const int d = edS[s];
          if (d >= 0) {
            const bool bnd = (s == 0 && prevd == d) || (nxt == 128 && nextd == d);
            unsigned int* ap = aggu + (size_t)d * 64 + jc;
            if (!bnd) *ap = run;
            else if (run) casmax(ap, run);
          }
        } else {                                  // owner of a spanning run
          os = s; onxt = nxt; od = edS[s]; opart = run;
        }
        s = nxt;
      }
    }
    __syncthreads();   // E: pmS ready

    // stage 3 pass 2: owners combine partials and write once.
    // Touches only pmS + registers (prevd/nextd/od captured) -> no barrier F:
    // next-tile esS/edS/pn writes are dead here; next pmS write is behind the
    // next tile's A..D barrier chain.
    if (os >= 0 && od >= 0) {
      const int endq = (onxt - 1) >> 4;
      #pragma unroll 4
      for (int qq = quarter + 1; qq <= endq; ++qq)
        opart = pkmax(opart, pmS[qq][jc]);
      const bool bnd = (os == 0 && prevd == od) || (onxt == 128 && nextd == od);
      unsigned int* ap = aggu + (size_t)od * 64 + jc;
      if (!bnd) *ap = opart;
      else if (opart) casmax(ap, opart);
    }
  }
}

// ---------------- fallback: atomic edge kernel (small ws) ----------------

__global__ __launch_bounds__(256, 2) void edge_atomic_kernel(
    const float* __restrict__ x, const int* __restrict__ ei,
    const float* __restrict__ w1, const float* __restrict__ b1,
    const float* __restrict__ w2, const float* __restrict__ b2,
    unsigned int* aggu, const int* __restrict__ flag64, int N, int E) {
  __shared__ unsigned short uA[EB * PADROW];
  __shared__ float w1s[6 * NHID];
  __shared__ float b1s[NHID], b2s[NHID];
  __shared__ int es[EB], ed[EB];

  const int t = threadIdx.x;
  const int lane = t & 63;
  const int w = t >> 6;
  const int m = lane & 15;
  const int q = lane >> 4;

  for (int i = t; i < 6 * NHID; i += 256) w1s[i] = w1[i];
  if (t < NHID) { b1s[t] = b1[t]; b2s[t] = b2[t]; }

  short8 bf[32];
  load_bfrags(w2, bf, m, q);

  const bool is64 = (flag64[0] != 0);
  const int nb = (E + EB - 1) / EB;

  for (int batch = blockIdx.x; batch < nb; batch += gridDim.x) {
    const int gbase = batch * EB;
    if (t < EB) {
      int e = gbase + t;
      es[t] = (e < E) ? (is64 ? ei[2 * e] : ei[e]) : 0;
    } else if (t < 2 * EB) {
      int tt = t - EB;
      int e = gbase + tt;
      ed[tt] = (e < E) ? (is64 ? ei[2 * E + 2 * e] : ei[E + e]) : 0;
    }
    __syncthreads();
    {
      const int e = t >> 2;
      const int c0 = (t & 3) * 32;
      const int si = es[e], di = ed[e];
      float xi0 = x[di * 3], xi1 = x[di * 3 + 1], xi2 = x[di * 3 + 2];
      float msg[6];
      msg[0] = xi0; msg[1] = xi1; msg[2] = xi2;
      msg[3] = x[si * 3] - xi0; msg[4] = x[si * 3 + 1] - xi1; msg[5] = x[si * 3 + 2] - xi2;
      unsigned int* d32 = (unsigned int*)uA;
      const int base32 = (e * PADROW + c0) >> 1;
      #pragma unroll
      for (int cc = 0; cc < 32; cc += 2) {
        float u0 = b1s[c0 + cc], u1 = b1s[c0 + cc + 1];
        #pragma unroll
        for (int d = 0; d < 6; ++d) {
          u0 += msg[d] * w1s[d * NHID + c0 + cc];
          u1 += msg[d] * w1s[d * NHID + c0 + cc + 1];
        }
        d32[base32 + (cc >> 1)] = pack2(fmaxf(u0, 0.f), fmaxf(u1, 0.f));
      }
    }
    __syncthreads();

    floatx4 acc[8];
    #pragma unroll
    for (int nt = 0; nt < 8; ++nt) { floatx4 z = {0.f, 0.f, 0.f, 0.f}; acc[nt] = z; }
    mfma_block(uA, bf, acc, w, m, q);

    #pragma unroll
    for (int nt = 0; nt < 8; ++nt) {
      const int c = nt * 16 + m;
      const float bb = b2s[c];
      const int kst = m * 8 + nt;
      #pragma unroll
      for (int r = 0; r < 4; ++r) {
        const int erow = 16 * w + q * 4 + r;
        if (gbase + erow < E) {
          float hb = acc[nt][r] + bb;
          if (hb > 0.f) {
            unsigned int v = (unsigned int)f2bf(hb);
            casmax(aggu + (size_t)ed[erow] * 64 + (kst >> 1), v << (16 * (kst & 1)));
          }
        }
      }
    }
    __syncthreads();
  }
}

// ---------------- fused node MLPs: enc (w3) + dec (w4,w5), agg16 input ----------------
// R9 structure (barriers B0/B1/B2/B3) — R10's barrier removal regressed.
// R15 lesson applies here too: acc zero-init FROZEN (bias in epilogue).

__global__ __launch_bounds__(256, 2) void encdec_kernel(
    const float* __restrict__ w3, const float* __restrict__ b3,
    const float* __restrict__ w4, const float* __restrict__ b4,
    const float* __restrict__ w5, const float* __restrict__ b5,
    const float* __restrict__ pos, const unsigned short* __restrict__ agg16,
    float* __restrict__ out, int N) {
  __shared__ unsigned short uA[EB * PADROW];
  __shared__ short8 w4f[2048];                    // k-permuted w4 frags
  __shared__ float w5s[NHID * 3];

  const int t = threadIdx.x;
  const int lane = t & 63;
  const int w = t >> 6;
  const int m = lane & 15;
  const int q = lane >> 4;

  float b3c[8], b4c[8];
  #pragma unroll
  for (int nt = 0; nt < 8; ++nt) { b3c[nt] = b3[nt * 16 + m]; b4c[nt] = b4[nt * 16 + m]; }

  short8 bf3[32];
  load_bfrags_perm(w3, bf3, m, q);                // k-permuted (agg16 is kstore-ordered)

  for (int idx = t; idx < 2048; idx += 256) {
    const int fg = idx >> 6, ln = idx & 63;
    const int mm = ln & 15;
    const int kc = fg >> 3, nt = fg & 7;
    short8 v;
    #pragma unroll
    for (int j = 0; j < 8; ++j) {
      const int khw = kc * 32 + (ln >> 4) * 8 + j;
      const int ctrue = ((khw & 7) << 4) | (khw >> 3);
      v[j] = (short)f2bf(w4[ctrue * NHID + nt * 16 + mm]);
    }
    w4f[idx] = v;
  }
  for (int i = t; i < NHID * 3; i += 256) w5s[i] = w5[i];
  const float b50 = b5[0], b51 = b5[1], b52 = b5[2];

  const int ch = t & 15;
  const int rr = t >> 4;
  const int nb = (N + EB - 1) / EB;
  __syncthreads();

  uint4 rv[4];
  const uint4 uz = make_uint4(0u, 0u, 0u, 0u);
  {
    const int b0 = blockIdx.x;
    #pragma unroll
    for (int k = 0; k < 4; ++k) {
      const int node = b0 * EB + rr + 16 * k;
      rv[k] = (b0 < nb && node < N) ? ((const uint4*)agg16)[(size_t)node * 16 + ch] : uz;
    }
  }

  for (int batch = blockIdx.x; batch < nb; batch += gridDim.x) {
    const int base = batch * EB;
    #pragma unroll
    for (int k = 0; k < 4; ++k)
      *(uint4*)(&uA[(rr + 16 * k) * PADROW + ch * 8]) = rv[k];
    __syncthreads();   // B0

    {
      const int nxb = batch + gridDim.x;
      #pragma unroll
      for (int k = 0; k < 4; ++k) {
        const int node = nxb * EB + rr + 16 * k;
        rv[k] = (nxb < nb && node < N) ? ((const uint4*)agg16)[(size_t)node * 16 + ch] : uz;
      }
    }

    floatx4 acc[8];
    #pragma unroll
    for (int nt = 0; nt < 8; ++nt) { floatx4 z = {0.f, 0.f, 0.f, 0.f}; acc[nt] = z; }
    mfma_block(uA, bf3, acc, w, m, q);
    __syncthreads();   // B1

    #pragma unroll
    for (int r = 0; r < 4; ++r) {
      union { short8 s; uint4 u; } cv;
      cv.u = make_uint4(
        pkbf(acc[0][r] + b3c[0], acc[1][r] + b3c[1]),
        pkbf(acc[2][r] + b3c[2], acc[3][r] + b3c[3]),
        pkbf(acc[4][r] + b3c[4], acc[5][r] + b3c[5]),
        pkbf(acc[6][r] + b3c[6], acc[7][r] + b3c[7]));
      *(short8*)(&uA[(16 * w + q * 4 + r) * PADROW + m * 8]) = cv.s;
    }
    __syncthreads();   // B2

    #pragma unroll
    for (int nt = 0; nt < 8; ++nt) { floatx4 z = {0.f, 0.f, 0.f, 0.f}; acc[nt] = z; }
    #pragma unroll
    for (int kc = 0; kc < 4; ++kc) {
      short8 a = *(const short8*)(&uA[(16 * w + m) * PADROW + kc * 32 + q * 8]);
      #pragma unroll
      for (int nt = 0; nt < 8; ++nt)
        acc[nt] = __builtin_amdgcn_mfma_f32_16x16x32_bf16(a, w4f[(kc * 8 + nt) * 64 + lane],
                                                          acc[nt], 0, 0, 0);
    }

    float p[4][3];
    #pragma unroll
    for (int r = 0; r < 4; ++r) { p[r][0] = 0.f; p[r][1] = 0.f; p[r][2] = 0.f; }
    #pragma unroll
    for (int nt = 0; nt < 8; ++nt) {
      const int c = nt * 16 + m;
      const float bb = b4c[nt];
      const float w50 = w5s[c * 3], w51 = w5s[c * 3 + 1], w52 = w5s[c * 3 + 2];
      #pragma unroll
      for (int r = 0; r < 4; ++r) {
        float tv = fmaxf(acc[nt][r] + bb, 0.f);
        p[r][0] += tv * w50; p[r][1] += tv * w51; p[r][2] += tv * w52;
      }
    }
    #pragma unroll
    for (int off = 8; off >= 1; off >>= 1) {
      #pragma unroll
      for (int r = 0; r < 4; ++r) {
        p[r][0] += __shfl_xor(p[r][0], off, 16);
        p[r][1] += __shfl_xor(p[r][1], off, 16);
        p[r][2] += __shfl_xor(p[r][2], off, 16);
      }
    }
    if (m == 0) {
      #pragma unroll
      for (int r = 0; r < 4; ++r) {
        const int node = base + 16 * w + q * 4 + r;
        if (node < N) {
          out[node * 3]     = pos[node * 3]     + 0.1f * tanhf(p[r][0] + b50);
          out[node * 3 + 1] = pos[node * 3 + 1] + 0.1f * tanhf(p[r][1] + b51);
          out[node * 3 + 2] = pos[node * 3 + 2] + 0.1f * tanhf(p[r][2] + b52);
        }
      }
    }
    __syncthreads();   // B3
  }
}

extern "C" void kernel_launch(void* const* d_in, const int* in_sizes, int n_in,
                              void* d_out, int out_size, void* d_ws, size_t ws_size,
                              hipStream_t stream) {
  const float* x   = (const float*)d_in[0];
  const float* pos = (const float*)d_in[1];
  const int*   ei  = (const int*)d_in[2];
  const float* w1  = (const float*)d_in[3];
  const float* b1  = (const float*)d_in[4];
  const float* w2  = (const float*)d_in[5];
  const float* b2  = (const float*)d_in[6];
  const float* w3  = (const float*)d_in[7];
  const float* b3  = (const float*)d_in[8];
  const float* w4  = (const float*)d_in[9];
  const float* b4  = (const float*)d_in[10];
  const float* w5  = (const float*)d_in[11];
  const float* b5  = (const float*)d_in[12];
  float* out = (float*)d_out;

  const int N = in_sizes[0] / 3;
  const int E = in_sizes[2] / 2;
  const int nbuck = (N + 255) >> 8;

  char* ws = (char*)d_ws;
  unsigned short* agg16 = (unsigned short*)ws;                // N*128 u16 (kstore order)
  const size_t aggB = (size_t)N * NHID * sizeof(unsigned short);
  const size_t midB = (((size_t)E * 4) + 15) & ~(size_t)15;   // u32-packed mid
  unsigned int* mid32 = (unsigned int*)(ws + aggB);
  int2* sorted = (int2*)(ws + aggB + midB);
  int*  mat    = (int*)(ws + aggB + midB + (size_t)E * 8);
  int*  btot   = mat + (size_t)nbuck * PB;
  int*  bstart = btot + nbuck;
  const size_t needed = aggB + midB + (size_t)E * 8 + ((size_t)nbuck * PB + nbuck + 520) * 4;

  if (ws_size >= needed && nbuck <= 511 && E >= 64) {
    part_hist<<<2048, 256, 0, stream>>>(ei, mat, E, nbuck, (float4*)agg16, N * 16);
    scan_rows<<<nbuck, 512, 0, stream>>>(mat, btot, nbuck);
    part_scatter<<<PB, 512, 0, stream>>>(ei, mat, btot, bstart, mid32, E, nbuck);
    bucket_sort<<<nbuck, 512, 0, stream>>>(mid32, bstart, sorted);
    edge_sorted_kernel<<<512, 512, 0, stream>>>(x, sorted, w1, b1, w2, b2,
                                                (unsigned int*)agg16, N, E);
  } else {
    int* flag2 = (int*)(ws + aggB);
    zero_detect_kernel<<<2048, 256, 0, stream>>>((float4*)agg16, N * 16, ei, flag2);
    edge_atomic_kernel<<<512, 256, 0, stream>>>(x, ei, w1, b1, w2, b2,
                                                (unsigned int*)agg16, flag2, N, E);
  }
  encdec_kernel<<<512, 256, 0, stream>>>(w3, b3, w4, b4, w5, b5, pos, agg16, out, N);
}

// Round 8
// 323.496 us; speedup vs baseline: 1.0657x; 1.0262x over previous
//
#include <hip/hip_runtime.h>
#include <hip/hip_bf16.h>

typedef __attribute__((ext_vector_type(8))) short short8;
typedef __attribute__((ext_vector_type(4))) float floatx4;
typedef __attribute__((ext_vector_type(2))) unsigned short ushortx2;

#define NHID 128
#define PADROW 136   // u16 row stride: 272B, 16B-aligned b128, benign banking
#define EB 64        // nodes per tile (encdec / fallback)
#define EB2 128      // edges per tile (edge_sorted)
#define PB 512       // partition blocks for the 2-level sort (R20)

__device__ __forceinline__ unsigned short f2bf(float x) {
  unsigned int u = __float_as_uint(x);
  u += 0x7FFFu + ((u >> 16) & 1u);          // RNE
  return (unsigned short)(u >> 16);
}

__device__ __forceinline__ unsigned int pkbf(float a, float b) {
  __hip_bfloat162 h = __float22bfloat162_rn(make_float2(a, b));
  union { __hip_bfloat162 h; unsigned int u; } cv;
  cv.h = h;
  return cv.u;
}

__device__ __forceinline__ unsigned int pack2(float a, float b) {
  return (unsigned int)f2bf(a) | ((unsigned int)f2bf(b) << 16);
}

// packed u16 max (v_pk_max_u16)
__device__ __forceinline__ unsigned int pkmax(unsigned int a, unsigned int b) {
  union { unsigned int u; ushortx2 v; } x, y;
  x.u = a; y.u = b;
  x.v = __builtin_elementwise_max(x.v, y.v);
  return x.u;
}

__device__ __forceinline__ void casmax(unsigned int* ap, unsigned int run) {
  unsigned int old = *ap;
  while (true) {
    unsigned int mx = pkmax(old, run);
    if (mx == old) break;
    unsigned int got = atomicCAS(ap, old, mx);
    if (got == old) break;
    old = got;
  }
}

// all-wave inline int64 probe: odd int32 slots all-zero <=> int64 edge_index
__device__ __forceinline__ bool detect64(const int* __restrict__ ei) {
  unsigned long long b = __ballot(ei[2 * (threadIdx.x & 63) + 1] != 0);
  return b == 0ULL;
}

// 32 loop-invariant B-fragments of a 128x128 row-major f32 weight (registers), natural k.
__device__ __forceinline__ void load_bfrags(const float* __restrict__ wmat,
                                            short8* bf, int m, int q) {
  #pragma unroll
  for (int kc = 0; kc < 4; ++kc) {
    #pragma unroll
    for (int nt = 0; nt < 8; ++nt) {
      short8 v;
      #pragma unroll
      for (int j = 0; j < 8; ++j)
        v[j] = (short)f2bf(wmat[(kc * 32 + q * 8 + j) * NHID + nt * 16 + m]);
      bf[kc * 8 + nt] = v;
    }
  }
}

// same but k-permuted: B[khw][n] = w[pi(khw)][n], pi(k) = ((k&7)<<4)|(k>>3)
__device__ __forceinline__ void load_bfrags_perm(const float* __restrict__ wmat,
                                                 short8* bf, int m, int q) {
  #pragma unroll
  for (int kc = 0; kc < 4; ++kc) {
    #pragma unroll
    for (int nt = 0; nt < 8; ++nt) {
      short8 v;
      #pragma unroll
      for (int j = 0; j < 8; ++j) {
        const int khw = kc * 32 + q * 8 + j;
        const int ctrue = ((khw & 7) << 4) | (khw >> 3);
        v[j] = (short)f2bf(wmat[ctrue * NHID + nt * 16 + m]);
      }
      bf[kc * 8 + nt] = v;
    }
  }
}

__device__ __forceinline__ void mfma_block(const unsigned short* uA,
                                           const short8* bf, floatx4* acc,
                                           int w, int m, int q) {
  #pragma unroll
  for (int kc = 0; kc < 4; ++kc) {
    short8 a = *(const short8*)(uA + (16 * w + m) * PADROW + kc * 32 + q * 8);
    #pragma unroll
    for (int nt = 0; nt < 8; ++nt)
      acc[nt] = __builtin_amdgcn_mfma_f32_16x16x32_bf16(a, bf[kc * 8 + nt],
                                                        acc[nt], 0, 0, 0);
  }
}

// fallback-path zero (agg16) + detect->flag
__global__ void zero_detect_kernel(float4* __restrict__ p, int n4,
                                   const int* __restrict__ ei, int* __restrict__ flag) {
  if (blockIdx.x == 0 && threadIdx.x < 64) {
    unsigned long long b = __ballot(ei[2 * threadIdx.x + 1] != 0);
    if (threadIdx.x == 0) flag[0] = (b == 0ULL) ? 1 : 0;
  }
  int i = blockIdx.x * blockDim.x + threadIdx.x;
  int stride = gridDim.x * blockDim.x;
  float4 z = make_float4(0.f, 0.f, 0.f, 0.f);
  for (; i < n4; i += stride) p[i] = z;
}

// ---------------- 2-level counting sort by dst (no global atomics) ----------------
// Split pipeline (R11): grid-barrier fusion regressed badly (R12/R13).
// R20: PB 256->512 (part_scatter 2 blocks/CU); mid packed to u32
// (s | (d&255)<<24, d>>8 == bucket id). Gained ~2.4 µs — sort path is
// latency/launch-bound, not BW-bound.

// A1: per-partition LDS histogram over coarse buckets (dst>>8); tail blocks zero agg16
__global__ __launch_bounds__(256) void part_hist(const int* __restrict__ ei,
                                                 int* __restrict__ mat, int E, int nbuck,
                                                 float4* __restrict__ aggz, int n4) {
  const int bl = blockIdx.x, t = threadIdx.x;
  if (bl >= PB) {
    int i = (bl - PB) * 256 + t;
    const int st = (gridDim.x - PB) * 256;
    float4 z = make_float4(0.f, 0.f, 0.f, 0.f);
    for (; i < n4; i += st) aggz[i] = z;
    return;
  }
  __shared__ int hist[512];
  const bool is64 = detect64(ei);
  for (int i = t; i < nbuck; i += 256) hist[i] = 0;
  __syncthreads();
  const int chunk = (E + PB - 1) / PB;
  const int lo = bl * chunk;
  const int hi = min(lo + chunk, E);
  for (int i = lo + t; i < hi; i += 256) {
    int d = is64 ? ei[2 * E + 2 * i] : ei[E + i];
    atomicAdd(&hist[d >> 8], 1);
  }
  __syncthreads();
  for (int bu = t; bu < nbuck; bu += 256) mat[bu * PB + bl] = hist[bu];
}

// A2: per-bucket exclusive scan over the PB partitions (in place) + bucket totals
__global__ __launch_bounds__(512) void scan_rows(int* __restrict__ mat,
                                                 int* __restrict__ btot, int nbuck) {
  __shared__ int sh[512];
  const int bu = blockIdx.x, t = threadIdx.x;
  const int v = mat[bu * PB + t];
  sh[t] = v;
  __syncthreads();
  for (int off = 1; off < 512; off <<= 1) {
    int x = (t >= off) ? sh[t - off] : 0;
    __syncthreads();
    sh[t] += x;
    __syncthreads();
  }
  mat[bu * PB + t] = sh[t] - v;
  if (t == 511) btot[bu] = sh[511];
}

// A3: scatter into coarse-bucket regions; bucket starts scanned in-LDS from btot.
__global__ __launch_bounds__(512) void part_scatter(const int* __restrict__ ei,
                                                    const int* __restrict__ mat,
                                                    const int* __restrict__ btot,
                                                    int* __restrict__ bstart,
                                                    unsigned int* __restrict__ mid32,
                                                    int E, int nbuck) {
  __shared__ int off[512];
  __shared__ int bsS[512];
  const bool is64 = detect64(ei);
  const int bl = blockIdx.x, t = threadIdx.x;
  const int o0 = (t < 256 && t < nbuck) ? btot[t] : 0;
  const int o1 = (t < 256 && t + 256 < nbuck) ? btot[t + 256] : 0;
  if (t < 256) { bsS[t] = o0; bsS[t + 256] = o1; }
  __syncthreads();
  for (int o = 1; o < 256; o <<= 1) {
    int x0 = (t >= o && t < 256) ? bsS[t - o] : 0;
    int x1 = (t >= o && t < 256) ? bsS[256 + t - o] : 0;
    __syncthreads();
    if (t < 256) { bsS[t] += x0; bsS[256 + t] += x1; }
    __syncthreads();
  }
  const int tot0 = bsS[255];
  if (t < 256) bsS[256 + t] += tot0;
  __syncthreads();
  if (t < 256) {
    const int ex0 = bsS[t] - o0;
    const int ex1 = bsS[256 + t] - o1;
    if (bl == 0) { bstart[t] = ex0; bstart[256 + t] = ex1; }
    off[t]       = ex0 + ((t < nbuck) ? mat[t * PB + bl] : 0);
    off[256 + t] = ex1 + ((t + 256 < nbuck) ? mat[(t + 256) * PB + bl] : 0);
  }
  __syncthreads();
  const int chunk = (E + PB - 1) / PB;
  const int lo = bl * chunk;
  const int hi = min(lo + chunk, E);
  for (int i = lo + t; i < hi; i += 512) {
    int s = is64 ? ei[2 * i]         : ei[i];
    int d = is64 ? ei[2 * E + 2 * i] : ei[E + i];
    int p = atomicAdd(&off[d >> 8], 1);
    mid32[p] = (unsigned int)s | ((unsigned int)(d & 255) << 24);
  }
}

// B: per-bucket counting sort by exact dst (256 local nodes), L2-resident traffic.
__global__ __launch_bounds__(512) void bucket_sort(const unsigned int* __restrict__ mid32,
                                                   const int* __restrict__ bstart,
                                                   int2* __restrict__ sorted) {
  __shared__ int h[256], cnt[256];
  const int bu = blockIdx.x, t = threadIdx.x;
  const int lo = bstart[bu], hi = bstart[bu + 1];
  if (t < 256) { h[t] = 0; cnt[t] = 0; }
  __syncthreads();
  for (int i = lo + t; i < hi; i += 512) atomicAdd(&h[mid32[i] >> 24], 1);
  __syncthreads();
  const int v = (t < 256) ? h[t] : 0;
  for (int off = 1; off < 256; off <<= 1) {
    int x = (t >= off && t < 256) ? h[t - off] : 0;
    __syncthreads();
    if (t < 256) h[t] += x;
    __syncthreads();
  }
  const int excl = (t < 256) ? h[t] - v : 0;
  __syncthreads();
  if (t < 256) h[t] = excl;
  __syncthreads();
  for (int i = lo + t; i < hi; i += 512) {
    const unsigned int e = mid32[i];
    const int dl = (int)(e >> 24);
    const int p = lo + h[dl] + atomicAdd(&cnt[dl], 1);
    sorted[p] = make_int2((int)(e & 0xFFFFFFu), (bu << 8) | dl);
  }
}

// ---------------- fused edge MLP (both layers MFMA) + segmented max ----------------
// FROZEN RULES (R10/R14/R15): acc MUST be zero-init; regs sit at 64 arch + 64
// acc = the residency-bucket edge — NO loop-invariant live-range growth.
// R16: layer-1 bias via spare K-slot. R17: layer-2 wave remap (32 rows x 64 cols).
// R18 REVERTED: SQ_LDS_BANK_CONFLICT here counts benign 2-way wave64 aliasing
// (exactly 4/edge), NOT stalls — don't chase it.
// R19: barrier F removed, prevd/nextd register-captured. 5 barriers/tile.
// R21: stage-3 pass 1 restructured — static 16-row scan. The old dynamic
// while-loop issued its hS reads through a variable-bound inner loop
// (serialized ds_read->waitcnt->pkmax chains + 64-bit clz/ffs per run).
// Now: 16 static ds_read_b32 (one lgkmcnt drain), boundaries from a
// precomputed 16-bit window W of the run-start bitmask; ffs survives only
// in the rare owner tail. Semantics identical (pmS / contained / owner /
// bnd cases mapped 1:1). All v[] indices compile-time (scratch rule #20).
// agg16: u16[N][128] in kstore (k-permuted) order.

__global__ __launch_bounds__(512, 2) void edge_sorted_kernel(
    const float* __restrict__ x, const int2* __restrict__ sorted,
    const float* __restrict__ w1, const float* __restrict__ b1,
    const float* __restrict__ w2, const float* __restrict__ b2,
    unsigned int* aggu, int N, int E) {
  __shared__ unsigned short us[EB2 * PADROW];     // uA then hS (bf16)
  __shared__ short8 w2f[2048];                    // 32 frags x 64 lanes, k-permuted
  __shared__ int esS[EB2], edS[EB2];
  __shared__ int pn[2];                           // dst before / after tile (-2 = none)
  __shared__ unsigned long long maskS[2];         // run-start bitmask
  __shared__ unsigned int pmS[8][64];             // per-quarter partial of run covering r0

  const int t = threadIdx.x;
  const int lane = t & 63;
  const int w = t >> 6;                           // wave 0..7
  const int m = lane & 15;
  const int q = lane >> 4;
  const int rowg = w >> 1;                        // layer-2: rows [32*rowg, +32)
  const int colg = w & 1;                         // layer-2: true cols [64*colg, +64)

  float b2c[4];
  #pragma unroll
  for (int nt = 0; nt < 4; ++nt) b2c[nt] = b2[(4 * colg + nt) * 16 + m];

  short8 bf1[8];
  #pragma unroll
  for (int nt = 0; nt < 8; ++nt) {
    short8 v;
    #pragma unroll
    for (int j = 0; j < 8; ++j) {
      short sj = 0;
      if (q == 0 && j < 6) sj = (short)f2bf(w1[j * NHID + nt * 16 + m]);
      else if (q == 0 && j == 6) sj = (short)f2bf(b1[nt * 16 + m]);  // bias row, k=6
      v[j] = sj;
    }
    bf1[nt] = v;
  }

  for (int idx = t; idx < 2048; idx += 512) {
    const int fg = idx >> 6, ln = idx & 63;
    const int mm = ln & 15;
    const int kc = fg >> 3, nt = fg & 7;
    short8 v;
    #pragma unroll
    for (int j = 0; j < 8; ++j) {
      const int khw = kc * 32 + (ln >> 4) * 8 + j;
      const int ctrue = ((khw & 7) << 4) | (khw >> 3);
      v[j] = (short)f2bf(w2[ctrue * NHID + nt * 16 + mm]);
    }
    w2f[idx] = v;
  }

  const int jc = t & 63;                          // u32 col in kstore order
  const int quarter = t >> 6;                     // rows [16*quarter, +16)

  const int nbt = (E + EB2 - 1) / EB2;
  __syncthreads();

  // preload first tile's index data
  int2 sv = make_int2(0, -1);
  {
    const int tile0 = blockIdx.x;
    const int gb = tile0 * EB2;
    if (t < EB2) {
      const int e = gb + t;
      if (tile0 < nbt && e < E) sv = sorted[e];
    } else if (t == EB2) {
      sv.y = (tile0 < nbt && gb > 0) ? sorted[gb - 1].y : -2;
    } else if (t == EB2 + 1) {
      sv.y = (tile0 < nbt && gb + EB2 < E) ? sorted[gb + EB2].y : -2;
    }
  }

  for (int tile = blockIdx.x; tile < nbt; tile += gridDim.x) {
    if (t < EB2) { esS[t] = sv.x; edS[t] = sv.y; }
    else if (t == EB2) pn[0] = sv.y;
    else if (t == EB2 + 1) pn[1] = sv.y;
    __syncthreads();   // A

    if (w == 0) {
      int d0 = edS[lane];
      int dp0 = (lane == 0) ? -9 : edS[lane - 1];
      unsigned long long mk0 = __ballot(lane == 0 || d0 != dp0);
      int d1 = edS[64 + lane];
      int dp1 = edS[63 + lane];
      unsigned long long mk1 = __ballot(d1 != dp1);
      if (lane == 0) { maskS[0] = mk0; maskS[1] = mk1; }
    }

    // layer 1 (zero acc init — FROZEN; bias enters via K-slot 6)
    floatx4 acc[8];
    #pragma unroll
    for (int nt = 0; nt < 8; ++nt) { floatx4 z = {0.f, 0.f, 0.f, 0.f}; acc[nt] = z; }
    short8 a1 = {0, 0, 0, 0, 0, 0, 0, 0};
    if (q == 0) {
      const int e = 16 * w + m;
      const int si = esS[e];
      const int d0 = edS[e];
      const int di = (d0 < 0) ? 0 : d0;
      float xi0 = x[di * 3], xi1 = x[di * 3 + 1], xi2 = x[di * 3 + 2];
      float dd0 = x[si * 3] - xi0, dd1 = x[si * 3 + 1] - xi1, dd2 = x[si * 3 + 2] - xi2;
      union { short8 s; uint4 u; } cv;
      cv.u = make_uint4(pkbf(xi0, xi1), pkbf(xi2, dd0), pkbf(dd1, dd2),
                        0x00003F80u);             // k=6: 1.0 (bias lane), k=7: 0
      a1 = cv.s;
    }
    #pragma unroll
    for (int nt = 0; nt < 8; ++nt)
      acc[nt] = __builtin_amdgcn_mfma_f32_16x16x32_bf16(a1, bf1[nt], acc[nt], 0, 0, 0);

    #pragma unroll
    for (int r = 0; r < 4; ++r) {
      union { short8 s; uint4 u; } cv;
      cv.u = make_uint4(
        pkbf(fmaxf(acc[0][r], 0.f), fmaxf(acc[1][r], 0.f)),
        pkbf(fmaxf(acc[2][r], 0.f), fmaxf(acc[3][r], 0.f)),
        pkbf(fmaxf(acc[4][r], 0.f), fmaxf(acc[5][r], 0.f)),
        pkbf(fmaxf(acc[6][r], 0.f), fmaxf(acc[7][r], 0.f)));
      *(short8*)(&us[(16 * w + q * 4 + r) * PADROW + m * 8]) = cv.s;
    }
    __syncthreads();   // B

    // layer 2 (zero acc init — FROZEN; bias in epilogue; R17 remap)
    #pragma unroll
    for (int nt = 0; nt < 8; ++nt) { floatx4 z = {0.f, 0.f, 0.f, 0.f}; acc[nt] = z; }
    #pragma unroll
    for (int kc = 0; kc < 4; ++kc) {
      short8 a0 = *(const short8*)(&us[(32 * rowg + m) * PADROW + kc * 32 + q * 8]);
      short8 a1r = *(const short8*)(&us[(32 * rowg + 16 + m) * PADROW + kc * 32 + q * 8]);
      #pragma unroll
      for (int nt = 0; nt < 4; ++nt) {
        short8 b = w2f[(kc * 8 + 4 * colg + nt) * 64 + lane];
        acc[nt]     = __builtin_amdgcn_mfma_f32_16x16x32_bf16(a0, b, acc[nt], 0, 0, 0);
        acc[4 + nt] = __builtin_amdgcn_mfma_f32_16x16x32_bf16(a1r, b, acc[4 + nt], 0, 0, 0);
      }
    }
    __syncthreads();   // C

    #pragma unroll
    for (int rb = 0; rb < 2; ++rb) {
      #pragma unroll
      for (int r = 0; r < 4; ++r) {
        uint2 uu;
        uu.x = pkbf(fmaxf(acc[rb * 4 + 0][r] + b2c[0], 0.f),
                    fmaxf(acc[rb * 4 + 1][r] + b2c[1], 0.f));
        uu.y = pkbf(fmaxf(acc[rb * 4 + 2][r] + b2c[2], 0.f),
                    fmaxf(acc[rb * 4 + 3][r] + b2c[3], 0.f));
        *(uint2*)(&us[(32 * rowg + 16 * rb + q * 4 + r) * PADROW + m * 8 + 4 * colg]) = uu;
      }
    }
    __syncthreads();   // D: hS ready

    // prefetch next tile's index data
    {
      const int tn = tile + gridDim.x;
      const int gb = tn * EB2;
      int2 nv = make_int2(0, -1);
      if (t < EB2) {
        const int e = gb + t;
        if (tn < nbt && e < E) nv = sorted[e];
      } else if (t == EB2) {
        nv.y = (tn < nbt && gb > 0) ? sorted[gb - 1].y : -2;
      } else if (t == EB2 + 1) {
        nv.y = (tn < nbt && gb + EB2 < E) ? sorted[gb + EB2].y : -2;
      }
      sv = nv;
    }

    // stage 3 pass 1 (R21): static 16-row scan.
    int os = -1, onxt = 0, od = -1; unsigned int opart = 0;
    int prevd, nextd;
    {
      const unsigned long long mk0 = maskS[0], mk1 = maskS[1];
      prevd = pn[0]; nextd = pn[1];
      const int r0 = quarter * 16;
      const unsigned int* us32 = (const unsigned int*)us;

      unsigned int v[16];
      #pragma unroll
      for (int r = 0; r < 16; ++r)
        v[r] = us32[(r0 + r) * (PADROW >> 1) + jc];

      // W bit r = "row r0+r is the last row of its run" = bit (r0+r+1) of the
      // 129-bit start mask (mk0 | mk1<<64 | 1<<128).
      const unsigned long long Am = (r0 < 64) ? mk0 : mk1;
      const unsigned long long Bm = (r0 < 64) ? mk1 : 1ULL;
      const int sh = (r0 & 63) + 1;               // 1..49
      const unsigned int W =
          (unsigned int)((Am >> sh) | (Bm << (64 - sh))) & 0xFFFFu;
      const int br0 =
          (int)((((r0 < 64) ? (mk0 >> r0) : (mk1 >> (r0 - 64))) & 1ULL));
      int s = br0 ? r0 : -1;                      // -1: run covering r0 started earlier
      unsigned int cur = 0;

      #pragma unroll
      for (int r = 0; r < 16; ++r) {
        cur = pkmax(cur, v[r]);
        if ((W >> r) & 1u) {                      // run ends at row r0+r
          if (s < 0) {
            pmS[quarter][jc] = cur;               // partial of run covering r0
          } else {
            const int d = edS[s];
            if (d >= 0) {
              const bool bnd = (s == 0 && prevd == d) ||
                               (r0 + r == 127 && nextd == d);
              unsigned int* ap = aggu + (size_t)d * 64 + jc;
              if (!bnd) *ap = cur;
              else if (cur) casmax(ap, cur);
            }
          }
          cur = 0; s = r0 + r + 1;
        }
      }

      if (!((W >> 15) & 1u)) {                    // last run extends past r1
        if (s < 0) {
          pmS[quarter][jc] = cur;                 // quarter fully inside a run
        } else {                                  // owner of a spanning run
          const int e0 = r0 + 15;                 // quarters 0..6 only (q7: W15=1)
          int nxt;
          if (e0 < 63) {
            unsigned long long ab = mk0 & (~0ULL << (e0 + 1));
            if (ab) nxt = __builtin_ffsll((long long)ab) - 1;
            else    nxt = mk1 ? 64 + __builtin_ffsll((long long)mk1) - 1 : 128;
          } else if (e0 == 63) {
            nxt = mk1 ? 64 + __builtin_ffsll((long long)mk1) - 1 : 128;
          } else {
            unsigned long long ab = mk1 & (~0ULL << (e0 - 63));
            nxt = ab ? 64 + __builtin_ffsll((long long)ab) - 1 : 128;
          }
          os = s; onxt = nxt; od = edS[s]; opart = cur;
        }
      }
    }
    __syncthreads();   // E: pmS ready

    // stage 3 pass 2: owners combine partials and write once.
    // Touches only pmS + registers (prevd/nextd/od captured) -> no barrier F.
    if (os >= 0 && od >= 0) {
      const int endq = (onxt - 1) >> 4;
      #pragma unroll 4
      for (int qq = quarter + 1; qq <= endq; ++qq)
        opart = pkmax(opart, pmS[qq][jc]);
      const bool bnd = (os == 0 && prevd == od) || (onxt == 128 && nextd == od);
      unsigned int* ap = aggu + (size_t)od * 64 + jc;
      if (!bnd) *ap = opart;
      else if (opart) casmax(ap, opart);
    }
  }
}

// ---------------- fallback: atomic edge kernel (small ws) ----------------

__global__ __launch_bounds__(256, 2) void edge_atomic_kernel(
    const float* __restrict__ x, const int* __restrict__ ei,
    const float* __restrict__ w1, const float* __restrict__ b1,
    const float* __restrict__ w2, const float* __restrict__ b2,
    unsigned int* aggu, const int* __restrict__ flag64, int N, int E) {
  __shared__ unsigned short uA[EB * PADROW];
  __shared__ float w1s[6 * NHID];
  __shared__ float b1s[NHID], b2s[NHID];
  __shared__ int es[EB], ed[EB];

  const int t = threadIdx.x;
  const int lane = t & 63;
  const int w = t >> 6;
  const int m = lane & 15;
  const int q = lane >> 4;

  for (int i = t; i < 6 * NHID; i += 256) w1s[i] = w1[i];
  if (t < NHID) { b1s[t] = b1[t]; b2s[t] = b2[t]; }

  short8 bf[32];
  load_bfrags(w2, bf, m, q);

  const bool is64 = (flag64[0] != 0);
  const int nb = (E + EB - 1) / EB;

  for (int batch = blockIdx.x; batch < nb; batch += gridDim.x) {
    const int gbase = batch * EB;
    if (t < EB) {
      int e = gbase + t;
      es[t] = (e < E) ? (is64 ? ei[2 * e] : ei[e]) : 0;
    } else if (t < 2 * EB) {
      int tt = t - EB;
      int e = gbase + tt;
      ed[tt] = (e < E) ? (is64 ? ei[2 * E + 2 * e] : ei[E + e]) : 0;
    }
    __syncthreads();
    {
      const int e = t >> 2;
      const int c0 = (t & 3) * 32;
      const int si = es[e], di = ed[e];
      float xi0 = x[di * 3], xi1 = x[di * 3 + 1], xi2 = x[di * 3 + 2];
      float msg[6];
      msg[0] = xi0; msg[1] = xi1; msg[2] = xi2;
      msg[3] = x[si * 3] - xi0; msg[4] = x[si * 3 + 1] - xi1; msg[5] = x[si * 3 + 2] - xi2;
      unsigned int* d32 = (unsigned int*)uA;
      const int base32 = (e * PADROW + c0) >> 1;
      #pragma unroll
      for (int cc = 0; cc < 32; cc += 2) {
        float u0 = b1s[c0 + cc], u1 = b1s[c0 + cc + 1];
        #pragma unroll
        for (int d = 0; d < 6; ++d) {
          u0 += msg[d] * w1s[d * NHID + c0 + cc];
          u1 += msg[d] * w1s[d * NHID + c0 + cc + 1];
        }
        d32[base32 + (cc >> 1)] = pack2(fmaxf(u0, 0.f), fmaxf(u1, 0.f));
      }
    }
    __syncthreads();

    floatx4 acc[8];
    #pragma unroll
    for (int nt = 0; nt < 8; ++nt) { floatx4 z = {0.f, 0.f, 0.f, 0.f}; acc[nt] = z; }
    mfma_block(uA, bf, acc, w, m, q);

    #pragma unroll
    for (int nt = 0; nt < 8; ++nt) {
      const int c = nt * 16 + m;
      const float bb = b2s[c];
      const int kst = m * 8 + nt;
      #pragma unroll
      for (int r = 0; r < 4; ++r) {
        const int erow = 16 * w + q * 4 + r;
        if (gbase + erow < E) {
          float hb = acc[nt][r] + bb;
          if (hb > 0.f) {
            unsigned int v = (unsigned int)f2bf(hb);
            casmax(aggu + (size_t)ed[erow] * 64 + (kst >> 1), v << (16 * (kst & 1)));
          }
        }
      }
    }
    __syncthreads();
  }
}

// ---------------- fused node MLPs: enc (w3) + dec (w4,w5), agg16 input ----------------
// R9 structure (barriers B0/B1/B2/B3) — R10's barrier removal regressed.
// R15 lesson applies here too: acc zero-init FROZEN (bias in epilogue).

__global__ __launch_bounds__(256, 2) void encdec_kernel(
    const float* __restrict__ w3, const float* __restrict__ b3,
    const float* __restrict__ w4, const float* __restrict__ b4,
    const float* __restrict__ w5, const float* __restrict__ b5,
    const float* __restrict__ pos, const unsigned short* __restrict__ agg16,
    float* __restrict__ out, int N) {
  __shared__ unsigned short uA[EB * PADROW];
  __shared__ short8 w4f[2048];                    // k-permuted w4 frags
  __shared__ float w5s[NHID * 3];

  const int t = threadIdx.x;
  const int lane = t & 63;
  const int w = t >> 6;
  const int m = lane & 15;
  const int q = lane >> 4;

  float b3c[8], b4c[8];
  #pragma unroll
  for (int nt = 0; nt < 8; ++nt) { b3c[nt] = b3[nt * 16 + m]; b4c[nt] = b4[nt * 16 + m]; }

  short8 bf3[32];
  load_bfrags_perm(w3, bf3, m, q);                // k-permuted (agg16 is kstore-ordered)

  for (int idx = t; idx < 2048; idx += 256) {
    const int fg = idx >> 6, ln = idx & 63;
    const int mm = ln & 15;
    const int kc = fg >> 3, nt = fg & 7;
    short8 v;
    #pragma unroll
    for (int j = 0; j < 8; ++j) {
      const int khw = kc * 32 + (ln >> 4) * 8 + j;
      const int ctrue = ((khw & 7) << 4) | (khw >> 3);
      v[j] = (short)f2bf(w4[ctrue * NHID + nt * 16 + mm]);
    }
    w4f[idx] = v;
  }
  for (int i = t; i < NHID * 3; i += 256) w5s[i] = w5[i];
  const float b50 = b5[0], b51 = b5[1], b52 = b5[2];

  const int ch = t & 15;
  const int rr = t >> 4;
  const int nb = (N + EB - 1) / EB;
  __syncthreads();

  uint4 rv[4];
  const uint4 uz = make_uint4(0u, 0u, 0u, 0u);
  {
    const int b0 = blockIdx.x;
    #pragma unroll
    for (int k = 0; k < 4; ++k) {
      const int node = b0 * EB + rr + 16 * k;
      rv[k] = (b0 < nb && node < N) ? ((const uint4*)agg16)[(size_t)node * 16 + ch] : uz;
    }
  }

  for (int batch = blockIdx.x; batch < nb; batch += gridDim.x) {
    const int base = batch * EB;
    #pragma unroll
    for (int k = 0; k < 4; ++k)
      *(uint4*)(&uA[(rr + 16 * k) * PADROW + ch * 8]) = rv[k];
    __syncthreads();   // B0

    {
      const int nxb = batch + gridDim.x;
      #pragma unroll
      for (int k = 0; k < 4; ++k) {
        const int node = nxb * EB + rr + 16 * k;
        rv[k] = (nxb < nb && node < N) ? ((const uint4*)agg16)[(size_t)node * 16 + ch] : uz;
      }
    }

    floatx4 acc[8];
    #pragma unroll
    for (int nt = 0; nt < 8; ++nt) { floatx4 z = {0.f, 0.f, 0.f, 0.f}; acc[nt] = z; }
    mfma_block(uA, bf3, acc, w, m, q);
    __syncthreads();   // B1

    #pragma unroll
    for (int r = 0; r < 4; ++r) {
      union { short8 s; uint4 u; } cv;
      cv.u = make_uint4(
        pkbf(acc[0][r] + b3c[0], acc[1][r] + b3c[1]),
        pkbf(acc[2][r] + b3c[2], acc[3][r] + b3c[3]),
        pkbf(acc[4][r] + b3c[4], acc[5][r] + b3c[5]),
        pkbf(acc[6][r] + b3c[6], acc[7][r] + b3c[7]));
      *(short8*)(&uA[(16 * w + q * 4 + r) * PADROW + m * 8]) = cv.s;
    }
    __syncthreads();   // B2

    #pragma unroll
    for (int nt = 0; nt < 8; ++nt) { floatx4 z = {0.f, 0.f, 0.f, 0.f}; acc[nt] = z; }
    #pragma unroll
    for (int kc = 0; kc < 4; ++kc) {
      short8 a = *(const short8*)(&uA[(16 * w + m) * PADROW + kc * 32 + q * 8]);
      #pragma unroll
      for (int nt = 0; nt < 8; ++nt)
        acc[nt] = __builtin_amdgcn_mfma_f32_16x16x32_bf16(a, w4f[(kc * 8 + nt) * 64 + lane],
                                                          acc[nt], 0, 0, 0);
    }

    float p[4][3];
    #pragma unroll
    for (int r = 0; r < 4; ++r) { p[r][0] = 0.f; p[r][1] = 0.f; p[r][2] = 0.f; }
    #pragma unroll
    for (int nt = 0; nt < 8; ++nt) {
      const int c = nt * 16 + m;
      const float bb = b4c[nt];
      const float w50 = w5s[c * 3], w51 = w5s[c * 3 + 1], w52 = w5s[c * 3 + 2];
      #pragma unroll
      for (int r = 0; r < 4; ++r) {
        float tv = fmaxf(acc[nt][r] + bb, 0.f);
        p[r][0] += tv * w50; p[r][1] += tv * w51; p[r][2] += tv * w52;
      }
    }
    #pragma unroll
    for (int off = 8; off >= 1; off >>= 1) {
      #pragma unroll
      for (int r = 0; r < 4; ++r) {
        p[r][0] += __shfl_xor(p[r][0], off, 16);
        p[r][1] += __shfl_xor(p[r][1], off, 16);
        p[r][2] += __shfl_xor(p[r][2], off, 16);
      }
    }
    if (m == 0) {
      #pragma unroll
      for (int r = 0; r < 4; ++r) {
        const int node = base + 16 * w + q * 4 + r;
        if (node < N) {
          out[node * 3]     = pos[node * 3]     + 0.1f * tanhf(p[r][0] + b50);
          out[node * 3 + 1] = pos[node * 3 + 1] + 0.1f * tanhf(p[r][1] + b51);
          out[node * 3 + 2] = pos[node * 3 + 2] + 0.1f * tanhf(p[r][2] + b52);
        }
      }
    }
    __syncthreads();   // B3
  }
}

extern "C" void kernel_launch(void* const* d_in, const int* in_sizes, int n_in,
                              void* d_out, int out_size, void* d_ws, size_t ws_size,
                              hipStream_t stream) {
  const float* x   = (const float*)d_in[0];
  const float* pos = (const float*)d_in[1];
  const int*   ei  = (const int*)d_in[2];
  const float* w1  = (const float*)d_in[3];
  const float* b1  = (const float*)d_in[4];
  const float* w2  = (const float*)d_in[5];
  const float* b2  = (const float*)d_in[6];
  const float* w3  = (const float*)d_in[7];
  const float* b3  = (const float*)d_in[8];
  const float* w4  = (const float*)d_in[9];
  const float* b4  = (const float*)d_in[10];
  const float* w5  = (const float*)d_in[11];
  const float* b5  = (const float*)d_in[12];
  float* out = (float*)d_out;

  const int N = in_sizes[0] / 3;
  const int E = in_sizes[2] / 2;
  const int nbuck = (N + 255) >> 8;

  char* ws = (char*)d_ws;
  unsigned short* agg16 = (unsigned short*)ws;                // N*128 u16 (kstore order)
  const size_t aggB = (size_t)N * NHID * sizeof(unsigned short);
  const size_t midB = (((size_t)E * 4) + 15) & ~(size_t)15;   // u32-packed mid
  unsigned int* mid32 = (unsigned int*)(ws + aggB);
  int2* sorted = (int2*)(ws + aggB + midB);
  int*  mat    = (int*)(ws + aggB + midB + (size_t)E * 8);
  int*  btot   = mat + (size_t)nbuck * PB;
  int*  bstart = btot + nbuck;
  const size_t needed = aggB + midB + (size_t)E * 8 + ((size_t)nbuck * PB + nbuck + 520) * 4;

  if (ws_size >= needed && nbuck <= 511 && E >= 64) {
    part_hist<<<2048, 256, 0, stream>>>(ei, mat, E, nbuck, (float4*)agg16, N * 16);
    scan_rows<<<nbuck, 512, 0, stream>>>(mat, btot, nbuck);
    part_scatter<<<PB, 512, 0, stream>>>(ei, mat, btot, bstart, mid32, E, nbuck);
    bucket_sort<<<nbuck, 512, 0, stream>>>(mid32, bstart, sorted);
    edge_sorted_kernel<<<512, 512, 0, stream>>>(x, sorted, w1, b1, w2, b2,
                                                (unsigned int*)agg16, N, E);
  } else {
    int* flag2 = (int*)(ws + aggB);
    zero_detect_kernel<<<2048, 256, 0, stream>>>((float4*)agg16, N * 16, ei, flag2);
    edge_atomic_kernel<<<512, 256, 0, stream>>>(x, ei, w1, b1, w2, b2,
                                                (unsigned int*)agg16, flag2, N, E);
  }
  encdec_kernel<<<512, 256, 0, stream>>>(w3, b3, w4, b4, w5, b5, pos, agg16, out, N);
}

// Round 9
// 321.607 us; speedup vs baseline: 1.0719x; 1.0059x over previous
//
#include <hip/hip_runtime.h>
#include <hip/hip_bf16.h>

typedef __attribute__((ext_vector_type(8))) short short8;
typedef __attribute__((ext_vector_type(4))) float floatx4;
typedef __attribute__((ext_vector_type(2))) unsigned short ushortx2;

#define NHID 128
#define PADROW 136   // u16 row stride: 272B, 16B-aligned b128, benign banking
#define EB 64        // nodes per tile (encdec / fallback)
#define EB2 128      // edges per tile (edge_sorted)
#define PB 512       // partition blocks for the 2-level sort (R20)

__device__ __forceinline__ unsigned short f2bf(float x) {
  unsigned int u = __float_as_uint(x);
  u += 0x7FFFu + ((u >> 16) & 1u);          // RNE
  return (unsigned short)(u >> 16);
}

__device__ __forceinline__ unsigned int pkbf(float a, float b) {
  __hip_bfloat162 h = __float22bfloat162_rn(make_float2(a, b));
  union { __hip_bfloat162 h; unsigned int u; } cv;
  cv.h = h;
  return cv.u;
}

__device__ __forceinline__ unsigned int pack2(float a, float b) {
  return (unsigned int)f2bf(a) | ((unsigned int)f2bf(b) << 16);
}

// packed u16 max (v_pk_max_u16)
__device__ __forceinline__ unsigned int pkmax(unsigned int a, unsigned int b) {
  union { unsigned int u; ushortx2 v; } x, y;
  x.u = a; y.u = b;
  x.v = __builtin_elementwise_max(x.v, y.v);
  return x.u;
}

__device__ __forceinline__ void casmax(unsigned int* ap, unsigned int run) {
  unsigned int old = *ap;
  while (true) {
    unsigned int mx = pkmax(old, run);
    if (mx == old) break;
    unsigned int got = atomicCAS(ap, old, mx);
    if (got == old) break;
    old = got;
  }
}

// all-wave inline int64 probe: odd int32 slots all-zero <=> int64 edge_index
__device__ __forceinline__ bool detect64(const int* __restrict__ ei) {
  unsigned long long b = __ballot(ei[2 * (threadIdx.x & 63) + 1] != 0);
  return b == 0ULL;
}

// 32 loop-invariant B-fragments of a 128x128 row-major f32 weight (registers), natural k.
__device__ __forceinline__ void load_bfrags(const float* __restrict__ wmat,
                                            short8* bf, int m, int q) {
  #pragma unroll
  for (int kc = 0; kc < 4; ++kc) {
    #pragma unroll
    for (int nt = 0; nt < 8; ++nt) {
      short8 v;
      #pragma unroll
      for (int j = 0; j < 8; ++j)
        v[j] = (short)f2bf(wmat[(kc * 32 + q * 8 + j) * NHID + nt * 16 + m]);
      bf[kc * 8 + nt] = v;
    }
  }
}

// same but k-permuted: B[khw][n] = w[pi(khw)][n], pi(k) = ((k&7)<<4)|(k>>3)
__device__ __forceinline__ void load_bfrags_perm(const float* __restrict__ wmat,
                                                 short8* bf, int m, int q) {
  #pragma unroll
  for (int kc = 0; kc < 4; ++kc) {
    #pragma unroll
    for (int nt = 0; nt < 8; ++nt) {
      short8 v;
      #pragma unroll
      for (int j = 0; j < 8; ++j) {
        const int khw = kc * 32 + q * 8 + j;
        const int ctrue = ((khw & 7) << 4) | (khw >> 3);
        v[j] = (short)f2bf(wmat[ctrue * NHID + nt * 16 + m]);
      }
      bf[kc * 8 + nt] = v;
    }
  }
}

__device__ __forceinline__ void mfma_block(const unsigned short* uA,
                                           const short8* bf, floatx4* acc,
                                           int w, int m, int q) {
  #pragma unroll
  for (int kc = 0; kc < 4; ++kc) {
    short8 a = *(const short8*)(uA + (16 * w + m) * PADROW + kc * 32 + q * 8);
    #pragma unroll
    for (int nt = 0; nt < 8; ++nt)
      acc[nt] = __builtin_amdgcn_mfma_f32_16x16x32_bf16(a, bf[kc * 8 + nt],
                                                        acc[nt], 0, 0, 0);
  }
}

// fallback-path zero (agg16) + detect->flag
__global__ void zero_detect_kernel(float4* __restrict__ p, int n4,
                                   const int* __restrict__ ei, int* __restrict__ flag) {
  if (blockIdx.x == 0 && threadIdx.x < 64) {
    unsigned long long b = __ballot(ei[2 * threadIdx.x + 1] != 0);
    if (threadIdx.x == 0) flag[0] = (b == 0ULL) ? 1 : 0;
  }
  int i = blockIdx.x * blockDim.x + threadIdx.x;
  int stride = gridDim.x * blockDim.x;
  float4 z = make_float4(0.f, 0.f, 0.f, 0.f);
  for (; i < n4; i += stride) p[i] = z;
}

// ---------------- 2-level counting sort by dst (no global atomics) ----------------
// Split pipeline (R11): grid-barrier fusion regressed badly (R12/R13).
// R20: PB 256->512 (part_scatter 2 blocks/CU); mid packed to u32
// (s | (d&255)<<24, d>>8 == bucket id). Sort path is latency/launch-bound.

// A1: per-partition LDS histogram over coarse buckets (dst>>8); tail blocks zero agg16
__global__ __launch_bounds__(256) void part_hist(const int* __restrict__ ei,
                                                 int* __restrict__ mat, int E, int nbuck,
                                                 float4* __restrict__ aggz, int n4) {
  const int bl = blockIdx.x, t = threadIdx.x;
  if (bl >= PB) {
    int i = (bl - PB) * 256 + t;
    const int st = (gridDim.x - PB) * 256;
    float4 z = make_float4(0.f, 0.f, 0.f, 0.f);
    for (; i < n4; i += st) aggz[i] = z;
    return;
  }
  __shared__ int hist[512];
  const bool is64 = detect64(ei);
  for (int i = t; i < nbuck; i += 256) hist[i] = 0;
  __syncthreads();
  const int chunk = (E + PB - 1) / PB;
  const int lo = bl * chunk;
  const int hi = min(lo + chunk, E);
  for (int i = lo + t; i < hi; i += 256) {
    int d = is64 ? ei[2 * E + 2 * i] : ei[E + i];
    atomicAdd(&hist[d >> 8], 1);
  }
  __syncthreads();
  for (int bu = t; bu < nbuck; bu += 256) mat[bu * PB + bl] = hist[bu];
}

// A2: per-bucket exclusive scan over the PB partitions (in place) + bucket totals
__global__ __launch_bounds__(512) void scan_rows(int* __restrict__ mat,
                                                 int* __restrict__ btot, int nbuck) {
  __shared__ int sh[512];
  const int bu = blockIdx.x, t = threadIdx.x;
  const int v = mat[bu * PB + t];
  sh[t] = v;
  __syncthreads();
  for (int off = 1; off < 512; off <<= 1) {
    int x = (t >= off) ? sh[t - off] : 0;
    __syncthreads();
    sh[t] += x;
    __syncthreads();
  }
  mat[bu * PB + t] = sh[t] - v;
  if (t == 511) btot[bu] = sh[511];
}

// A3: scatter into coarse-bucket regions; bucket starts scanned in-LDS from btot.
__global__ __launch_bounds__(512) void part_scatter(const int* __restrict__ ei,
                                                    const int* __restrict__ mat,
                                                    const int* __restrict__ btot,
                                                    int* __restrict__ bstart,
                                                    unsigned int* __restrict__ mid32,
                                                    int E, int nbuck) {
  __shared__ int off[512];
  __shared__ int bsS[512];
  const bool is64 = detect64(ei);
  const int bl = blockIdx.x, t = threadIdx.x;
  const int o0 = (t < 256 && t < nbuck) ? btot[t] : 0;
  const int o1 = (t < 256 && t + 256 < nbuck) ? btot[t + 256] : 0;
  if (t < 256) { bsS[t] = o0; bsS[t + 256] = o1; }
  __syncthreads();
  for (int o = 1; o < 256; o <<= 1) {
    int x0 = (t >= o && t < 256) ? bsS[t - o] : 0;
    int x1 = (t >= o && t < 256) ? bsS[256 + t - o] : 0;
    __syncthreads();
    if (t < 256) { bsS[t] += x0; bsS[256 + t] += x1; }
    __syncthreads();
  }
  const int tot0 = bsS[255];
  if (t < 256) bsS[256 + t] += tot0;
  __syncthreads();
  if (t < 256) {
    const int ex0 = bsS[t] - o0;
    const int ex1 = bsS[256 + t] - o1;
    if (bl == 0) { bstart[t] = ex0; bstart[256 + t] = ex1; }
    off[t]       = ex0 + ((t < nbuck) ? mat[t * PB + bl] : 0);
    off[256 + t] = ex1 + ((t + 256 < nbuck) ? mat[(t + 256) * PB + bl] : 0);
  }
  __syncthreads();
  const int chunk = (E + PB - 1) / PB;
  const int lo = bl * chunk;
  const int hi = min(lo + chunk, E);
  for (int i = lo + t; i < hi; i += 512) {
    int s = is64 ? ei[2 * i]         : ei[i];
    int d = is64 ? ei[2 * E + 2 * i] : ei[E + i];
    int p = atomicAdd(&off[d >> 8], 1);
    mid32[p] = (unsigned int)s | ((unsigned int)(d & 255) << 24);
  }
}

// B: per-bucket counting sort by exact dst (256 local nodes), L2-resident traffic.
__global__ __launch_bounds__(512) void bucket_sort(const unsigned int* __restrict__ mid32,
                                                   const int* __restrict__ bstart,
                                                   int2* __restrict__ sorted) {
  __shared__ int h[256], cnt[256];
  const int bu = blockIdx.x, t = threadIdx.x;
  const int lo = bstart[bu], hi = bstart[bu + 1];
  if (t < 256) { h[t] = 0; cnt[t] = 0; }
  __syncthreads();
  for (int i = lo + t; i < hi; i += 512) atomicAdd(&h[mid32[i] >> 24], 1);
  __syncthreads();
  const int v = (t < 256) ? h[t] : 0;
  for (int off = 1; off < 256; off <<= 1) {
    int x = (t >= off && t < 256) ? h[t - off] : 0;
    __syncthreads();
    if (t < 256) h[t] += x;
    __syncthreads();
  }
  const int excl = (t < 256) ? h[t] - v : 0;
  __syncthreads();
  if (t < 256) h[t] = excl;
  __syncthreads();
  for (int i = lo + t; i < hi; i += 512) {
    const unsigned int e = mid32[i];
    const int dl = (int)(e >> 24);
    const int p = lo + h[dl] + atomicAdd(&cnt[dl], 1);
    sorted[p] = make_int2((int)(e & 0xFFFFFFu), (bu << 8) | dl);
  }
}

// ---------------- fused edge MLP (both layers MFMA) + segmented max ----------------
// FROZEN RULES (R10/R14/R15): acc MUST be zero-init; regs sit at 64 arch + 64
// acc = the residency-bucket edge — NO loop-invariant live-range growth.
// R16: layer-1 bias via spare K-slot. R17: layer-2 wave remap (32 rows x 64 cols).
// R18 REVERTED: SQ_LDS_BANK_CONFLICT counts benign 2-way wave64 aliasing, NOT
// stalls — don't chase it. R19: barrier F removed, prevd/nextd reg-captured.
// R21: stage-3 pass 1 static 16-row scan (167->155 µs).
// R22: x-gather prefetched one tile ahead. The 6 scattered 4B x-loads per edge
// (data-dependent on indices published at barrier A) sat on the critical path
// between A and the layer-1 MFMA. Now the post-D prefetch block (acc dead)
// gathers + packs next tile's A-rows (incl. k=6 bias slot) into xiS[128]
// (uint4, 2KB LDS); layer-1 reads one b128. Gather latency hides under
// stage-3 of the previous tile. Writes pre-E, reads post-next-A: double-
// fenced (R19 argument). esS[] dead -> deleted. Transient regs only.
// agg16: u16[N][128] in kstore (k-permuted) order.

__global__ __launch_bounds__(512, 2) void edge_sorted_kernel(
    const float* __restrict__ x, const int2* __restrict__ sorted,
    const float* __restrict__ w1, const float* __restrict__ b1,
    const float* __restrict__ w2, const float* __restrict__ b2,
    unsigned int* aggu, int N, int E) {
  __shared__ unsigned short us[EB2 * PADROW];     // uA then hS (bf16)
  __shared__ short8 w2f[2048];                    // 32 frags x 64 lanes, k-permuted
  __shared__ int edS[EB2];
  __shared__ uint4 xiS[EB2];                      // R22: prefetched packed A-rows
  __shared__ int pn[2];                           // dst before / after tile (-2 = none)
  __shared__ unsigned long long maskS[2];         // run-start bitmask
  __shared__ unsigned int pmS[8][64];             // per-quarter partial of run covering r0

  const int t = threadIdx.x;
  const int lane = t & 63;
  const int w = t >> 6;                           // wave 0..7
  const int m = lane & 15;
  const int q = lane >> 4;
  const int rowg = w >> 1;                        // layer-2: rows [32*rowg, +32)
  const int colg = w & 1;                         // layer-2: true cols [64*colg, +64)

  float b2c[4];
  #pragma unroll
  for (int nt = 0; nt < 4; ++nt) b2c[nt] = b2[(4 * colg + nt) * 16 + m];

  short8 bf1[8];
  #pragma unroll
  for (int nt = 0; nt < 8; ++nt) {
    short8 v;
    #pragma unroll
    for (int j = 0; j < 8; ++j) {
      short sj = 0;
      if (q == 0 && j < 6) sj = (short)f2bf(w1[j * NHID + nt * 16 + m]);
      else if (q == 0 && j == 6) sj = (short)f2bf(b1[nt * 16 + m]);  // bias row, k=6
      v[j] = sj;
    }
    bf1[nt] = v;
  }

  for (int idx = t; idx < 2048; idx += 512) {
    const int fg = idx >> 6, ln = idx & 63;
    const int mm = ln & 15;
    const int kc = fg >> 3, nt = fg & 7;
    short8 v;
    #pragma unroll
    for (int j = 0; j < 8; ++j) {
      const int khw = kc * 32 + (ln >> 4) * 8 + j;
      const int ctrue = ((khw & 7) << 4) | (khw >> 3);
      v[j] = (short)f2bf(w2[ctrue * NHID + nt * 16 + mm]);
    }
    w2f[idx] = v;
  }

  const int jc = t & 63;                          // u32 col in kstore order
  const int quarter = t >> 6;                     // rows [16*quarter, +16)

  const int nbt = (E + EB2 - 1) / EB2;
  __syncthreads();

  // preload first tile's index data + packed A-rows (R22)
  int2 sv = make_int2(0, -1);
  {
    const int tile0 = blockIdx.x;
    const int gb = tile0 * EB2;
    if (t < EB2) {
      const int e = gb + t;
      if (tile0 < nbt && e < E) sv = sorted[e];
    } else if (t == EB2) {
      sv.y = (tile0 < nbt && gb > 0) ? sorted[gb - 1].y : -2;
    } else if (t == EB2 + 1) {
      sv.y = (tile0 < nbt && gb + EB2 < E) ? sorted[gb + EB2].y : -2;
    }
    if (t < EB2) {
      const int si = sv.x;
      const int di = (sv.y < 0) ? 0 : sv.y;
      float xi0 = x[di * 3], xi1 = x[di * 3 + 1], xi2 = x[di * 3 + 2];
      float dd0 = x[si * 3] - xi0, dd1 = x[si * 3 + 1] - xi1, dd2 = x[si * 3 + 2] - xi2;
      xiS[t] = make_uint4(pkbf(xi0, xi1), pkbf(xi2, dd0), pkbf(dd1, dd2),
                          0x00003F80u);           // k=6: 1.0 (bias lane), k=7: 0
    }
  }

  for (int tile = blockIdx.x; tile < nbt; tile += gridDim.x) {
    if (t < EB2) edS[t] = sv.y;
    else if (t == EB2) pn[0] = sv.y;
    else if (t == EB2 + 1) pn[1] = sv.y;
    __syncthreads();   // A

    if (w == 0) {
      int d0 = edS[lane];
      int dp0 = (lane == 0) ? -9 : edS[lane - 1];
      unsigned long long mk0 = __ballot(lane == 0 || d0 != dp0);
      int d1 = edS[64 + lane];
      int dp1 = edS[63 + lane];
      unsigned long long mk1 = __ballot(d1 != dp1);
      if (lane == 0) { maskS[0] = mk0; maskS[1] = mk1; }
    }

    // layer 1 (zero acc init — FROZEN; A-row from xiS, bias in K-slot 6)
    floatx4 acc[8];
    #pragma unroll
    for (int nt = 0; nt < 8; ++nt) { floatx4 z = {0.f, 0.f, 0.f, 0.f}; acc[nt] = z; }
    short8 a1 = {0, 0, 0, 0, 0, 0, 0, 0};
    if (q == 0) {
      union { uint4 u; short8 s; } cv;
      cv.u = xiS[16 * w + m];
      a1 = cv.s;
    }
    #pragma unroll
    for (int nt = 0; nt < 8; ++nt)
      acc[nt] = __builtin_amdgcn_mfma_f32_16x16x32_bf16(a1, bf1[nt], acc[nt], 0, 0, 0);

    #pragma unroll
    for (int r = 0; r < 4; ++r) {
      union { short8 s; uint4 u; } cv;
      cv.u = make_uint4(
        pkbf(fmaxf(acc[0][r], 0.f), fmaxf(acc[1][r], 0.f)),
        pkbf(fmaxf(acc[2][r], 0.f), fmaxf(acc[3][r], 0.f)),
        pkbf(fmaxf(acc[4][r], 0.f), fmaxf(acc[5][r], 0.f)),
        pkbf(fmaxf(acc[6][r], 0.f), fmaxf(acc[7][r], 0.f)));
      *(short8*)(&us[(16 * w + q * 4 + r) * PADROW + m * 8]) = cv.s;
    }
    __syncthreads();   // B

    // layer 2 (zero acc init — FROZEN; bias in epilogue; R17 remap)
    #pragma unroll
    for (int nt = 0; nt < 8; ++nt) { floatx4 z = {0.f, 0.f, 0.f, 0.f}; acc[nt] = z; }
    #pragma unroll
    for (int kc = 0; kc < 4; ++kc) {
      short8 a0 = *(const short8*)(&us[(32 * rowg + m) * PADROW + kc * 32 + q * 8]);
      short8 a1r = *(const short8*)(&us[(32 * rowg + 16 + m) * PADROW + kc * 32 + q * 8]);
      #pragma unroll
      for (int nt = 0; nt < 4; ++nt) {
        short8 b = w2f[(kc * 8 + 4 * colg + nt) * 64 + lane];
        acc[nt]     = __builtin_amdgcn_mfma_f32_16x16x32_bf16(a0, b, acc[nt], 0, 0, 0);
        acc[4 + nt] = __builtin_amdgcn_mfma_f32_16x16x32_bf16(a1r, b, acc[4 + nt], 0, 0, 0);
      }
    }
    __syncthreads();   // C

    #pragma unroll
    for (int rb = 0; rb < 2; ++rb) {
      #pragma unroll
      for (int r = 0; r < 4; ++r) {
        uint2 uu;
        uu.x = pkbf(fmaxf(acc[rb * 4 + 0][r] + b2c[0], 0.f),
                    fmaxf(acc[rb * 4 + 1][r] + b2c[1], 0.f));
        uu.y = pkbf(fmaxf(acc[rb * 4 + 2][r] + b2c[2], 0.f),
                    fmaxf(acc[rb * 4 + 3][r] + b2c[3], 0.f));
        *(uint2*)(&us[(32 * rowg + 16 * rb + q * 4 + r) * PADROW + m * 8 + 4 * colg]) = uu;
      }
    }
    __syncthreads();   // D: hS ready

    // prefetch next tile's index data + packed A-rows (R22)
    {
      const int tn = tile + gridDim.x;
      const int gb = tn * EB2;
      int2 nv = make_int2(0, -1);
      if (t < EB2) {
        const int e = gb + t;
        if (tn < nbt && e < E) nv = sorted[e];
      } else if (t == EB2) {
        nv.y = (tn < nbt && gb > 0) ? sorted[gb - 1].y : -2;
      } else if (t == EB2 + 1) {
        nv.y = (tn < nbt && gb + EB2 < E) ? sorted[gb + EB2].y : -2;
      }
      sv = nv;
      if (t < EB2) {
        const int si = nv.x;
        const int di = (nv.y < 0) ? 0 : nv.y;
        float xi0 = x[di * 3], xi1 = x[di * 3 + 1], xi2 = x[di * 3 + 2];
        float dd0 = x[si * 3] - xi0, dd1 = x[si * 3 + 1] - xi1, dd2 = x[si * 3 + 2] - xi2;
        xiS[t] = make_uint4(pkbf(xi0, xi1), pkbf(xi2, dd0), pkbf(dd1, dd2),
                            0x00003F80u);
      }
    }

    // stage 3 pass 1 (R21): static 16-row scan.
    int os = -1, onxt = 0, od = -1; unsigned int opart = 0;
    int prevd, nextd;
    {
      const unsigned long long mk0 = maskS[0], mk1 = maskS[1];
      prevd = pn[0]; nextd = pn[1];
      const int r0 = quarter * 16;
      const unsigned int* us32 = (const unsigned int*)us;

      unsigned int v[16];
      #pragma unroll
      for (int r = 0; r < 16; ++r)
        v[r] = us32[(r0 + r) * (PADROW >> 1) + jc];

      // W bit r = "row r0+r is the last row of its run" = bit (r0+r+1) of the
      // 129-bit start mask (mk0 | mk1<<64 | 1<<128).
      const unsigned long long Am = (r0 < 64) ? mk0 : mk1;
      const unsigned long long Bm = (r0 < 64) ? mk1 : 1ULL;
      const int sh = (r0 & 63) + 1;               // 1..49
      const unsigned int W =
          (unsigned int)((Am >> sh) | (Bm << (64 - sh))) & 0xFFFFu;
      const int br0 =
          (int)((((r0 < 64) ? (mk0 >> r0) : (mk1 >> (r0 - 64))) & 1ULL));
      int s = br0 ? r0 : -1;                      // -1: run covering r0 started earlier
      unsigned int cur = 0;

      #pragma unroll
      for (int r = 0; r < 16; ++r) {
        cur = pkmax(cur, v[r]);
        if ((W >> r) & 1u) {                      // run ends at row r0+r
          if (s < 0) {
            pmS[quarter][jc] = cur;               // partial of run covering r0
          } else {
            const int d = edS[s];
            if (d >= 0) {
              const bool bnd = (s == 0 && prevd == d) ||
                               (r0 + r == 127 && nextd == d);
              unsigned int* ap = aggu + (size_t)d * 64 + jc;
              if (!bnd) *ap = cur;
              else if (cur) casmax(ap, cur);
            }
          }
          cur = 0; s = r0 + r + 1;
        }
      }

      if (!((W >> 15) & 1u)) {                    // last run extends past r1
        if (s < 0) {
          pmS[quarter][jc] = cur;                 // quarter fully inside a run
        } else {                                  // owner of a spanning run
          const int e0 = r0 + 15;                 // quarters 0..6 only (q7: W15=1)
          int nxt;
          if (e0 < 63) {
            unsigned long long ab = mk0 & (~0ULL << (e0 + 1));
            if (ab) nxt = __builtin_ffsll((long long)ab) - 1;
            else    nxt = mk1 ? 64 + __builtin_ffsll((long long)mk1) - 1 : 128;
          } else if (e0 == 63) {
            nxt = mk1 ? 64 + __builtin_ffsll((long long)mk1) - 1 : 128;
          } else {
            unsigned long long ab = mk1 & (~0ULL << (e0 - 63));
            nxt = ab ? 64 + __builtin_ffsll((long long)ab) - 1 : 128;
          }
          os = s; onxt = nxt; od = edS[s]; opart = cur;
        }
      }
    }
    __syncthreads();   // E: pmS ready

    // stage 3 pass 2: owners combine partials and write once.
    // Touches only pmS + registers (prevd/nextd/od captured) -> no barrier F.
    if (os >= 0 && od >= 0) {
      const int endq = (onxt - 1) >> 4;
      #pragma unroll 4
      for (int qq = quarter + 1; qq <= endq; ++qq)
        opart = pkmax(opart, pmS[qq][jc]);
      const bool bnd = (os == 0 && prevd == od) || (onxt == 128 && nextd == od);
      unsigned int* ap = aggu + (size_t)od * 64 + jc;
      if (!bnd) *ap = opart;
      else if (opart) casmax(ap, opart);
    }
  }
}

// ---------------- fallback: atomic edge kernel (small ws) ----------------

__global__ __launch_bounds__(256, 2) void edge_atomic_kernel(
    const float* __restrict__ x, const int* __restrict__ ei,
    const float* __restrict__ w1, const float* __restrict__ b1,
    const float* __restrict__ w2, const float* __restrict__ b2,
    unsigned int* aggu, const int* __restrict__ flag64, int N, int E) {
  __shared__ unsigned short uA[EB * PADROW];
  __shared__ float w1s[6 * NHID];
  __shared__ float b1s[NHID], b2s[NHID];
  __shared__ int es[EB], ed[EB];

  const int t = threadIdx.x;
  const int lane = t & 63;
  const int w = t >> 6;
  const int m = lane & 15;
  const int q = lane >> 4;

  for (int i = t; i < 6 * NHID; i += 256) w1s[i] = w1[i];
  if (t < NHID) { b1s[t] = b1[t]; b2s[t] = b2[t]; }

  short8 bf[32];
  load_bfrags(w2, bf, m, q);

  const bool is64 = (flag64[0] != 0);
  const int nb = (E + EB - 1) / EB;

  for (int batch = blockIdx.x; batch < nb; batch += gridDim.x) {
    const int gbase = batch * EB;
    if (t < EB) {
      int e = gbase + t;
      es[t] = (e < E) ? (is64 ? ei[2 * e] : ei[e]) : 0;
    } else if (t < 2 * EB) {
      int tt = t - EB;
      int e = gbase + tt;
      ed[tt] = (e < E) ? (is64 ? ei[2 * E + 2 * e] : ei[E + e]) : 0;
    }
    __syncthreads();
    {
      const int e = t >> 2;
      const int c0 = (t & 3) * 32;
      const int si = es[e], di = ed[e];
      float xi0 = x[di * 3], xi1 = x[di * 3 + 1], xi2 = x[di * 3 + 2];
      float msg[6];
      msg[0] = xi0; msg[1] = xi1; msg[2] = xi2;
      msg[3] = x[si * 3] - xi0; msg[4] = x[si * 3 + 1] - xi1; msg[5] = x[si * 3 + 2] - xi2;
      unsigned int* d32 = (unsigned int*)uA;
      const int base32 = (e * PADROW + c0) >> 1;
      #pragma unroll
      for (int cc = 0; cc < 32; cc += 2) {
        float u0 = b1s[c0 + cc], u1 = b1s[c0 + cc + 1];
        #pragma unroll
        for (int d = 0; d < 6; ++d) {
          u0 += msg[d] * w1s[d * NHID + c0 + cc];
          u1 += msg[d] * w1s[d * NHID + c0 + cc + 1];
        }
        d32[base32 + (cc >> 1)] = pack2(fmaxf(u0, 0.f), fmaxf(u1, 0.f));
      }
    }
    __syncthreads();

    floatx4 acc[8];
    #pragma unroll
    for (int nt = 0; nt < 8; ++nt) { floatx4 z = {0.f, 0.f, 0.f, 0.f}; acc[nt] = z; }
    mfma_block(uA, bf, acc, w, m, q);

    #pragma unroll
    for (int nt = 0; nt < 8; ++nt) {
      const int c = nt * 16 + m;
      const float bb = b2s[c];
      const int kst = m * 8 + nt;
      #pragma unroll
      for (int r = 0; r < 4; ++r) {
        const int erow = 16 * w + q * 4 + r;
        if (gbase + erow < E) {
          float hb = acc[nt][r] + bb;
          if (hb > 0.f) {
            unsigned int v = (unsigned int)f2bf(hb);
            casmax(aggu + (size_t)ed[erow] * 64 + (kst >> 1), v << (16 * (kst & 1)));
          }
        }
      }
    }
    __syncthreads();
  }
}

// ---------------- fused node MLPs: enc (w3) + dec (w4,w5), agg16 input ----------------
// R9 structure (barriers B0/B1/B2/B3) — R10's barrier removal regressed.
// R15 lesson applies here too: acc zero-init FROZEN (bias in epilogue).

__global__ __launch_bounds__(256, 2) void encdec_kernel(
    const float* __restrict__ w3, const float* __restrict__ b3,
    const float* __restrict__ w4, const float* __restrict__ b4,
    const float* __restrict__ w5, const float* __restrict__ b5,
    const float* __restrict__ pos, const unsigned short* __restrict__ agg16,
    float* __restrict__ out, int N) {
  __shared__ unsigned short uA[EB * PADROW];
  __shared__ short8 w4f[2048];                    // k-permuted w4 frags
  __shared__ float w5s[NHID * 3];

  const int t = threadIdx.x;
  const int lane = t & 63;
  const int w = t >> 6;
  const int m = lane & 15;
  const int q = lane >> 4;

  float b3c[8], b4c[8];
  #pragma unroll
  for (int nt = 0; nt < 8; ++nt) { b3c[nt] = b3[nt * 16 + m]; b4c[nt] = b4[nt * 16 + m]; }

  short8 bf3[32];
  load_bfrags_perm(w3, bf3, m, q);                // k-permuted (agg16 is kstore-ordered)

  for (int idx = t; idx < 2048; idx += 256) {
    const int fg = idx >> 6, ln = idx & 63;
    const int mm = ln & 15;
    const int kc = fg >> 3, nt = fg & 7;
    short8 v;
    #pragma unroll
    for (int j = 0; j < 8; ++j) {
      const int khw = kc * 32 + (ln >> 4) * 8 + j;
      const int ctrue = ((khw & 7) << 4) | (khw >> 3);
      v[j] = (short)f2bf(w4[ctrue * NHID + nt * 16 + mm]);
    }
    w4f[idx] = v;
  }
  for (int i = t; i < NHID * 3; i += 256) w5s[i] = w5[i];
  const float b50 = b5[0], b51 = b5[1], b52 = b5[2];

  const int ch = t & 15;
  const int rr = t >> 4;
  const int nb = (N + EB - 1) / EB;
  __syncthreads();

  uint4 rv[4];
  const uint4 uz = make_uint4(0u, 0u, 0u, 0u);
  {
    const int b0 = blockIdx.x;
    #pragma unroll
    for (int k = 0; k < 4; ++k) {
      const int node = b0 * EB + rr + 16 * k;
      rv[k] = (b0 < nb && node < N) ? ((const uint4*)agg16)[(size_t)node * 16 + ch] : uz;
    }
  }

  for (int batch = blockIdx.x; batch < nb; batch += gridDim.x) {
    const int base = batch * EB;
    #pragma unroll
    for (int k = 0; k < 4; ++k)
      *(uint4*)(&uA[(rr + 16 * k) * PADROW + ch * 8]) = rv[k];
    __syncthreads();   // B0

    {
      const int nxb = batch + gridDim.x;
      #pragma unroll
      for (int k = 0; k < 4; ++k) {
        const int node = nxb * EB + rr + 16 * k;
        rv[k] = (nxb < nb && node < N) ? ((const uint4*)agg16)[(size_t)node * 16 + ch] : uz;
      }
    }

    floatx4 acc[8];
    #pragma unroll
    for (int nt = 0; nt < 8; ++nt) { floatx4 z = {0.f, 0.f, 0.f, 0.f}; acc[nt] = z; }
    mfma_block(uA, bf3, acc, w, m, q);
    __syncthreads();   // B1

    #pragma unroll
    for (int r = 0; r < 4; ++r) {
      union { short8 s; uint4 u; } cv;
      cv.u = make_uint4(
        pkbf(acc[0][r] + b3c[0], acc[1][r] + b3c[1]),
        pkbf(acc[2][r] + b3c[2], acc[3][r] + b3c[3]),
        pkbf(acc[4][r] + b3c[4], acc[5][r] + b3c[5]),
        pkbf(acc[6][r] + b3c[6], acc[7][r] + b3c[7]));
      *(short8*)(&uA[(16 * w + q * 4 + r) * PADROW + m * 8]) = cv.s;
    }
    __syncthreads();   // B2

    #pragma unroll
    for (int nt = 0; nt < 8; ++nt) { floatx4 z = {0.f, 0.f, 0.f, 0.f}; acc[nt] = z; }
    #pragma unroll
    for (int kc = 0; kc < 4; ++kc) {
      short8 a = *(const short8*)(&uA[(16 * w + m) * PADROW + kc * 32 + q * 8]);
      #pragma unroll
      for (int nt = 0; nt < 8; ++nt)
        acc[nt] = __builtin_amdgcn_mfma_f32_16x16x32_bf16(a, w4f[(kc * 8 + nt) * 64 + lane],
                                                          acc[nt], 0, 0, 0);
    }

    float p[4][3];
    #pragma unroll
    for (int r = 0; r < 4; ++r) { p[r][0] = 0.f; p[r][1] = 0.f; p[r][2] = 0.f; }
    #pragma unroll
    for (int nt = 0; nt < 8; ++nt) {
      const int c = nt * 16 + m;
      const float bb = b4c[nt];
      const float w50 = w5s[c * 3], w51 = w5s[c * 3 + 1], w52 = w5s[c * 3 + 2];
      #pragma unroll
      for (int r = 0; r < 4; ++r) {
        float tv = fmaxf(acc[nt][r] + bb, 0.f);
        p[r][0] += tv * w50; p[r][1] += tv * w51; p[r][2] += tv * w52;
      }
    }
    #pragma unroll
    for (int off = 8; off >= 1; off >>= 1) {
      #pragma unroll
      for (int r = 0; r < 4; ++r) {
        p[r][0] += __shfl_xor(p[r][0], off, 16);
        p[r][1] += __shfl_xor(p[r][1], off, 16);
        p[r][2] += __shfl_xor(p[r][2], off, 16);
      }
    }
    if (m == 0) {
      #pragma unroll
      for (int r = 0; r < 4; ++r) {
        const int node = base + 16 * w + q * 4 + r;
        if (node < N) {
          out[node * 3]     = pos[node * 3]     + 0.1f * tanhf(p[r][0] + b50);
          out[node * 3 + 1] = pos[node * 3 + 1] + 0.1f * tanhf(p[r][1] + b51);
          out[node * 3 + 2] = pos[node * 3 + 2] + 0.1f * tanhf(p[r][2] + b52);
        }
      }
    }
    __syncthreads();   // B3
  }
}

extern "C" void kernel_launch(void* const* d_in, const int* in_sizes, int n_in,
                              void* d_out, int out_size, void* d_ws, size_t ws_size,
                              hipStream_t stream) {
  const float* x   = (const float*)d_in[0];
  const float* pos = (const float*)d_in[1];
  const int*   ei  = (const int*)d_in[2];
  const float* w1  = (const float*)d_in[3];
  const float* b1  = (const float*)d_in[4];
  const float* w2  = (const float*)d_in[5];
  const float* b2  = (const float*)d_in[6];
  const float* w3  = (const float*)d_in[7];
  const float* b3  = (const float*)d_in[8];
  const float* w4  = (const float*)d_in[9];
  const float* b4  = (const float*)d_in[10];
  const float* w5  = (const float*)d_in[11];
  const float* b5  = (const float*)d_in[12];
  float* out = (float*)d_out;

  const int N = in_sizes[0] / 3;
  const int E = in_sizes[2] / 2;
  const int nbuck = (N + 255) >> 8;

  char* ws = (char*)d_ws;
  unsigned short* agg16 = (unsigned short*)ws;                // N*128 u16 (kstore order)
  const size_t aggB = (size_t)N * NHID * sizeof(unsigned short);
  const size_t midB = (((size_t)E * 4) + 15) & ~(size_t)15;   // u32-packed mid
  unsigned int* mid32 = (unsigned int*)(ws + aggB);
  int2* sorted = (int2*)(ws + aggB + midB);
  int*  mat    = (int*)(ws + aggB + midB + (size_t)E * 8);
  int*  btot   = mat + (size_t)nbuck * PB;
  int*  bstart = btot + nbuck;
  const size_t needed = aggB + midB + (size_t)E * 8 + ((size_t)nbuck * PB + nbuck + 520) * 4;

  if (ws_size >= needed && nbuck <= 511 && E >= 64) {
    part_hist<<<2048, 256, 0, stream>>>(ei, mat, E, nbuck, (float4*)agg16, N * 16);
    scan_rows<<<nbuck, 512, 0, stream>>>(mat, btot, nbuck);
    part_scatter<<<PB, 512, 0, stream>>>(ei, mat, btot, bstart, mid32, E, nbuck);
    bucket_sort<<<nbuck, 512, 0, stream>>>(mid32, bstart, sorted);
    edge_sorted_kernel<<<512, 512, 0, stream>>>(x, sorted, w1, b1, w2, b2,
                                                (unsigned int*)agg16, N, E);
  } else {
    int* flag2 = (int*)(ws + aggB);
    zero_detect_kernel<<<2048, 256, 0, stream>>>((float4*)agg16, N * 16, ei, flag2);
    edge_atomic_kernel<<<512, 256, 0, stream>>>(x, ei, w1, b1, w2, b2,
                                                (unsigned int*)agg16, flag2, N, E);
  }
  encdec_kernel<<<512, 256, 0, stream>>>(w3, b3, w4, b4, w5, b5, pos, agg16, out, N);
}

// Round 10
// 320.251 us; speedup vs baseline: 1.0765x; 1.0042x over previous
//
#include <hip/hip_runtime.h>
#include <hip/hip_bf16.h>

typedef __attribute__((ext_vector_type(8))) short short8;
typedef __attribute__((ext_vector_type(4))) float floatx4;
typedef __attribute__((ext_vector_type(2))) unsigned short ushortx2;

#define NHID 128
#define PADROW 136   // u16 row stride: 272B, 16B-aligned b128, benign banking
#define EB 64        // nodes per tile (encdec / fallback)
#define EB2 128      // edges per tile (edge_sorted)
#define PB 512       // partition blocks for the 2-level sort (R20)

__device__ __forceinline__ unsigned short f2bf(float x) {
  unsigned int u = __float_as_uint(x);
  u += 0x7FFFu + ((u >> 16) & 1u);          // RNE
  return (unsigned short)(u >> 16);
}

__device__ __forceinline__ unsigned int pkbf(float a, float b) {
  __hip_bfloat162 h = __float22bfloat162_rn(make_float2(a, b));
  union { __hip_bfloat162 h; unsigned int u; } cv;
  cv.h = h;
  return cv.u;
}

__device__ __forceinline__ unsigned int pack2(float a, float b) {
  return (unsigned int)f2bf(a) | ((unsigned int)f2bf(b) << 16);
}

// packed u16 max (v_pk_max_u16)
__device__ __forceinline__ unsigned int pkmax(unsigned int a, unsigned int b) {
  union { unsigned int u; ushortx2 v; } x, y;
  x.u = a; y.u = b;
  x.v = __builtin_elementwise_max(x.v, y.v);
  return x.u;
}

__device__ __forceinline__ void casmax(unsigned int* ap, unsigned int run) {
  unsigned int old = *ap;
  while (true) {
    unsigned int mx = pkmax(old, run);
    if (mx == old) break;
    unsigned int got = atomicCAS(ap, old, mx);
    if (got == old) break;
    old = got;
  }
}

// all-wave inline int64 probe: odd int32 slots all-zero <=> int64 edge_index
__device__ __forceinline__ bool detect64(const int* __restrict__ ei) {
  unsigned long long b = __ballot(ei[2 * (threadIdx.x & 63) + 1] != 0);
  return b == 0ULL;
}

// 32 loop-invariant B-fragments of a 128x128 row-major f32 weight (registers), natural k.
__device__ __forceinline__ void load_bfrags(const float* __restrict__ wmat,
                                            short8* bf, int m, int q) {
  #pragma unroll
  for (int kc = 0; kc < 4; ++kc) {
    #pragma unroll
    for (int nt = 0; nt < 8; ++nt) {
      short8 v;
      #pragma unroll
      for (int j = 0; j < 8; ++j)
        v[j] = (short)f2bf(wmat[(kc * 32 + q * 8 + j) * NHID + nt * 16 + m]);
      bf[kc * 8 + nt] = v;
    }
  }
}

// same but k-permuted: B[khw][n] = w[pi(khw)][n], pi(k) = ((k&7)<<4)|(k>>3)
__device__ __forceinline__ void load_bfrags_perm(const float* __restrict__ wmat,
                                                 short8* bf, int m, int q) {
  #pragma unroll
  for (int kc = 0; kc < 4; ++kc) {
    #pragma unroll
    for (int nt = 0; nt < 8; ++nt) {
      short8 v;
      #pragma unroll
      for (int j = 0; j < 8; ++j) {
        const int khw = kc * 32 + q * 8 + j;
        const int ctrue = ((khw & 7) << 4) | (khw >> 3);
        v[j] = (short)f2bf(wmat[ctrue * NHID + nt * 16 + m]);
      }
      bf[kc * 8 + nt] = v;
    }
  }
}

__device__ __forceinline__ void mfma_block(const unsigned short* uA,
                                           const short8* bf, floatx4* acc,
                                           int w, int m, int q) {
  #pragma unroll
  for (int kc = 0; kc < 4; ++kc) {
    short8 a = *(const short8*)(uA + (16 * w + m) * PADROW + kc * 32 + q * 8);
    #pragma unroll
    for (int nt = 0; nt < 8; ++nt)
      acc[nt] = __builtin_amdgcn_mfma_f32_16x16x32_bf16(a, bf[kc * 8 + nt],
                                                        acc[nt], 0, 0, 0);
  }
}

// fallback-path zero (agg16) + detect->flag
__global__ void zero_detect_kernel(float4* __restrict__ p, int n4,
                                   const int* __restrict__ ei, int* __restrict__ flag) {
  if (blockIdx.x == 0 && threadIdx.x < 64) {
    unsigned long long b = __ballot(ei[2 * threadIdx.x + 1] != 0);
    if (threadIdx.x == 0) flag[0] = (b == 0ULL) ? 1 : 0;
  }
  int i = blockIdx.x * blockDim.x + threadIdx.x;
  int stride = gridDim.x * blockDim.x;
  float4 z = make_float4(0.f, 0.f, 0.f, 0.f);
  for (; i < n4; i += stride) p[i] = z;
}

// ---------------- 2-level counting sort by dst (no global atomics) ----------------
// Split pipeline (R11): grid-barrier fusion regressed badly (R12/R13).
// R20: PB 256->512 (part_scatter 2 blocks/CU); mid packed to u32
// (s | (d&255)<<24, d>>8 == bucket id). Sort path is latency/launch-bound;
// the non-edge residual is ~167 µs FIXED across all sort changes (R0..R9) —
// mostly harness/launch overhead. Don't optimize it further.

// A1: per-partition LDS histogram over coarse buckets (dst>>8); tail blocks zero agg16
__global__ __launch_bounds__(256) void part_hist(const int* __restrict__ ei,
                                                 int* __restrict__ mat, int E, int nbuck,
                                                 float4* __restrict__ aggz, int n4) {
  const int bl = blockIdx.x, t = threadIdx.x;
  if (bl >= PB) {
    int i = (bl - PB) * 256 + t;
    const int st = (gridDim.x - PB) * 256;
    float4 z = make_float4(0.f, 0.f, 0.f, 0.f);
    for (; i < n4; i += st) aggz[i] = z;
    return;
  }
  __shared__ int hist[512];
  const bool is64 = detect64(ei);
  for (int i = t; i < nbuck; i += 256) hist[i] = 0;
  __syncthreads();
  const int chunk = (E + PB - 1) / PB;
  const int lo = bl * chunk;
  const int hi = min(lo + chunk, E);
  for (int i = lo + t; i < hi; i += 256) {
    int d = is64 ? ei[2 * E + 2 * i] : ei[E + i];
    atomicAdd(&hist[d >> 8], 1);
  }
  __syncthreads();
  for (int bu = t; bu < nbuck; bu += 256) mat[bu * PB + bl] = hist[bu];
}

// A2: per-bucket exclusive scan over the PB partitions (in place) + bucket totals
__global__ __launch_bounds__(512) void scan_rows(int* __restrict__ mat,
                                                 int* __restrict__ btot, int nbuck) {
  __shared__ int sh[512];
  const int bu = blockIdx.x, t = threadIdx.x;
  const int v = mat[bu * PB + t];
  sh[t] = v;
  __syncthreads();
  for (int off = 1; off < 512; off <<= 1) {
    int x = (t >= off) ? sh[t - off] : 0;
    __syncthreads();
    sh[t] += x;
    __syncthreads();
  }
  mat[bu * PB + t] = sh[t] - v;
  if (t == 511) btot[bu] = sh[511];
}

// A3: scatter into coarse-bucket regions; bucket starts scanned in-LDS from btot.
__global__ __launch_bounds__(512) void part_scatter(const int* __restrict__ ei,
                                                    const int* __restrict__ mat,
                                                    const int* __restrict__ btot,
                                                    int* __restrict__ bstart,
                                                    unsigned int* __restrict__ mid32,
                                                    int E, int nbuck) {
  __shared__ int off[512];
  __shared__ int bsS[512];
  const bool is64 = detect64(ei);
  const int bl = blockIdx.x, t = threadIdx.x;
  const int o0 = (t < 256 && t < nbuck) ? btot[t] : 0;
  const int o1 = (t < 256 && t + 256 < nbuck) ? btot[t + 256] : 0;
  if (t < 256) { bsS[t] = o0; bsS[t + 256] = o1; }
  __syncthreads();
  for (int o = 1; o < 256; o <<= 1) {
    int x0 = (t >= o && t < 256) ? bsS[t - o] : 0;
    int x1 = (t >= o && t < 256) ? bsS[256 + t - o] : 0;
    __syncthreads();
    if (t < 256) { bsS[t] += x0; bsS[256 + t] += x1; }
    __syncthreads();
  }
  const int tot0 = bsS[255];
  if (t < 256) bsS[256 + t] += tot0;
  __syncthreads();
  if (t < 256) {
    const int ex0 = bsS[t] - o0;
    const int ex1 = bsS[256 + t] - o1;
    if (bl == 0) { bstart[t] = ex0; bstart[256 + t] = ex1; }
    off[t]       = ex0 + ((t < nbuck) ? mat[t * PB + bl] : 0);
    off[256 + t] = ex1 + ((t + 256 < nbuck) ? mat[(t + 256) * PB + bl] : 0);
  }
  __syncthreads();
  const int chunk = (E + PB - 1) / PB;
  const int lo = bl * chunk;
  const int hi = min(lo + chunk, E);
  for (int i = lo + t; i < hi; i += 512) {
    int s = is64 ? ei[2 * i]         : ei[i];
    int d = is64 ? ei[2 * E + 2 * i] : ei[E + i];
    int p = atomicAdd(&off[d >> 8], 1);
    mid32[p] = (unsigned int)s | ((unsigned int)(d & 255) << 24);
  }
}

// B: per-bucket counting sort by exact dst (256 local nodes), L2-resident traffic.
__global__ __launch_bounds__(512) void bucket_sort(const unsigned int* __restrict__ mid32,
                                                   const int* __restrict__ bstart,
                                                   int2* __restrict__ sorted) {
  __shared__ int h[256], cnt[256];
  const int bu = blockIdx.x, t = threadIdx.x;
  const int lo = bstart[bu], hi = bstart[bu + 1];
  if (t < 256) { h[t] = 0; cnt[t] = 0; }
  __syncthreads();
  for (int i = lo + t; i < hi; i += 512) atomicAdd(&h[mid32[i] >> 24], 1);
  __syncthreads();
  const int v = (t < 256) ? h[t] : 0;
  for (int off = 1; off < 256; off <<= 1) {
    int x = (t >= off && t < 256) ? h[t - off] : 0;
    __syncthreads();
    if (t < 256) h[t] += x;
    __syncthreads();
  }
  const int excl = (t < 256) ? h[t] - v : 0;
  __syncthreads();
  if (t < 256) h[t] = excl;
  __syncthreads();
  for (int i = lo + t; i < hi; i += 512) {
    const unsigned int e = mid32[i];
    const int dl = (int)(e >> 24);
    const int p = lo + h[dl] + atomicAdd(&cnt[dl], 1);
    sorted[p] = make_int2((int)(e & 0xFFFFFFu), (bu << 8) | dl);
  }
}

// ---------------- fused edge MLP (both layers MFMA) + segmented max ----------------
// FROZEN RULES (R10/R14/R15): acc MUST be zero-init; regs sit at 64 arch + 64
// acc = the residency-bucket edge — NO loop-invariant live-range growth.
// R16: layer-1 bias via spare K-slot. R17: layer-2 wave remap (32 rows x 64 cols).
// R18 REVERTED: SQ_LDS_BANK_CONFLICT counts benign 2-way wave64 aliasing, NOT
// stalls — don't chase it. R19: barrier F removed, prevd/nextd reg-captured.
// R21: stage-3 pass 1 static 16-row scan (167->155 µs).
// R22: x-gather prefetched one tile ahead into xiS (155.5->154.5 — mostly
// already hidden).
// R23: barrier A removed. The ballot now runs from REGISTERS in waves 0/1
// (threads 0..127 hold sv.y = this tile's d); the wave-boundary value d[63]
// is published by t==63 during the PREVIOUS prefetch (d63S, pre-E write,
// post-E read). All former barrier-A consumers are fenced elsewhere: xiS
// (pre-E write -> post-E read), edS/pn (loop-top write -> post-D read via
// B/C/D). One extra one-time __syncthreads() after preload covers tile 0.
// 4 barriers/tile (B/C/D/E).
// agg16: u16[N][128] in kstore (k-permuted) order.

__global__ __launch_bounds__(512, 2) void edge_sorted_kernel(
    const float* __restrict__ x, const int2* __restrict__ sorted,
    const float* __restrict__ w1, const float* __restrict__ b1,
    const float* __restrict__ w2, const float* __restrict__ b2,
    unsigned int* aggu, int N, int E) {
  __shared__ unsigned short us[EB2 * PADROW];     // uA then hS (bf16)
  __shared__ short8 w2f[2048];                    // 32 frags x 64 lanes, k-permuted
  __shared__ int edS[EB2];
  __shared__ uint4 xiS[EB2];                      // R22: prefetched packed A-rows
  __shared__ int pn[2];                           // dst before / after tile (-2 = none)
  __shared__ int d63S;                            // R23: d[63] of the CURRENT tile
  __shared__ unsigned long long maskS[2];         // run-start bitmask
  __shared__ unsigned int pmS[8][64];             // per-quarter partial of run covering r0

  const int t = threadIdx.x;
  const int lane = t & 63;
  const int w = t >> 6;                           // wave 0..7
  const int m = lane & 15;
  const int q = lane >> 4;
  const int rowg = w >> 1;                        // layer-2: rows [32*rowg, +32)
  const int colg = w & 1;                         // layer-2: true cols [64*colg, +64)

  float b2c[4];
  #pragma unroll
  for (int nt = 0; nt < 4; ++nt) b2c[nt] = b2[(4 * colg + nt) * 16 + m];

  short8 bf1[8];
  #pragma unroll
  for (int nt = 0; nt < 8; ++nt) {
    short8 v;
    #pragma unroll
    for (int j = 0; j < 8; ++j) {
      short sj = 0;
      if (q == 0 && j < 6) sj = (short)f2bf(w1[j * NHID + nt * 16 + m]);
      else if (q == 0 && j == 6) sj = (short)f2bf(b1[nt * 16 + m]);  // bias row, k=6
      v[j] = sj;
    }
    bf1[nt] = v;
  }

  for (int idx = t; idx < 2048; idx += 512) {
    const int fg = idx >> 6, ln = idx & 63;
    const int mm = ln & 15;
    const int kc = fg >> 3, nt = fg & 7;
    short8 v;
    #pragma unroll
    for (int j = 0; j < 8; ++j) {
      const int khw = kc * 32 + (ln >> 4) * 8 + j;
      const int ctrue = ((khw & 7) << 4) | (khw >> 3);
      v[j] = (short)f2bf(w2[ctrue * NHID + nt * 16 + mm]);
    }
    w2f[idx] = v;
  }

  const int jc = t & 63;                          // u32 col in kstore order
  const int quarter = t >> 6;                     // rows [16*quarter, +16)

  const int nbt = (E + EB2 - 1) / EB2;
  __syncthreads();

  // preload first tile's index data + packed A-rows (R22) + d63S (R23)
  int2 sv = make_int2(0, -1);
  {
    const int tile0 = blockIdx.x;
    const int gb = tile0 * EB2;
    if (t < EB2) {
      const int e = gb + t;
      if (tile0 < nbt && e < E) sv = sorted[e];
    } else if (t == EB2) {
      sv.y = (tile0 < nbt && gb > 0) ? sorted[gb - 1].y : -2;
    } else if (t == EB2 + 1) {
      sv.y = (tile0 < nbt && gb + EB2 < E) ? sorted[gb + EB2].y : -2;
    }
    if (t < EB2) {
      const int si = sv.x;
      const int di = (sv.y < 0) ? 0 : sv.y;
      float xi0 = x[di * 3], xi1 = x[di * 3 + 1], xi2 = x[di * 3 + 2];
      float dd0 = x[si * 3] - xi0, dd1 = x[si * 3 + 1] - xi1, dd2 = x[si * 3 + 2] - xi2;
      xiS[t] = make_uint4(pkbf(xi0, xi1), pkbf(xi2, dd0), pkbf(dd1, dd2),
                          0x00003F80u);           // k=6: 1.0 (bias lane), k=7: 0
      if (t == 63) d63S = sv.y;
    }
  }
  __syncthreads();                                // one-time: d63S/xiS for tile 0

  for (int tile = blockIdx.x; tile < nbt; tile += gridDim.x) {
    if (t < EB2) edS[t] = sv.y;
    else if (t == EB2) pn[0] = sv.y;
    else if (t == EB2 + 1) pn[1] = sv.y;

    // R23: register ballot (no barrier A). Waves 0/1 hold this tile's d in sv.y.
    if (w == 0) {
      const int d0 = sv.y;
      const int dp = __shfl_up(d0, 1);
      unsigned long long mk = __ballot(lane == 0 || d0 != dp);
      if (lane == 0) maskS[0] = mk;
    } else if (w == 1) {
      const int d1 = sv.y;
      int dp = __shfl_up(d1, 1);
      if (lane == 0) dp = d63S;                   // d[63], published pre-E (prev)
      unsigned long long mk = __ballot(d1 != dp);
      if (lane == 0) maskS[1] = mk;
    }

    // layer 1 (zero acc init — FROZEN; A-row from xiS, bias in K-slot 6)
    floatx4 acc[8];
    #pragma unroll
    for (int nt = 0; nt < 8; ++nt) { floatx4 z = {0.f, 0.f, 0.f, 0.f}; acc[nt] = z; }
    short8 a1 = {0, 0, 0, 0, 0, 0, 0, 0};
    if (q == 0) {
      union { uint4 u; short8 s; } cv;
      cv.u = xiS[16 * w + m];
      a1 = cv.s;
    }
    #pragma unroll
    for (int nt = 0; nt < 8; ++nt)
      acc[nt] = __builtin_amdgcn_mfma_f32_16x16x32_bf16(a1, bf1[nt], acc[nt], 0, 0, 0);

    #pragma unroll
    for (int r = 0; r < 4; ++r) {
      union { short8 s; uint4 u; } cv;
      cv.u = make_uint4(
        pkbf(fmaxf(acc[0][r], 0.f), fmaxf(acc[1][r], 0.f)),
        pkbf(fmaxf(acc[2][r], 0.f), fmaxf(acc[3][r], 0.f)),
        pkbf(fmaxf(acc[4][r], 0.f), fmaxf(acc[5][r], 0.f)),
        pkbf(fmaxf(acc[6][r], 0.f), fmaxf(acc[7][r], 0.f)));
      *(short8*)(&us[(16 * w + q * 4 + r) * PADROW + m * 8]) = cv.s;
    }
    __syncthreads();   // B

    // layer 2 (zero acc init — FROZEN; bias in epilogue; R17 remap)
    #pragma unroll
    for (int nt = 0; nt < 8; ++nt) { floatx4 z = {0.f, 0.f, 0.f, 0.f}; acc[nt] = z; }
    #pragma unroll
    for (int kc = 0; kc < 4; ++kc) {
      short8 a0 = *(const short8*)(&us[(32 * rowg + m) * PADROW + kc * 32 + q * 8]);
      short8 a1r = *(const short8*)(&us[(32 * rowg + 16 + m) * PADROW + kc * 32 + q * 8]);
      #pragma unroll
      for (int nt = 0; nt < 4; ++nt) {
        short8 b = w2f[(kc * 8 + 4 * colg + nt) * 64 + lane];
        acc[nt]     = __builtin_amdgcn_mfma_f32_16x16x32_bf16(a0, b, acc[nt], 0, 0, 0);
        acc[4 + nt] = __builtin_amdgcn_mfma_f32_16x16x32_bf16(a1r, b, acc[4 + nt], 0, 0, 0);
      }
    }
    __syncthreads();   // C

    #pragma unroll
    for (int rb = 0; rb < 2; ++rb) {
      #pragma unroll
      for (int r = 0; r < 4; ++r) {
        uint2 uu;
        uu.x = pkbf(fmaxf(acc[rb * 4 + 0][r] + b2c[0], 0.f),
                    fmaxf(acc[rb * 4 + 1][r] + b2c[1], 0.f));
        uu.y = pkbf(fmaxf(acc[rb * 4 + 2][r] + b2c[2], 0.f),
                    fmaxf(acc[rb * 4 + 3][r] + b2c[3], 0.f));
        *(uint2*)(&us[(32 * rowg + 16 * rb + q * 4 + r) * PADROW + m * 8 + 4 * colg]) = uu;
      }
    }
    __syncthreads();   // D: hS ready

    // prefetch next tile's index data + packed A-rows (R22) + d63S (R23)
    {
      const int tn = tile + gridDim.x;
      const int gb = tn * EB2;
      int2 nv = make_int2(0, -1);
      if (t < EB2) {
        const int e = gb + t;
        if (tn < nbt && e < E) nv = sorted[e];
      } else if (t == EB2) {
        nv.y = (tn < nbt && gb > 0) ? sorted[gb - 1].y : -2;
      } else if (t == EB2 + 1) {
        nv.y = (tn < nbt && gb + EB2 < E) ? sorted[gb + EB2].y : -2;
      }
      sv = nv;
      if (t < EB2) {
        const int si = nv.x;
        const int di = (nv.y < 0) ? 0 : nv.y;
        float xi0 = x[di * 3], xi1 = x[di * 3 + 1], xi2 = x[di * 3 + 2];
        float dd0 = x[si * 3] - xi0, dd1 = x[si * 3 + 1] - xi1, dd2 = x[si * 3 + 2] - xi2;
        xiS[t] = make_uint4(pkbf(xi0, xi1), pkbf(xi2, dd0), pkbf(dd1, dd2),
                            0x00003F80u);
        if (t == 63) d63S = nv.y;
      }
    }

    // stage 3 pass 1 (R21): static 16-row scan.
    int os = -1, onxt = 0, od = -1; unsigned int opart = 0;
    int prevd, nextd;
    {
      const unsigned long long mk0 = maskS[0], mk1 = maskS[1];
      prevd = pn[0]; nextd = pn[1];
      const int r0 = quarter * 16;
      const unsigned int* us32 = (const unsigned int*)us;

      unsigned int v[16];
      #pragma unroll
      for (int r = 0; r < 16; ++r)
        v[r] = us32[(r0 + r) * (PADROW >> 1) + jc];

      // W bit r = "row r0+r is the last row of its run" = bit (r0+r+1) of the
      // 129-bit start mask (mk0 | mk1<<64 | 1<<128).
      const unsigned long long Am = (r0 < 64) ? mk0 : mk1;
      const unsigned long long Bm = (r0 < 64) ? mk1 : 1ULL;
      const int sh = (r0 & 63) + 1;               // 1..49
      const unsigned int W =
          (unsigned int)((Am >> sh) | (Bm << (64 - sh))) & 0xFFFFu;
      const int br0 =
          (int)((((r0 < 64) ? (mk0 >> r0) : (mk1 >> (r0 - 64))) & 1ULL));
      int s = br0 ? r0 : -1;                      // -1: run covering r0 started earlier
      unsigned int cur = 0;

      #pragma unroll
      for (int r = 0; r < 16; ++r) {
        cur = pkmax(cur, v[r]);
        if ((W >> r) & 1u) {                      // run ends at row r0+r
          if (s < 0) {
            pmS[quarter][jc] = cur;               // partial of run covering r0
          } else {
            const int d = edS[s];
            if (d >= 0) {
              const bool bnd = (s == 0 && prevd == d) ||
                               (r0 + r == 127 && nextd == d);
              unsigned int* ap = aggu + (size_t)d * 64 + jc;
              if (!bnd) *ap = cur;
              else if (cur) casmax(ap, cur);
            }
          }
          cur = 0; s = r0 + r + 1;
        }
      }

      if (!((W >> 15) & 1u)) {                    // last run extends past r1
        if (s < 0) {
          pmS[quarter][jc] = cur;                 // quarter fully inside a run
        } else {                                  // owner of a spanning run
          const int e0 = r0 + 15;                 // quarters 0..6 only (q7: W15=1)
          int nxt;
          if (e0 < 63) {
            unsigned long long ab = mk0 & (~0ULL << (e0 + 1));
            if (ab) nxt = __builtin_ffsll((long long)ab) - 1;
            else    nxt = mk1 ? 64 + __builtin_ffsll((long long)mk1) - 1 : 128;
          } else if (e0 == 63) {
            nxt = mk1 ? 64 + __builtin_ffsll((long long)mk1) - 1 : 128;
          } else {
            unsigned long long ab = mk1 & (~0ULL << (e0 - 63));
            nxt = ab ? 64 + __builtin_ffsll((long long)ab) - 1 : 128;
          }
          os = s; onxt = nxt; od = edS[s]; opart = cur;
        }
      }
    }
    __syncthreads();   // E: pmS ready

    // stage 3 pass 2: owners combine partials and write once.
    // Touches only pmS + registers (prevd/nextd/od captured) -> no barrier F.
    if (os >= 0 && od >= 0) {
      const int endq = (onxt - 1) >> 4;
      #pragma unroll 4
      for (int qq = quarter + 1; qq <= endq; ++qq)
        opart = pkmax(opart, pmS[qq][jc]);
      const bool bnd = (os == 0 && prevd == od) || (onxt == 128 && nextd == od);
      unsigned int* ap = aggu + (size_t)od * 64 + jc;
      if (!bnd) *ap = opart;
      else if (opart) casmax(ap, opart);
    }
  }
}

// ---------------- fallback: atomic edge kernel (small ws) ----------------

__global__ __launch_bounds__(256, 2) void edge_atomic_kernel(
    const float* __restrict__ x, const int* __restrict__ ei,
    const float* __restrict__ w1, const float* __restrict__ b1,
    const float* __restrict__ w2, const float* __restrict__ b2,
    unsigned int* aggu, const int* __restrict__ flag64, int N, int E) {
  __shared__ unsigned short uA[EB * PADROW];
  __shared__ float w1s[6 * NHID];
  __shared__ float b1s[NHID], b2s[NHID];
  __shared__ int es[EB], ed[EB];

  const int t = threadIdx.x;
  const int lane = t & 63;
  const int w = t >> 6;
  const int m = lane & 15;
  const int q = lane >> 4;

  for (int i = t; i < 6 * NHID; i += 256) w1s[i] = w1[i];
  if (t < NHID) { b1s[t] = b1[t]; b2s[t] = b2[t]; }

  short8 bf[32];
  load_bfrags(w2, bf, m, q);

  const bool is64 = (flag64[0] != 0);
  const int nb = (E + EB - 1) / EB;

  for (int batch = blockIdx.x; batch < nb; batch += gridDim.x) {
    const int gbase = batch * EB;
    if (t < EB) {
      int e = gbase + t;
      es[t] = (e < E) ? (is64 ? ei[2 * e] : ei[e]) : 0;
    } else if (t < 2 * EB) {
      int tt = t - EB;
      int e = gbase + tt;
      ed[tt] = (e < E) ? (is64 ? ei[2 * E + 2 * e] : ei[E + e]) : 0;
    }
    __syncthreads();
    {
      const int e = t >> 2;
      const int c0 = (t & 3) * 32;
      const int si = es[e], di = ed[e];
      float xi0 = x[di * 3], xi1 = x[di * 3 + 1], xi2 = x[di * 3 + 2];
      float msg[6];
      msg[0] = xi0; msg[1] = xi1; msg[2] = xi2;
      msg[3] = x[si * 3] - xi0; msg[4] = x[si * 3 + 1] - xi1; msg[5] = x[si * 3 + 2] - xi2;
      unsigned int* d32 = (unsigned int*)uA;
      const int base32 = (e * PADROW + c0) >> 1;
      #pragma unroll
      for (int cc = 0; cc < 32; cc += 2) {
        float u0 = b1s[c0 + cc], u1 = b1s[c0 + cc + 1];
        #pragma unroll
        for (int d = 0; d < 6; ++d) {
          u0 += msg[d] * w1s[d * NHID + c0 + cc];
          u1 += msg[d] * w1s[d * NHID + c0 + cc + 1];
        }
        d32[base32 + (cc >> 1)] = pack2(fmaxf(u0, 0.f), fmaxf(u1, 0.f));
      }
    }
    __syncthreads();

    floatx4 acc[8];
    #pragma unroll
    for (int nt = 0; nt < 8; ++nt) { floatx4 z = {0.f, 0.f, 0.f, 0.f}; acc[nt] = z; }
    mfma_block(uA, bf, acc, w, m, q);

    #pragma unroll
    for (int nt = 0; nt < 8; ++nt) {
      const int c = nt * 16 + m;
      const float bb = b2s[c];
      const int kst = m * 8 + nt;
      #pragma unroll
      for (int r = 0; r < 4; ++r) {
        const int erow = 16 * w + q * 4 + r;
        if (gbase + erow < E) {
          float hb = acc[nt][r] + bb;
          if (hb > 0.f) {
            unsigned int v = (unsigned int)f2bf(hb);
            casmax(aggu + (size_t)ed[erow] * 64 + (kst >> 1), v << (16 * (kst & 1)));
          }
        }
      }
    }
    __syncthreads();
  }
}

// ---------------- fused node MLPs: enc (w3) + dec (w4,w5), agg16 input ----------------
// R9 structure (barriers B0/B1/B2/B3) — R10's barrier removal regressed.
// R15 lesson applies here too: acc zero-init FROZEN (bias in epilogue).

__global__ __launch_bounds__(256, 2) void encdec_kernel(
    const float* __restrict__ w3, const float* __restrict__ b3,
    const float* __restrict__ w4, const float* __restrict__ b4,
    const float* __restrict__ w5, const float* __restrict__ b5,
    const float* __restrict__ pos, const unsigned short* __restrict__ agg16,
    float* __restrict__ out, int N) {
  __shared__ unsigned short uA[EB * PADROW];
  __shared__ short8 w4f[2048];                    // k-permuted w4 frags
  __shared__ float w5s[NHID * 3];

  const int t = threadIdx.x;
  const int lane = t & 63;
  const int w = t >> 6;
  const int m = lane & 15;
  const int q = lane >> 4;

  float b3c[8], b4c[8];
  #pragma unroll
  for (int nt = 0; nt < 8; ++nt) { b3c[nt] = b3[nt * 16 + m]; b4c[nt] = b4[nt * 16 + m]; }

  short8 bf3[32];
  load_bfrags_perm(w3, bf3, m, q);                // k-permuted (agg16 is kstore-ordered)

  for (int idx = t; idx < 2048; idx += 256) {
    const int fg = idx >> 6, ln = idx & 63;
    const int mm = ln & 15;
    const int kc = fg >> 3, nt = fg & 7;
    short8 v;
    #pragma unroll
    for (int j = 0; j < 8; ++j) {
      const int khw = kc * 32 + (ln >> 4) * 8 + j;
      const int ctrue = ((khw & 7) << 4) | (khw >> 3);
      v[j] = (short)f2bf(w4[ctrue * NHID + nt * 16 + mm]);
    }
    w4f[idx] = v;
  }
  for (int i = t; i < NHID * 3; i += 256) w5s[i] = w5[i];
  const float b50 = b5[0], b51 = b5[1], b52 = b5[2];

  const int ch = t & 15;
  const int rr = t >> 4;
  const int nb = (N + EB - 1) / EB;
  __syncthreads();

  uint4 rv[4];
  const uint4 uz = make_uint4(0u, 0u, 0u, 0u);
  {
    const int b0 = blockIdx.x;
    #pragma unroll
    for (int k = 0; k < 4; ++k) {
      const int node = b0 * EB + rr + 16 * k;
      rv[k] = (b0 < nb && node < N) ? ((const uint4*)agg16)[(size_t)node * 16 + ch] : uz;
    }
  }

  for (int batch = blockIdx.x; batch < nb; batch += gridDim.x) {
    const int base = batch * EB;
    #pragma unroll
    for (int k = 0; k < 4; ++k)
      *(uint4*)(&uA[(rr + 16 * k) * PADROW + ch * 8]) = rv[k];
    __syncthreads();   // B0

    {
      const int nxb = batch + gridDim.x;
      #pragma unroll
      for (int k = 0; k < 4; ++k) {
        const int node = nxb * EB + rr + 16 * k;
        rv[k] = (nxb < nb && node < N) ? ((const uint4*)agg16)[(size_t)node * 16 + ch] : uz;
      }
    }

    floatx4 acc[8];
    #pragma unroll
    for (int nt = 0; nt < 8; ++nt) { floatx4 z = {0.f, 0.f, 0.f, 0.f}; acc[nt] = z; }
    mfma_block(uA, bf3, acc, w, m, q);
    __syncthreads();   // B1

    #pragma unroll
    for (int r = 0; r < 4; ++r) {
      union { short8 s; uint4 u; } cv;
      cv.u = make_uint4(
        pkbf(acc[0][r] + b3c[0], acc[1][r] + b3c[1]),
        pkbf(acc[2][r] + b3c[2], acc[3][r] + b3c[3]),
        pkbf(acc[4][r] + b3c[4], acc[5][r] + b3c[5]),
        pkbf(acc[6][r] + b3c[6], acc[7][r] + b3c[7]));
      *(short8*)(&uA[(16 * w + q * 4 + r) * PADROW + m * 8]) = cv.s;
    }
    __syncthreads();   // B2

    #pragma unroll
    for (int nt = 0; nt < 8; ++nt) { floatx4 z = {0.f, 0.f, 0.f, 0.f}; acc[nt] = z; }
    #pragma unroll
    for (int kc = 0; kc < 4; ++kc) {
      short8 a = *(const short8*)(&uA[(16 * w + m) * PADROW + kc * 32 + q * 8]);
      #pragma unroll
      for (int nt = 0; nt < 8; ++nt)
        acc[nt] = __builtin_amdgcn_mfma_f32_16x16x32_bf16(a, w4f[(kc * 8 + nt) * 64 + lane],
                                                          acc[nt], 0, 0, 0);
    }

    float p[4][3];
    #pragma unroll
    for (int r = 0; r < 4; ++r) { p[r][0] = 0.f; p[r][1] = 0.f; p[r][2] = 0.f; }
    #pragma unroll
    for (int nt = 0; nt < 8; ++nt) {
      const int c = nt * 16 + m;
      const float bb = b4c[nt];
      const float w50 = w5s[c * 3], w51 = w5s[c * 3 + 1], w52 = w5s[c * 3 + 2];
      #pragma unroll
      for (int r = 0; r < 4; ++r) {
        float tv = fmaxf(acc[nt][r] + bb, 0.f);
        p[r][0] += tv * w50; p[r][1] += tv * w51; p[r][2] += tv * w52;
      }
    }
    #pragma unroll
    for (int off = 8; off >= 1; off >>= 1) {
      #pragma unroll
      for (int r = 0; r < 4; ++r) {
        p[r][0] += __shfl_xor(p[r][0], off, 16);
        p[r][1] += __shfl_xor(p[r][1], off, 16);
        p[r][2] += __shfl_xor(p[r][2], off, 16);
      }
    }
    if (m == 0) {
      #pragma unroll
      for (int r = 0; r < 4; ++r) {
        const int node = base + 16 * w + q * 4 + r;
        if (node < N) {
          out[node * 3]     = pos[node * 3]     + 0.1f * tanhf(p[r][0] + b50);
          out[node * 3 + 1] = pos[node * 3 + 1] + 0.1f * tanhf(p[r][1] + b51);
          out[node * 3 + 2] = pos[node * 3 + 2] + 0.1f * tanhf(p[r][2] + b52);
        }
      }
    }
    __syncthreads();   // B3
  }
}

extern "C" void kernel_launch(void* const* d_in, const int* in_sizes, int n_in,
                              void* d_out, int out_size, void* d_ws, size_t ws_size,
                              hipStream_t stream) {
  const float* x   = (const float*)d_in[0];
  const float* pos = (const float*)d_in[1];
  const int*   ei  = (const int*)d_in[2];
  const float* w1  = (const float*)d_in[3];
  const float* b1  = (const float*)d_in[4];
  const float* w2  = (const float*)d_in[5];
  const float* b2  = (const float*)d_in[6];
  const float* w3  = (const float*)d_in[7];
  const float* b3  = (const float*)d_in[8];
  const float* w4  = (const float*)d_in[9];
  const float* b4  = (const float*)d_in[10];
  const float* w5  = (const float*)d_in[11];
  const float* b5  = (const float*)d_in[12];
  float* out = (float*)d_out;

  const int N = in_sizes[0] / 3;
  const int E = in_sizes[2] / 2;
  const int nbuck = (N + 255) >> 8;

  char* ws = (char*)d_ws;
  unsigned short* agg16 = (unsigned short*)ws;                // N*128 u16 (kstore order)
  const size_t aggB = (size_t)N * NHID * sizeof(unsigned short);
  const size_t midB = (((size_t)E * 4) + 15) & ~(size_t)15;   // u32-packed mid
  unsigned int* mid32 = (unsigned int*)(ws + aggB);
  int2* sorted = (int2*)(ws + aggB + midB);
  int*  mat    = (int*)(ws + aggB + midB + (size_t)E * 8);
  int*  btot   = mat + (size_t)nbuck * PB;
  int*  bstart = btot + nbuck;
  const size_t needed = aggB + midB + (size_t)E * 8 + ((size_t)nbuck * PB + nbuck + 520) * 4;

  if (ws_size >= needed && nbuck <= 511 && E >= 64) {
    part_hist<<<2048, 256, 0, stream>>>(ei, mat, E, nbuck, (float4*)agg16, N * 16);
    scan_rows<<<nbuck, 512, 0, stream>>>(mat, btot, nbuck);
    part_scatter<<<PB, 512, 0, stream>>>(ei, mat, btot, bstart, mid32, E, nbuck);
    bucket_sort<<<nbuck, 512, 0, stream>>>(mid32, bstart, sorted);
    edge_sorted_kernel<<<512, 512, 0, stream>>>(x, sorted, w1, b1, w2, b2,
                                                (unsigned int*)agg16, N, E);
  } else {
    int* flag2 = (int*)(ws + aggB);
    zero_detect_kernel<<<2048, 256, 0, stream>>>((float4*)agg16, N * 16, ei, flag2);
    edge_atomic_kernel<<<512, 256, 0, stream>>>(x, ei, w1, b1, w2, b2,
                                                (unsigned int*)agg16, flag2, N, E);
  }
  encdec_kernel<<<512, 256, 0, stream>>>(w3, b3, w4, b4, w5, b5, pos, agg16, out, N);
}